// Round 7
// baseline (702.866 us; speedup 1.0000x reference)
//
#include <hip/hip_runtime.h>
#include <math.h>

constexpr int LL   = 384;
constexpr int FF   = 128;
constexpr int NH   = 12;
constexpr int HQK  = 384;
constexpr int HV   = 384;
constexpr int HP3  = 288;
constexpr int NPT  = 96;
constexpr int CC   = 64;
constexpr int DOUT = 1824;

__device__ inline unsigned short f2bf(float f) {
    unsigned int u = __float_as_uint(f);
    return (unsigned short)((u + 0x7fff + ((u >> 16) & 1)) >> 16);
}
__device__ inline float bf2f(unsigned short s) {
    return __uint_as_float(((unsigned int)s) << 16);
}

// sense-reversal global barrier; safe because grid (384) <= guaranteed capacity (512):
// LDS 70656B -> 2 blocks/CU, launch_bounds(512,4) -> VGPR<=128 -> 16 waves/CU -> 2 blocks/CU.
__device__ inline void gbar(unsigned* cnt, unsigned* gen, unsigned nb) {
    __syncthreads();
    if (threadIdx.x == 0) {
        __threadfence();   // release prior writes (agent scope: L1/L2 wb)
        unsigned g = __hip_atomic_load(gen, __ATOMIC_RELAXED, __HIP_MEMORY_SCOPE_AGENT);
        unsigned a = __hip_atomic_fetch_add(cnt, 1u, __ATOMIC_ACQ_REL, __HIP_MEMORY_SCOPE_AGENT);
        if (a == nb - 1u) {
            __hip_atomic_store(cnt, 0u, __ATOMIC_RELAXED, __HIP_MEMORY_SCOPE_AGENT);
            __hip_atomic_store(gen, g + 1u, __ATOMIC_RELEASE, __HIP_MEMORY_SCOPE_AGENT);
        } else {
            unsigned cur;
            do {
                __builtin_amdgcn_s_sleep(2);
                cur = __hip_atomic_load(gen, __ATOMIC_ACQUIRE, __HIP_MEMORY_SCOPE_AGENT);
            } while (cur == g);
        }
        __threadfence();   // acquire: invalidate caches before consuming others' writes
    }
    __syncthreads();
}

__global__ void __launch_bounds__(512, 4) mega(
    const float* __restrict__ R, const float* __restrict__ t,
    const float* __restrict__ x, const float* __restrict__ z,
    const float* __restrict__ Wq, const float* __restrict__ Wk, const float* __restrict__ Wv,
    const float* __restrict__ Wpb, const float* __restrict__ spc,
    const float* __restrict__ Wqp, const float* __restrict__ Wkp, const float* __restrict__ Wvp,
    const float* __restrict__ Wout, const float* __restrict__ bout,
    const float* __restrict__ ln1g, const float* __restrict__ ln1b,
    const float* __restrict__ W1, const float* __restrict__ b1,
    const float* __restrict__ W2, const float* __restrict__ b2,
    const float* __restrict__ W3, const float* __restrict__ b3,
    const float* __restrict__ ln2g, const float* __restrict__ ln2b,
    float* __restrict__ out,
    float* qb, float* kb, float* vb, float* qp, float* kp, float* vp,
    float* qnb, float* knb, float* lgA, float* feat, float* part,
    unsigned* bar)
{
    __shared__ __align__(16) unsigned char sm[70656];
    const int bid = blockIdx.x, tid = threadIdx.x;
    const unsigned nb = gridDim.x;
    unsigned* bcnt = bar;
    unsigned* bgen = bar + 1;

    // ================= P1: six projections (tiled GEMM) =================
    {
        float* xs = (float*)sm;   // 64 x 132
        for (int job = bid; job < 378; job += nb) {
            const int ct = job % 63, rt = job / 63;
            const float* W; float* O; int ld, cb;
            if (ct < 12)      { W = Wq;  O = qb; ld = 384; cb = ct * 32; }
            else if (ct < 24) { W = Wk;  O = kb; ld = 384; cb = (ct - 12) * 32; }
            else if (ct < 36) { W = Wv;  O = vb; ld = 384; cb = (ct - 24) * 32; }
            else if (ct < 45) { W = Wqp; O = qp; ld = 288; cb = (ct - 36) * 32; }
            else if (ct < 54) { W = Wkp; O = kp; ld = 288; cb = (ct - 45) * 32; }
            else              { W = Wvp; O = vp; ld = 288; cb = (ct - 54) * 32; }
            const int r0 = rt * 64;
            const float4* xsrc = (const float4*)(x + (size_t)r0 * FF);
#pragma unroll
            for (int k = 0; k < 4; ++k) {
                int idx = tid + k * 512;
                float4 v = xsrc[idx];
                int row = idx >> 5, c4 = (idx & 31) * 4;
                float* d = &xs[row * 132 + c4];
                d[0] = v.x; d[1] = v.y; d[2] = v.z; d[3] = v.w;
            }
            __syncthreads();
            const int row = tid >> 3, cg = tid & 7;
            const float* Wp = W + cb + cg * 4;
            const float* xr = &xs[row * 132];
            float a0 = 0.f, a1 = 0.f, a2 = 0.f, a3 = 0.f;
#pragma unroll 8
            for (int f = 0; f < FF; ++f) {
                float4 w = *(const float4*)(Wp + (size_t)f * ld);
                float xa = xr[f];
                a0 = fmaf(xa, w.x, a0); a1 = fmaf(xa, w.y, a1);
                a2 = fmaf(xa, w.z, a2); a3 = fmaf(xa, w.w, a3);
            }
            float* o = O + (size_t)(r0 + row) * ld + cb + cg * 4;
            o[0] = a0; o[1] = a1; o[2] = a2; o[3] = a3;
            __syncthreads();
        }
    }
    gbar(bcnt, bgen, nb);

    // ================= P2: rigid transforms (in place) + point norms =================
    {
        float* nq = (float*)sm;
        float* nk = nq + 128;
        for (int i = bid; i < LL; i += (int)nb) {
            if (tid < 288) {
                const int set = tid / 96, pt = tid % 96;
                const float r00 = R[i*9+0], r01 = R[i*9+1], r02 = R[i*9+2];
                const float r10 = R[i*9+3], r11 = R[i*9+4], r12 = R[i*9+5];
                const float r20 = R[i*9+6], r21 = R[i*9+7], r22 = R[i*9+8];
                const float t0 = t[i*3+0], t1 = t[i*3+1], t2 = t[i*3+2];
                float* P = (set == 0) ? qp : (set == 1) ? kp : vp;
                const size_t base = (size_t)i * HP3 + pt * 3;
                float l0 = P[base], l1 = P[base+1], l2 = P[base+2];
                float g0 = fmaf(r00, l0, fmaf(r01, l1, fmaf(r02, l2, t0)));
                float g1 = fmaf(r10, l0, fmaf(r11, l1, fmaf(r12, l2, t1)));
                float g2 = fmaf(r20, l0, fmaf(r21, l1, fmaf(r22, l2, t2)));
                P[base] = g0; P[base+1] = g1; P[base+2] = g2;
                float nn = g0*g0 + g1*g1 + g2*g2;
                if (set == 0) nq[pt] = nn;
                else if (set == 1) nk[pt] = nn;
            }
            __syncthreads();
            if (tid < NH) {
                float sq = 0.f, sk = 0.f;
#pragma unroll
                for (int p = 0; p < 8; ++p) { sq += nq[tid*8+p]; sk += nk[tid*8+p]; }
                qnb[(size_t)i*NH + tid] = sq;
                knb[(size_t)i*NH + tid] = sk;
            }
            __syncthreads();
        }
    }
    gbar(bcnt, bgen, nb);

    // ================= P3: node+spatial logits (rank-58 bilinear GEMM) =================
    {
        float* As = (float*)sm;          // 64 x 60
        float* Bs = As + 64 * 60;
        for (int job = bid; job < 432; job += nb) {
            const int it = job / 72, rem = job % 72, jt = rem / 12, h = rem % 12;
            const float g = log1pf(expf(spc[h]));
            const float s3 = 0.5773502691896258f;
            const float c1 = s3 * 0.17677669529663687f;
            const float c2 = s3 * g * (1.f / 6.f);
            const float c3 = -s3 * g * (1.f / 12.f);
            const int i0 = it * 64, j0 = jt * 64;
            for (int idx = tid; idx < 2048; idx += 512) {
                int r = idx >> 5, c = idx & 31;
                As[r*60 + c] = qb[(size_t)(i0 + r) * HQK + h*32 + c];
                Bs[r*60 + c] = kb[(size_t)(j0 + r) * HQK + h*32 + c] * c1;
            }
            for (int idx = tid; idx < 2048; idx += 512) {
                int r = idx >> 5, c = idx & 31;
                if (c < 24) {
                    As[r*60 + 32 + c] = qp[(size_t)(i0 + r) * HP3 + h*24 + c];
                    Bs[r*60 + 32 + c] = kp[(size_t)(j0 + r) * HP3 + h*24 + c] * c2;
                } else if (c == 24) {
                    As[r*60 + 56] = qnb[(size_t)(i0 + r) * NH + h];
                    As[r*60 + 57] = 1.f;
                    As[r*60 + 58] = 0.f; As[r*60 + 59] = 0.f;
                    Bs[r*60 + 56] = c3;
                    Bs[r*60 + 57] = c3 * knb[(size_t)(j0 + r) * NH + h];
                    Bs[r*60 + 58] = 0.f; Bs[r*60 + 59] = 0.f;
                }
            }
            __syncthreads();
            const int tx = tid & 15, ty = tid >> 4;   // ty 0..31 -> rows 2ty,2ty+1
            float acc[2][4] = {};
            for (int k4 = 0; k4 < 60; k4 += 4) {
                float4 a[2], b[4];
                a[0] = *(const float4*)&As[(ty*2 + 0)*60 + k4];
                a[1] = *(const float4*)&As[(ty*2 + 1)*60 + k4];
#pragma unroll
                for (int c = 0; c < 4; ++c) b[c] = *(const float4*)&Bs[(tx*4 + c)*60 + k4];
#pragma unroll
                for (int r = 0; r < 2; ++r)
#pragma unroll
                    for (int c = 0; c < 4; ++c) {
                        acc[r][c] = fmaf(a[r].x, b[c].x, acc[r][c]);
                        acc[r][c] = fmaf(a[r].y, b[c].y, acc[r][c]);
                        acc[r][c] = fmaf(a[r].z, b[c].z, acc[r][c]);
                        acc[r][c] = fmaf(a[r].w, b[c].w, acc[r][c]);
                    }
            }
#pragma unroll
            for (int r = 0; r < 2; ++r)
                *(float4*)&lgA[((size_t)(i0 + ty*2 + r) * NH + h) * LL + j0 + tx*4] =
                    make_float4(acc[r][0], acc[r][1], acc[r][2], acc[r][3]);
            __syncthreads();
        }
    }
    gbar(bcnt, bgen, nb);

    // ================= P4: pair term + softmax + p2n (z bf16 in LDS) =================
    {
        unsigned short* z_s = (unsigned short*)sm;     // 384 x 68 bf16 = 52224 B
        float* red = (float*)sm;                        // aliased after barrier
        float* a_s = (float*)(sm + 52224);              // 12 x 384 = 18432 B
        const int wv = tid >> 6, lane = tid & 63;
        for (int i = bid; i < LL; i += (int)nb) {
            const float4* zsrc = (const float4*)(z + (size_t)i * (LL * CC));
#pragma unroll
            for (int k = 0; k < 12; ++k) {
                int idx = tid + k * 512;
                float4 v = zsrc[idx];
                int j = idx >> 4, c4 = idx & 15;
                ushort4 pk;
                pk.x = f2bf(v.x); pk.y = f2bf(v.y); pk.z = f2bf(v.z); pk.w = f2bf(v.w);
                *(ushort4*)&z_s[j * 68 + c4 * 4] = pk;
            }
            __syncthreads();
            if (tid < 384) {
                const int j = tid;
                float pacc[12] = {};
                const unsigned short* zrow = &z_s[j * 68];
                for (int c = 0; c < CC; ++c) {
                    float zc = bf2f(zrow[c]);
#pragma unroll
                    for (int hh = 0; hh < 12; ++hh)
                        pacc[hh] = fmaf(zc, Wpb[c * NH + hh], pacc[hh]);
                }
                const float s3 = 0.5773502691896258f;
#pragma unroll
                for (int hh = 0; hh < 12; ++hh)
                    a_s[hh * 384 + j] = lgA[((size_t)i * NH + hh) * LL + j] + pacc[hh] * s3;
            }
            __syncthreads();
            if (wv < 6) {
#pragma unroll
                for (int rr = 0; rr < 2; ++rr) {
                    const int h = wv * 2 + rr;
                    float v[6];
#pragma unroll
                    for (int k = 0; k < 6; ++k) v[k] = a_s[h * 384 + lane + k * 64];
                    float m = v[0];
#pragma unroll
                    for (int k = 1; k < 6; ++k) m = fmaxf(m, v[k]);
#pragma unroll
                    for (int off = 32; off; off >>= 1) m = fmaxf(m, __shfl_xor(m, off));
                    float s = 0.f;
#pragma unroll
                    for (int k = 0; k < 6; ++k) { v[k] = expf(v[k] - m); s += v[k]; }
#pragma unroll
                    for (int off = 32; off; off >>= 1) s += __shfl_xor(s, off);
                    float inv = 1.f / s;
#pragma unroll
                    for (int k = 0; k < 6; ++k) {
                        float a = v[k] * inv;
                        a_s[h * 384 + lane + k * 64] = a;
                        lgA[((size_t)i * NH + h) * LL + lane + k * 64] = a;
                    }
                }
            }
            __syncthreads();
            const int c4 = tid & 15, jc = tid >> 4;
            float4 acc[12] = {};
            const int jbase = jc * 12;
#pragma unroll
            for (int j4 = 0; j4 < 3; ++j4) {
                const int j = jbase + j4 * 4;
                float zv[4][4];
#pragma unroll
                for (int jj = 0; jj < 4; ++jj) {
                    ushort4 zz = *(const ushort4*)&z_s[(j + jj) * 68 + c4 * 4];
                    zv[jj][0] = bf2f(zz.x); zv[jj][1] = bf2f(zz.y);
                    zv[jj][2] = bf2f(zz.z); zv[jj][3] = bf2f(zz.w);
                }
#pragma unroll
                for (int hh = 0; hh < 12; ++hh) {
                    float4 a4 = *(const float4*)&a_s[hh * 384 + j];
                    acc[hh].x = fmaf(a4.x, zv[0][0], acc[hh].x); acc[hh].y = fmaf(a4.x, zv[0][1], acc[hh].y);
                    acc[hh].z = fmaf(a4.x, zv[0][2], acc[hh].z); acc[hh].w = fmaf(a4.x, zv[0][3], acc[hh].w);
                    acc[hh].x = fmaf(a4.y, zv[1][0], acc[hh].x); acc[hh].y = fmaf(a4.y, zv[1][1], acc[hh].y);
                    acc[hh].z = fmaf(a4.y, zv[1][2], acc[hh].z); acc[hh].w = fmaf(a4.y, zv[1][3], acc[hh].w);
                    acc[hh].x = fmaf(a4.z, zv[2][0], acc[hh].x); acc[hh].y = fmaf(a4.z, zv[2][1], acc[hh].y);
                    acc[hh].z = fmaf(a4.z, zv[2][2], acc[hh].z); acc[hh].w = fmaf(a4.z, zv[2][3], acc[hh].w);
                    acc[hh].x = fmaf(a4.w, zv[3][0], acc[hh].x); acc[hh].y = fmaf(a4.w, zv[3][1], acc[hh].y);
                    acc[hh].z = fmaf(a4.w, zv[3][2], acc[hh].z); acc[hh].w = fmaf(a4.w, zv[3][3], acc[hh].w);
                }
            }
            __syncthreads();   // all z_s reads done; red aliases z_s
#pragma unroll
            for (int hh = 0; hh < 12; ++hh) {
                acc[hh].x += __shfl_xor(acc[hh].x, 16); acc[hh].y += __shfl_xor(acc[hh].y, 16);
                acc[hh].z += __shfl_xor(acc[hh].z, 16); acc[hh].w += __shfl_xor(acc[hh].w, 16);
                acc[hh].x += __shfl_xor(acc[hh].x, 32); acc[hh].y += __shfl_xor(acc[hh].y, 32);
                acc[hh].z += __shfl_xor(acc[hh].z, 32); acc[hh].w += __shfl_xor(acc[hh].w, 32);
            }
            if (lane < 16) {
#pragma unroll
                for (int hh = 0; hh < 12; ++hh)
                    *(float4*)&red[wv * 768 + hh * 64 + lane * 4] = acc[hh];
            }
            __syncthreads();
            if (tid < 192) {
                int hh = tid >> 4, cc = tid & 15;
                float4 s = make_float4(0.f, 0.f, 0.f, 0.f);
#pragma unroll
                for (int w = 0; w < 8; ++w) {
                    float4 p = *(const float4*)&red[w * 768 + hh * 64 + cc * 4];
                    s.x += p.x; s.y += p.y; s.z += p.z; s.w += p.w;
                }
                *(float4*)&feat[(size_t)i * DOUT + hh * 64 + cc * 4] = s;
            }
            __syncthreads();
        }
    }
    gbar(bcnt, bgen, nb);

    // ================= P5: node + vp aggregation + frame transform =================
    {
        float* a_l = (float*)sm;                       // 16 x 384 = 24576 B (alpha in LDS)
        float* bs  = (float*)(sm + 24576);             // 128 x 57 = 29184 B
        float (*sa)[24] = (float (*)[24])(sm + 24576 + 29184);   // 16 x 24
        const int wv = tid >> 6, n = tid & 63;
        for (int job = bid; job < 288; job += nb) {
            const int it = job / 12, h = job % 12;
            const int i0 = it * 16;
            for (int r = 0; r < 16; ++r)
                if (tid < 384)
                    a_l[r * 384 + tid] = lgA[((size_t)(i0 + r) * NH + h) * LL + tid];
            float acc[2] = {0.f, 0.f};
            for (int tile = 0; tile < 3; ++tile) {
                const int j0 = tile * 128;
                __syncthreads();
                for (int idx = tid; idx < 1792; idx += 512) {
                    int jr = idx / 14, q2 = idx % 14;
                    const float* src = (q2 < 8)
                        ? vb + (size_t)(j0 + jr) * HV + h * 32 + q2 * 4
                        : vp + (size_t)(j0 + jr) * HP3 + h * 24 + (q2 - 8) * 4;
                    int c0 = (q2 < 8) ? q2 * 4 : 32 + (q2 - 8) * 4;
                    float* d = &bs[jr * 57 + c0];
                    d[0] = src[0]; d[1] = src[1]; d[2] = src[2]; d[3] = src[3];
                }
                __syncthreads();
                if (n < 56) {
                    for (int j4 = 0; j4 < 32; ++j4) {
                        float bv0 = bs[(j4*4+0)*57 + n];
                        float bv1 = bs[(j4*4+1)*57 + n];
                        float bv2 = bs[(j4*4+2)*57 + n];
                        float bv3 = bs[(j4*4+3)*57 + n];
#pragma unroll
                        for (int r = 0; r < 2; ++r) {
                            const float* ar = &a_l[(wv*2 + r) * 384 + j0 + j4 * 4];
                            acc[r] = fmaf(ar[0], bv0, acc[r]);
                            acc[r] = fmaf(ar[1], bv1, acc[r]);
                            acc[r] = fmaf(ar[2], bv2, acc[r]);
                            acc[r] = fmaf(ar[3], bv3, acc[r]);
                        }
                    }
                }
            }
            __syncthreads();
            if (n < 56) {
                if (n < 32) {
#pragma unroll
                    for (int r = 0; r < 2; ++r)
                        feat[(size_t)(i0 + wv*2 + r) * DOUT + 768 + h * 32 + n] = acc[r];
                } else {
#pragma unroll
                    for (int r = 0; r < 2; ++r)
                        sa[wv*2 + r][n - 32] = acc[r];
                }
            }
            __syncthreads();
            if (tid < 128) {
                const int ri = tid >> 3, p = tid & 7;
                const int i = i0 + ri;
                const int pt = h * 8 + p;
                float a0 = sa[ri][p*3+0], a1 = sa[ri][p*3+1], a2 = sa[ri][p*3+2];
                float d0 = a0 - t[i*3+0], d1 = a1 - t[i*3+1], d2 = a2 - t[i*3+2];
                float f0 = R[i*9+0]*d0 + R[i*9+3]*d1 + R[i*9+6]*d2;
                float f1 = R[i*9+1]*d0 + R[i*9+4]*d1 + R[i*9+7]*d2;
                float f2 = R[i*9+2]*d0 + R[i*9+5]*d1 + R[i*9+8]*d2;
                float dist = sqrtf(f0*f0 + f1*f1 + f2*f2);
                float inv = 1.f / (dist + 1e-4f);
                float* fr = feat + (size_t)i * DOUT;
                fr[1152 + pt*3+0] = f0; fr[1152 + pt*3+1] = f1; fr[1152 + pt*3+2] = f2;
                fr[1440 + pt] = dist;
                fr[1536 + pt*3+0] = f0*inv; fr[1536 + pt*3+1] = f1*inv; fr[1536 + pt*3+2] = f2*inv;
            }
            __syncthreads();
        }
    }
    gbar(bcnt, bgen, nb);

    // ================= P6: out-projection split-K GEMM =================
    {
        float* As = (float*)sm;    // 32 x 153
        for (int job = bid; job < 144; job += nb) {
            const int mt = job / 12, ks = job % 12;
            const int m0 = mt * 32, k0 = ks * 152;
            for (int idx = tid; idx < 1216; idx += 512) {
                int r = idx / 38, c4 = idx % 38;
                float4 v = *(const float4*)&feat[(size_t)(m0 + r) * DOUT + k0 + c4 * 4];
                float* d = &As[r * 153 + c4 * 4];
                d[0] = v.x; d[1] = v.y; d[2] = v.z; d[3] = v.w;
            }
            __syncthreads();
            const int f0 = (tid & 31) * 4;
            const int r0 = (tid >> 5) * 2;
            const float* ar0 = &As[r0 * 153];
            const float* ar1 = &As[(r0 + 1) * 153];
            const float* wp = Wout + (size_t)k0 * FF + f0;
            float a00=0,a01=0,a02=0,a03=0, a10=0,a11=0,a12=0,a13=0;
#pragma unroll 4
            for (int k = 0; k < 152; ++k) {
                float4 w = *(const float4*)(wp + (size_t)k * FF);
                float xa = ar0[k], xb = ar1[k];
                a00 = fmaf(xa, w.x, a00); a01 = fmaf(xa, w.y, a01);
                a02 = fmaf(xa, w.z, a02); a03 = fmaf(xa, w.w, a03);
                a10 = fmaf(xb, w.x, a10); a11 = fmaf(xb, w.y, a11);
                a12 = fmaf(xb, w.z, a12); a13 = fmaf(xb, w.w, a13);
            }
            float* o0 = part + ((size_t)ks * LL + m0 + r0) * FF + f0;
            *(float4*)o0 = make_float4(a00, a01, a02, a03);
            *(float4*)(o0 + FF) = make_float4(a10, a11, a12, a13);
            __syncthreads();
        }
    }
    gbar(bcnt, bgen, nb);

    // ================= P7: LN1 + MLP + LN2 per row =================
    {
        float (*prt)[128] = (float (*)[128])sm;
        float* x1s = (float*)(sm + 4 * 128 * 4);
        float* hbA = x1s + 128;
        float* hbB = hbA + 128;
        float* wrA = hbB + 128;
        float* wrB = wrA + 2;
        const int f = tid & 127, q = tid >> 7;
        for (int i = bid; i < LL; i += (int)nb) {
            float acc = 0.f;
#pragma unroll
            for (int k = 0; k < 3; ++k)
                acc += part[((size_t)(q * 3 + k) * LL + i) * FF + f];
            prt[q][f] = acc;
            __syncthreads();
            float s1 = 0.f, dv1 = 0.f;
            if (tid < 128) {
                s1 = prt[0][f] + prt[1][f] + prt[2][f] + prt[3][f]
                   + bout[f] + x[(size_t)i * FF + f];
                float r = s1;
#pragma unroll
                for (int off = 32; off; off >>= 1) r += __shfl_xor(r, off);
                if ((tid & 63) == 0) wrA[tid >> 6] = r;
            }
            __syncthreads();
            if (tid < 128) {
                float mu = (wrA[0] + wrA[1]) * (1.f / FF);
                dv1 = s1 - mu;
                float r = dv1 * dv1;
#pragma unroll
                for (int off = 32; off; off >>= 1) r += __shfl_xor(r, off);
                if ((tid & 63) == 0) wrB[tid >> 6] = r;
            }
            __syncthreads();
            if (tid < 128) {
                float var = (wrB[0] + wrB[1]) * (1.f / FF);
                x1s[f] = dv1 * rsqrtf(var + 1e-5f) * ln1g[f] + ln1b[f];
            }
            __syncthreads();
            // MLP L1 (split-K=4)
            {
                const int k0 = q * 32;
                float p0=0,p1=0,p2=0,p3=0;
                for (int k = 0; k < 8; ++k) {
                    int d = k0 + k * 4;
                    p0 = fmaf(x1s[d+0], W1[(size_t)(d+0)*FF + f], p0);
                    p1 = fmaf(x1s[d+1], W1[(size_t)(d+1)*FF + f], p1);
                    p2 = fmaf(x1s[d+2], W1[(size_t)(d+2)*FF + f], p2);
                    p3 = fmaf(x1s[d+3], W1[(size_t)(d+3)*FF + f], p3);
                }
                prt[q][f] = p0 + p1 + p2 + p3;
            }
            __syncthreads();
            if (tid < 128) hbA[f] = fmaxf(prt[0][f]+prt[1][f]+prt[2][f]+prt[3][f] + b1[f], 0.f);
            __syncthreads();
            // L2
            {
                const int k0 = q * 32;
                float p0=0,p1=0,p2=0,p3=0;
                for (int k = 0; k < 8; ++k) {
                    int d = k0 + k * 4;
                    p0 = fmaf(hbA[d+0], W2[(size_t)(d+0)*FF + f], p0);
                    p1 = fmaf(hbA[d+1], W2[(size_t)(d+1)*FF + f], p1);
                    p2 = fmaf(hbA[d+2], W2[(size_t)(d+2)*FF + f], p2);
                    p3 = fmaf(hbA[d+3], W2[(size_t)(d+3)*FF + f], p3);
                }
                prt[q][f] = p0 + p1 + p2 + p3;
            }
            __syncthreads();
            if (tid < 128) hbB[f] = fmaxf(prt[0][f]+prt[1][f]+prt[2][f]+prt[3][f] + b2[f], 0.f);
            __syncthreads();
            // L3
            {
                const int k0 = q * 32;
                float p0=0,p1=0,p2=0,p3=0;
                for (int k = 0; k < 8; ++k) {
                    int d = k0 + k * 4;
                    p0 = fmaf(hbB[d+0], W3[(size_t)(d+0)*FF + f], p0);
                    p1 = fmaf(hbB[d+1], W3[(size_t)(d+1)*FF + f], p1);
                    p2 = fmaf(hbB[d+2], W3[(size_t)(d+2)*FF + f], p2);
                    p3 = fmaf(hbB[d+3], W3[(size_t)(d+3)*FF + f], p3);
                }
                prt[q][f] = p0 + p1 + p2 + p3;
            }
            __syncthreads();
            float s2 = 0.f, dv2 = 0.f;
            if (tid < 128) {
                s2 = x1s[f] + prt[0][f]+prt[1][f]+prt[2][f]+prt[3][f] + b3[f];
                float r = s2;
#pragma unroll
                for (int off = 32; off; off >>= 1) r += __shfl_xor(r, off);
                if ((tid & 63) == 0) wrA[tid >> 6] = r;
            }
            __syncthreads();
            if (tid < 128) {
                float mu = (wrA[0] + wrA[1]) * (1.f / FF);
                dv2 = s2 - mu;
                float r = dv2 * dv2;
#pragma unroll
                for (int off = 32; off; off >>= 1) r += __shfl_xor(r, off);
                if ((tid & 63) == 0) wrB[tid >> 6] = r;
            }
            __syncthreads();
            if (tid < 128) {
                float var = (wrB[0] + wrB[1]) * (1.f / FF);
                out[(size_t)i * FF + f] = dv2 * rsqrtf(var + 1e-5f) * ln2g[f] + ln2b[f];
            }
            __syncthreads();
        }
    }
}

extern "C" void kernel_launch(void* const* d_in, const int* in_sizes, int n_in,
                              void* d_out, int out_size, void* d_ws, size_t ws_size,
                              hipStream_t stream) {
    const float* R    = (const float*)d_in[0];
    const float* t    = (const float*)d_in[1];
    const float* x    = (const float*)d_in[2];
    const float* z    = (const float*)d_in[3];
    const float* Wq   = (const float*)d_in[5];
    const float* Wk   = (const float*)d_in[6];
    const float* Wv   = (const float*)d_in[7];
    const float* Wpb  = (const float*)d_in[8];
    const float* spc  = (const float*)d_in[9];
    const float* Wqp  = (const float*)d_in[10];
    const float* Wkp  = (const float*)d_in[11];
    const float* Wvp  = (const float*)d_in[12];
    const float* Wout = (const float*)d_in[13];
    const float* bout = (const float*)d_in[14];
    const float* ln1g = (const float*)d_in[15];
    const float* ln1b = (const float*)d_in[16];
    const float* W1   = (const float*)d_in[17];
    const float* b1   = (const float*)d_in[18];
    const float* W2   = (const float*)d_in[19];
    const float* b2   = (const float*)d_in[20];
    const float* W3   = (const float*)d_in[21];
    const float* b3   = (const float*)d_in[22];
    const float* ln2g = (const float*)d_in[23];
    const float* ln2b = (const float*)d_in[24];
    float* out = (float*)d_out;

    unsigned* bar = (unsigned*)d_ws;        // [cnt, gen] + pad to 16 B
    float* base = (float*)d_ws + 4;
    float* qb   = base;
    float* kb   = qb   + (size_t)LL * HQK;
    float* vb   = kb   + (size_t)LL * HQK;
    float* qp   = vb   + (size_t)LL * HV;
    float* kp   = qp   + (size_t)LL * HP3;
    float* vp   = kp   + (size_t)LL * HP3;
    float* qnb  = vp   + (size_t)LL * HP3;
    float* knb  = qnb  + (size_t)LL * NH;
    float* lgA  = knb  + (size_t)LL * NH;        // [384][12][384] logits -> alpha
    float* feat = lgA  + (size_t)LL * NH * LL;   // [384][1824]
    float* part = feat + (size_t)LL * DOUT;      // [12][384][128]

    hipMemsetAsync(d_ws, 0, 16, stream);         // reset barrier (graph-capturable)
    mega<<<384, 512, 0, stream>>>(R, t, x, z, Wq, Wk, Wv, Wpb, spc, Wqp, Wkp, Wvp,
                                  Wout, bout, ln1g, ln1b, W1, b1, W2, b2, W3, b3,
                                  ln2g, ln2b, out,
                                  qb, kb, vb, qp, kp, vp, qnb, knb, lgA, feat, part,
                                  bar);
}

// Round 8
// 108.086 us; speedup vs baseline: 6.5029x; 6.5029x over previous
//
#include <hip/hip_runtime.h>
#include <math.h>

constexpr int LL   = 384;
constexpr int FF   = 128;
constexpr int NH   = 12;
constexpr int HQK  = 384;
constexpr int HV   = 384;
constexpr int HP3  = 288;
constexpr int NPT  = 96;
constexpr int CC   = 64;
constexpr int DOUT = 1824;

__device__ inline unsigned short f2bf(float f) {
    unsigned int u = __float_as_uint(f);
    return (unsigned short)((u + 0x7fff + ((u >> 16) & 1)) >> 16);
}
__device__ inline float bf2f(unsigned short s) {
    return __uint_as_float(((unsigned int)s) << 16);
}

// ---------------- K1a: six projections (raw, local coords) + z L3-prefetch ----------------
// 1D grid: blocks 0..377 = GEMM jobs (63 col-tiles x 6 row-tiles); 378..441 = z prefetch.
__global__ void __launch_bounds__(256) k1a_gemm(
    const float* __restrict__ x, const float* __restrict__ z,
    const float* __restrict__ Wq, const float* __restrict__ Wk, const float* __restrict__ Wv,
    const float* __restrict__ Wqp, const float* __restrict__ Wkp, const float* __restrict__ Wvp,
    float* __restrict__ qb, float* __restrict__ kb, float* __restrict__ vb,
    float* __restrict__ qpl, float* __restrict__ kpl, float* __restrict__ vpl,
    float* __restrict__ dump) {
    const int bid = blockIdx.x, tid = threadIdx.x;
    if (bid >= 378) {   // z prefetch -> warm L3 (z fits 256MB Infinity Cache)
        const int pid = bid - 378;
        const float4* src = (const float4*)z + (size_t)pid * 36864;
        float4 s = make_float4(0.f, 0.f, 0.f, 0.f);
        for (int k = 0; k < 144; ++k) {
            float4 v = src[tid + k * 256];
            s.x += v.x; s.y += v.y; s.z += v.z; s.w += v.w;
        }
        dump[pid * 256 + tid] = s.x + s.y + s.z + s.w;  // part buffer; k5a overwrites
        return;
    }
    const int ct = bid % 63, rt = bid / 63;
    __shared__ float xs[64 * 132];

    const float* W; float* O; int ld, cb;
    if (ct < 12)      { W = Wq;  O = qb;  ld = 384; cb = ct * 32; }
    else if (ct < 24) { W = Wk;  O = kb;  ld = 384; cb = (ct - 12) * 32; }
    else if (ct < 36) { W = Wv;  O = vb;  ld = 384; cb = (ct - 24) * 32; }
    else if (ct < 45) { W = Wqp; O = qpl; ld = 288; cb = (ct - 36) * 32; }
    else if (ct < 54) { W = Wkp; O = kpl; ld = 288; cb = (ct - 45) * 32; }
    else              { W = Wvp; O = vpl; ld = 288; cb = (ct - 54) * 32; }
    const int r0 = rt * 64;

    const float4* xsrc = (const float4*)(x + (size_t)r0 * FF);
#pragma unroll
    for (int k = 0; k < 8; ++k) {
        int idx = tid + k * 256;
        float4 v = xsrc[idx];
        int row = idx >> 5, c4 = (idx & 31) * 4;
        float* d = &xs[row * 132 + c4];
        d[0] = v.x; d[1] = v.y; d[2] = v.z; d[3] = v.w;
    }
    __syncthreads();

    const int cq = (tid & 7) * 4;
    const int rr = (tid >> 3) * 2;
    const float* Wp = W + cb + cq;
    const float* xr0 = &xs[rr * 132];
    const float* xr1 = &xs[(rr + 1) * 132];
    float a00=0,a01=0,a02=0,a03=0, a10=0,a11=0,a12=0,a13=0;
#pragma unroll 8
    for (int f = 0; f < FF; ++f) {
        const float4 w = *(const float4*)(Wp + (size_t)f * ld);
        float xa = xr0[f], xb = xr1[f];
        a00 = fmaf(xa, w.x, a00); a01 = fmaf(xa, w.y, a01);
        a02 = fmaf(xa, w.z, a02); a03 = fmaf(xa, w.w, a03);
        a10 = fmaf(xb, w.x, a10); a11 = fmaf(xb, w.y, a11);
        a12 = fmaf(xb, w.z, a12); a13 = fmaf(xb, w.w, a13);
    }
    float* o0 = O + (size_t)(r0 + rr) * ld + cb + cq;
    float* o1 = o0 + ld;
    o0[0]=a00; o0[1]=a01; o0[2]=a02; o0[3]=a03;
    o1[0]=a10; o1[1]=a11; o1[2]=a12; o1[3]=a13;
}

// ---------------- K3: node+spatial logits; rigid transform + norms inlined ----------------
// grid (6 it, 6 jt, 12 h), 256 thr. A[32+c]=qp_g*c2 (scale on A), B raw; k56: qn*c3 x 1; k57: 1 x kn*c3.
__global__ void __launch_bounds__(256) k3_node(
    const float* __restrict__ qb, const float* __restrict__ kb,
    const float* __restrict__ qpl, const float* __restrict__ kpl,
    const float* __restrict__ R, const float* __restrict__ t,
    const float* __restrict__ spc, float* __restrict__ lgN) {
    const int it = blockIdx.x, jt = blockIdx.y, h = blockIdx.z;
    const int tid = threadIdx.x;
    __shared__ float As[64 * 60];
    __shared__ float Bs[64 * 60];
    __shared__ float pnA[512], pnB[512];
    const float g = log1pf(expf(spc[h]));
    const float s3 = 0.5773502691896258f;
    const float c1 = s3 * 0.17677669529663687f;
    const float c2 = s3 * g * (1.f / 6.f);
    const float c3 = -s3 * g * (1.f / 12.f);
    const int i0 = it * 64, j0 = jt * 64;

    // node part
    for (int idx = tid; idx < 2048; idx += 256) {
        int r = idx >> 5, c = idx & 31;
        As[r*60 + c] = qb[(size_t)(i0 + r) * HQK + h*32 + c];
        Bs[r*60 + c] = kb[(size_t)(j0 + r) * HQK + h*32 + c] * c1;
    }
    // point part: transform local -> global on load; per-point norms
    for (int idx = tid; idx < 1024; idx += 256) {
        const int side = idx >> 9, rem = idx & 511;
        const int r = rem >> 3, p = rem & 7;
        const int row = (side ? j0 : i0) + r;
        const float* P = side ? kpl : qpl;
        const float* lp = P + (size_t)row * HP3 + (h*8 + p) * 3;
        float l0 = lp[0], l1 = lp[1], l2 = lp[2];
        float g0 = fmaf(R[row*9+0], l0, fmaf(R[row*9+1], l1, fmaf(R[row*9+2], l2, t[row*3+0])));
        float g1 = fmaf(R[row*9+3], l0, fmaf(R[row*9+4], l1, fmaf(R[row*9+5], l2, t[row*3+1])));
        float g2 = fmaf(R[row*9+6], l0, fmaf(R[row*9+7], l1, fmaf(R[row*9+8], l2, t[row*3+2])));
        float nn = g0*g0 + g1*g1 + g2*g2;
        if (side == 0) {
            float* d = &As[r*60 + 32 + p*3];
            d[0] = g0 * c2; d[1] = g1 * c2; d[2] = g2 * c2;
            pnA[r*8 + p] = nn;
        } else {
            float* d = &Bs[r*60 + 32 + p*3];
            d[0] = g0; d[1] = g1; d[2] = g2;
            pnB[r*8 + p] = nn;
        }
    }
    __syncthreads();
    if (tid < 64) {
        float s = 0.f;
#pragma unroll
        for (int p = 0; p < 8; ++p) s += pnA[tid*8 + p];
        As[tid*60 + 56] = s * c3;
        As[tid*60 + 57] = 1.f;
        As[tid*60 + 58] = 0.f; As[tid*60 + 59] = 0.f;
    } else if (tid < 128) {
        const int r = tid - 64;
        float s = 0.f;
#pragma unroll
        for (int p = 0; p < 8; ++p) s += pnB[r*8 + p];
        Bs[r*60 + 56] = 1.f;
        Bs[r*60 + 57] = s * c3;
        Bs[r*60 + 58] = 0.f; Bs[r*60 + 59] = 0.f;
    }
    __syncthreads();

    const int tx = tid & 15, ty = tid >> 4;
    float acc[4][4] = {};
    for (int k4 = 0; k4 < 60; k4 += 4) {
        float4 a[4], b[4];
#pragma unroll
        for (int r = 0; r < 4; ++r) a[r] = *(const float4*)&As[(ty*4 + r)*60 + k4];
#pragma unroll
        for (int c = 0; c < 4; ++c) b[c] = *(const float4*)&Bs[(tx*4 + c)*60 + k4];
#pragma unroll
        for (int r = 0; r < 4; ++r)
#pragma unroll
            for (int c = 0; c < 4; ++c) {
                acc[r][c] = fmaf(a[r].x, b[c].x, acc[r][c]);
                acc[r][c] = fmaf(a[r].y, b[c].y, acc[r][c]);
                acc[r][c] = fmaf(a[r].z, b[c].z, acc[r][c]);
                acc[r][c] = fmaf(a[r].w, b[c].w, acc[r][c]);
            }
    }
#pragma unroll
    for (int r = 0; r < 4; ++r)
        *(float4*)&lgN[((size_t)(i0 + ty*4 + r) * NH + h) * LL + j0 + tx*4] =
            make_float4(acc[r][0], acc[r][1], acc[r][2], acc[r][3]);
}

// ---------------- K4a: pair term + softmax + p2n; z bf16 in LDS, red aliased ----------------
__global__ void __launch_bounds__(512, 4) k4a_fused(
    const float* __restrict__ z, const float* __restrict__ Wpb,
    float* __restrict__ lgA, float* __restrict__ feat) {
    const int i = blockIdx.x, tid = threadIdx.x;
    __shared__ __align__(16) unsigned char zu[384 * 68 * 2];
    unsigned short* z_s = (unsigned short*)zu;
    float* red = (float*)zu;
    __shared__ float a_s[NH * 384];

    const float4* zsrc = (const float4*)(z + (size_t)i * (LL * CC));
#pragma unroll
    for (int k = 0; k < 12; ++k) {
        int idx = tid + k * 512;
        float4 v = zsrc[idx];
        int j = idx >> 4, c4 = idx & 15;
        ushort4 pk;
        pk.x = f2bf(v.x); pk.y = f2bf(v.y); pk.z = f2bf(v.z); pk.w = f2bf(v.w);
        *(ushort4*)&z_s[j * 68 + c4 * 4] = pk;
    }
    __syncthreads();

    if (tid < 384) {
        const int j = tid;
        float pacc[12] = {};
        const unsigned short* zrow = &z_s[j * 68];
        for (int c = 0; c < CC; ++c) {
            float zc = bf2f(zrow[c]);
#pragma unroll
            for (int hh = 0; hh < 12; ++hh)
                pacc[hh] = fmaf(zc, Wpb[c * NH + hh], pacc[hh]);
        }
        const float s3 = 0.5773502691896258f;
#pragma unroll
        for (int hh = 0; hh < 12; ++hh)
            a_s[hh * 384 + j] = lgA[((size_t)i * NH + hh) * LL + j] + pacc[hh] * s3;
    }
    __syncthreads();

    const int wv = tid >> 6, lane = tid & 63;
    if (wv < 6) {
#pragma unroll
        for (int rr = 0; rr < 2; ++rr) {
            const int h = wv * 2 + rr;
            float v[6];
#pragma unroll
            for (int k = 0; k < 6; ++k) v[k] = a_s[h * 384 + lane + k * 64];
            float m = v[0];
#pragma unroll
            for (int k = 1; k < 6; ++k) m = fmaxf(m, v[k]);
#pragma unroll
            for (int off = 32; off; off >>= 1) m = fmaxf(m, __shfl_xor(m, off));
            float s = 0.f;
#pragma unroll
            for (int k = 0; k < 6; ++k) { v[k] = expf(v[k] - m); s += v[k]; }
#pragma unroll
            for (int off = 32; off; off >>= 1) s += __shfl_xor(s, off);
            float inv = 1.f / s;
#pragma unroll
            for (int k = 0; k < 6; ++k) {
                float a = v[k] * inv;
                a_s[h * 384 + lane + k * 64] = a;
                lgA[((size_t)i * NH + h) * LL + lane + k * 64] = a;
            }
        }
    }
    __syncthreads();

    const int c4 = tid & 15, jc = tid >> 4;
    float4 acc[12] = {};
    const int jbase = jc * 12;
#pragma unroll
    for (int j4 = 0; j4 < 3; ++j4) {
        const int j = jbase + j4 * 4;
        float zv[4][4];
#pragma unroll
        for (int jj = 0; jj < 4; ++jj) {
            ushort4 zz = *(const ushort4*)&z_s[(j + jj) * 68 + c4 * 4];
            zv[jj][0] = bf2f(zz.x); zv[jj][1] = bf2f(zz.y);
            zv[jj][2] = bf2f(zz.z); zv[jj][3] = bf2f(zz.w);
        }
#pragma unroll
        for (int hh = 0; hh < 12; ++hh) {
            float4 a4 = *(const float4*)&a_s[hh * 384 + j];
            acc[hh].x = fmaf(a4.x, zv[0][0], acc[hh].x); acc[hh].y = fmaf(a4.x, zv[0][1], acc[hh].y);
            acc[hh].z = fmaf(a4.x, zv[0][2], acc[hh].z); acc[hh].w = fmaf(a4.x, zv[0][3], acc[hh].w);
            acc[hh].x = fmaf(a4.y, zv[1][0], acc[hh].x); acc[hh].y = fmaf(a4.y, zv[1][1], acc[hh].y);
            acc[hh].z = fmaf(a4.y, zv[1][2], acc[hh].z); acc[hh].w = fmaf(a4.y, zv[1][3], acc[hh].w);
            acc[hh].x = fmaf(a4.z, zv[2][0], acc[hh].x); acc[hh].y = fmaf(a4.z, zv[2][1], acc[hh].y);
            acc[hh].z = fmaf(a4.z, zv[2][2], acc[hh].z); acc[hh].w = fmaf(a4.z, zv[2][3], acc[hh].w);
            acc[hh].x = fmaf(a4.w, zv[3][0], acc[hh].x); acc[hh].y = fmaf(a4.w, zv[3][1], acc[hh].y);
            acc[hh].z = fmaf(a4.w, zv[3][2], acc[hh].z); acc[hh].w = fmaf(a4.w, zv[3][3], acc[hh].w);
        }
    }
    __syncthreads();   // z_s reads done; red aliases z_s
#pragma unroll
    for (int hh = 0; hh < 12; ++hh) {
        acc[hh].x += __shfl_xor(acc[hh].x, 16); acc[hh].y += __shfl_xor(acc[hh].y, 16);
        acc[hh].z += __shfl_xor(acc[hh].z, 16); acc[hh].w += __shfl_xor(acc[hh].w, 16);
        acc[hh].x += __shfl_xor(acc[hh].x, 32); acc[hh].y += __shfl_xor(acc[hh].y, 32);
        acc[hh].z += __shfl_xor(acc[hh].z, 32); acc[hh].w += __shfl_xor(acc[hh].w, 32);
    }
    if (lane < 16) {
#pragma unroll
        for (int hh = 0; hh < 12; ++hh)
            *(float4*)&red[wv * 768 + hh * 64 + lane * 4] = acc[hh];
    }
    __syncthreads();
    if (tid < 192) {
        int hh = tid >> 4, cc = tid & 15;
        float4 s = make_float4(0.f, 0.f, 0.f, 0.f);
#pragma unroll
        for (int w = 0; w < 8; ++w) {
            float4 p = *(const float4*)&red[w * 768 + hh * 64 + cc * 4];
            s.x += p.x; s.y += p.y; s.z += p.z; s.w += p.w;
        }
        *(float4*)&feat[(size_t)i * DOUT + hh * 64 + cc * 4] = s;
    }
}

// ---------------- K4b: node+vp aggregation (vp transform inlined) + frame transform ----------------
__global__ void __launch_bounds__(256) k4b_aggr(
    const float* __restrict__ alpha, const float* __restrict__ vb,
    const float* __restrict__ vpl, const float* __restrict__ R,
    const float* __restrict__ t, float* __restrict__ feat) {
    const int it = blockIdx.x, h = blockIdx.y;
    const int tid = threadIdx.x;
    __shared__ float bs[128 * 57];
    __shared__ float sa[16][24];
    const int i0 = it * 16;
    const int wv = __builtin_amdgcn_readfirstlane(tid >> 6);
    const int n = tid & 63;
    const float* arow0 = alpha + ((size_t)(i0 + wv * 4) * NH + h) * LL;

    float acc[4] = {};
    for (int tile = 0; tile < 3; ++tile) {
        const int j0 = tile * 128;
        __syncthreads();
        for (int idx = tid; idx < 2048; idx += 256) {
            if (idx < 1024) {   // vb chunks
                int jr = idx >> 3, q = idx & 7;
                const float* src = vb + (size_t)(j0 + jr) * HV + h * 32 + q * 4;
                float* d = &bs[jr * 57 + q * 4];
                d[0] = src[0]; d[1] = src[1]; d[2] = src[2]; d[3] = src[3];
            } else {            // vp points: transform local -> global
                int id2 = idx - 1024;
                int jr = id2 >> 3, p = id2 & 7;
                const int row = j0 + jr;
                const float* lp = vpl + (size_t)row * HP3 + (h*8 + p) * 3;
                float l0 = lp[0], l1 = lp[1], l2 = lp[2];
                float g0 = fmaf(R[row*9+0], l0, fmaf(R[row*9+1], l1, fmaf(R[row*9+2], l2, t[row*3+0])));
                float g1 = fmaf(R[row*9+3], l0, fmaf(R[row*9+4], l1, fmaf(R[row*9+5], l2, t[row*3+1])));
                float g2 = fmaf(R[row*9+6], l0, fmaf(R[row*9+7], l1, fmaf(R[row*9+8], l2, t[row*3+2])));
                float* d = &bs[jr * 57 + 32 + p * 3];
                d[0] = g0; d[1] = g1; d[2] = g2;
            }
        }
        __syncthreads();
        if (n < 56) {
            for (int j4 = 0; j4 < 32; ++j4) {
                float bv0 = bs[(j4*4+0)*57 + n];
                float bv1 = bs[(j4*4+1)*57 + n];
                float bv2 = bs[(j4*4+2)*57 + n];
                float bv3 = bs[(j4*4+3)*57 + n];
#pragma unroll
                for (int r = 0; r < 4; ++r) {
                    const float* ar = arow0 + (size_t)r * (NH * LL) + j0 + j4 * 4;
                    acc[r] = fmaf(ar[0], bv0, acc[r]);
                    acc[r] = fmaf(ar[1], bv1, acc[r]);
                    acc[r] = fmaf(ar[2], bv2, acc[r]);
                    acc[r] = fmaf(ar[3], bv3, acc[r]);
                }
            }
        }
    }
    __syncthreads();
    if (n < 56) {
        if (n < 32) {
#pragma unroll
            for (int r = 0; r < 4; ++r) {
                int i = i0 + wv * 4 + r;
                feat[(size_t)i * DOUT + 768 + h * 32 + n] = acc[r];
            }
        } else {
#pragma unroll
            for (int r = 0; r < 4; ++r)
                sa[wv * 4 + r][n - 32] = acc[r];
        }
    }
    __syncthreads();
    if (tid < 128) {
        const int ri = tid >> 3, p = tid & 7;
        const int i = i0 + ri;
        const int pt = h * 8 + p;
        float a0 = sa[ri][p*3+0], a1 = sa[ri][p*3+1], a2 = sa[ri][p*3+2];
        float d0 = a0 - t[i*3+0], d1 = a1 - t[i*3+1], d2 = a2 - t[i*3+2];
        float f0 = R[i*9+0]*d0 + R[i*9+3]*d1 + R[i*9+6]*d2;
        float f1 = R[i*9+1]*d0 + R[i*9+4]*d1 + R[i*9+7]*d2;
        float f2 = R[i*9+2]*d0 + R[i*9+5]*d1 + R[i*9+8]*d2;
        float dist = sqrtf(f0*f0 + f1*f1 + f2*f2);
        float inv = 1.f / (dist + 1e-4f);
        float* fr = feat + (size_t)i * DOUT;
        fr[1152 + pt*3+0] = f0; fr[1152 + pt*3+1] = f1; fr[1152 + pt*3+2] = f2;
        fr[1440 + pt] = dist;
        fr[1536 + pt*3+0] = f0*inv; fr[1536 + pt*3+1] = f1*inv; fr[1536 + pt*3+2] = f2*inv;
    }
}

// ---------------- K5a: out-projection split-K GEMM ----------------
__global__ void __launch_bounds__(512) k5a_outproj(
    const float* __restrict__ feat, const float* __restrict__ Wout,
    float* __restrict__ partial) {
    const int mt = blockIdx.x, ks = blockIdx.y, tid = threadIdx.x;
    __shared__ float As[32 * 153];
    const int m0 = mt * 32, k0 = ks * 152;

    for (int idx = tid; idx < 32 * 38; idx += 512) {
        int r = idx / 38, c4 = idx % 38;
        float4 v = *(const float4*)&feat[(size_t)(m0 + r) * DOUT + k0 + c4 * 4];
        float* d = &As[r * 153 + c4 * 4];
        d[0] = v.x; d[1] = v.y; d[2] = v.z; d[3] = v.w;
    }
    __syncthreads();

    const int f0 = (tid & 31) * 4;
    const int r0 = (tid >> 5) * 2;
    const float* ar0 = &As[r0 * 153];
    const float* ar1 = &As[(r0 + 1) * 153];
    const float* wp = Wout + (size_t)k0 * FF + f0;
    float a00=0,a01=0,a02=0,a03=0, a10=0,a11=0,a12=0,a13=0;
#pragma unroll 4
    for (int k = 0; k < 152; ++k) {
        float4 w = *(const float4*)(wp + (size_t)k * FF);
        float xa = ar0[k], xb = ar1[k];
        a00 = fmaf(xa, w.x, a00); a01 = fmaf(xa, w.y, a01);
        a02 = fmaf(xa, w.z, a02); a03 = fmaf(xa, w.w, a03);
        a10 = fmaf(xb, w.x, a10); a11 = fmaf(xb, w.y, a11);
        a12 = fmaf(xb, w.z, a12); a13 = fmaf(xb, w.w, a13);
    }
    float* o0 = partial + ((size_t)ks * LL + m0 + r0) * FF + f0;
    *(float4*)o0 = make_float4(a00, a01, a02, a03);
    *(float4*)(o0 + FF) = make_float4(a10, a11, a12, a13);
}

// ---------------- K5b: per-row LN1 + MLP + LN2 ----------------
__global__ void __launch_bounds__(256) k5b_rowepi(
    const float* __restrict__ partial, const float* __restrict__ bout,
    const float* __restrict__ x,
    const float* __restrict__ ln1g, const float* __restrict__ ln1b,
    const float* __restrict__ W1, const float* __restrict__ b1,
    const float* __restrict__ W2, const float* __restrict__ b2,
    const float* __restrict__ W3, const float* __restrict__ b3,
    const float* __restrict__ ln2g, const float* __restrict__ ln2b,
    float* __restrict__ out) {
    const int i = blockIdx.x, tid = threadIdx.x;
    const int f = tid & 127, half = tid >> 7;
    __shared__ float prt[2][128];
    __shared__ float x1s[128], hbA[128], hbB[128];
    __shared__ float wrA[2], wrB[2];

    {
        float acc = 0.f;
#pragma unroll
        for (int k = 0; k < 6; ++k)
            acc += partial[((size_t)(half * 6 + k) * LL + i) * FF + f];
        prt[half][f] = acc;
    }
    __syncthreads();

    float s1 = 0.f, dv1 = 0.f;
    if (tid < 128) {
        s1 = prt[0][f] + prt[1][f] + bout[f] + x[(size_t)i * FF + f];
        float r = s1;
#pragma unroll
        for (int off = 32; off; off >>= 1) r += __shfl_xor(r, off);
        if ((tid & 63) == 0) wrA[tid >> 6] = r;
    }
    __syncthreads();
    if (tid < 128) {
        float mu = (wrA[0] + wrA[1]) * (1.f / FF);
        dv1 = s1 - mu;
        float r = dv1 * dv1;
#pragma unroll
        for (int off = 32; off; off >>= 1) r += __shfl_xor(r, off);
        if ((tid & 63) == 0) wrB[tid >> 6] = r;
    }
    __syncthreads();
    if (tid < 128) {
        float var = (wrB[0] + wrB[1]) * (1.f / FF);
        x1s[f] = dv1 * rsqrtf(var + 1e-5f) * ln1g[f] + ln1b[f];
    }
    __syncthreads();

    {
        float p0=0,p1=0,p2=0,p3=0;
        const int k0 = half * 64;
        for (int k = 0; k < 16; ++k) {
            int d = k0 + k * 4;
            p0 = fmaf(x1s[d+0], W1[(size_t)(d+0)*FF + f], p0);
            p1 = fmaf(x1s[d+1], W1[(size_t)(d+1)*FF + f], p1);
            p2 = fmaf(x1s[d+2], W1[(size_t)(d+2)*FF + f], p2);
            p3 = fmaf(x1s[d+3], W1[(size_t)(d+3)*FF + f], p3);
        }
        prt[half][f] = p0 + p1 + p2 + p3;
    }
    __syncthreads();
    if (tid < 128) hbA[f] = fmaxf(prt[0][f] + prt[1][f] + b1[f], 0.f);
    __syncthreads();
    {
        float p0=0,p1=0,p2=0,p3=0;
        const int k0 = half * 64;
        for (int k = 0; k < 16; ++k) {
            int d = k0 + k * 4;
            p0 = fmaf(hbA[d+0], W2[(size_t)(d+0)*FF + f], p0);
            p1 = fmaf(hbA[d+1], W2[(size_t)(d+1)*FF + f], p1);
            p2 = fmaf(hbA[d+2], W2[(size_t)(d+2)*FF + f], p2);
            p3 = fmaf(hbA[d+3], W2[(size_t)(d+3)*FF + f], p3);
        }
        prt[half][f] = p0 + p1 + p2 + p3;
    }
    __syncthreads();
    if (tid < 128) hbB[f] = fmaxf(prt[0][f] + prt[1][f] + b2[f], 0.f);
    __syncthreads();
    {
        float p0=0,p1=0,p2=0,p3=0;
        const int k0 = half * 64;
        for (int k = 0; k < 16; ++k) {
            int d = k0 + k * 4;
            p0 = fmaf(hbB[d+0], W3[(size_t)(d+0)*FF + f], p0);
            p1 = fmaf(hbB[d+1], W3[(size_t)(d+1)*FF + f], p1);
            p2 = fmaf(hbB[d+2], W3[(size_t)(d+2)*FF + f], p2);
            p3 = fmaf(hbB[d+3], W3[(size_t)(d+3)*FF + f], p3);
        }
        prt[half][f] = p0 + p1 + p2 + p3;
    }
    __syncthreads();

    float s2 = 0.f, dv2 = 0.f;
    if (tid < 128) {
        s2 = x1s[f] + prt[0][f] + prt[1][f] + b3[f];
        float r = s2;
#pragma unroll
        for (int off = 32; off; off >>= 1) r += __shfl_xor(r, off);
        if ((tid & 63) == 0) wrA[tid >> 6] = r;
    }
    __syncthreads();
    if (tid < 128) {
        float mu = (wrA[0] + wrA[1]) * (1.f / FF);
        dv2 = s2 - mu;
        float r = dv2 * dv2;
#pragma unroll
        for (int off = 32; off; off >>= 1) r += __shfl_xor(r, off);
        if ((tid & 63) == 0) wrB[tid >> 6] = r;
    }
    __syncthreads();
    if (tid < 128) {
        float var = (wrB[0] + wrB[1]) * (1.f / FF);
        out[(size_t)i * FF + f] = dv2 * rsqrtf(var + 1e-5f) * ln2g[f] + ln2b[f];
    }
}

extern "C" void kernel_launch(void* const* d_in, const int* in_sizes, int n_in,
                              void* d_out, int out_size, void* d_ws, size_t ws_size,
                              hipStream_t stream) {
    const float* R    = (const float*)d_in[0];
    const float* t    = (const float*)d_in[1];
    const float* x    = (const float*)d_in[2];
    const float* z    = (const float*)d_in[3];
    const float* Wq   = (const float*)d_in[5];
    const float* Wk   = (const float*)d_in[6];
    const float* Wv   = (const float*)d_in[7];
    const float* Wpb  = (const float*)d_in[8];
    const float* spc  = (const float*)d_in[9];
    const float* Wqp  = (const float*)d_in[10];
    const float* Wkp  = (const float*)d_in[11];
    const float* Wvp  = (const float*)d_in[12];
    const float* Wout = (const float*)d_in[13];
    const float* bout = (const float*)d_in[14];
    const float* ln1g = (const float*)d_in[15];
    const float* ln1b = (const float*)d_in[16];
    const float* W1   = (const float*)d_in[17];
    const float* b1   = (const float*)d_in[18];
    const float* W2   = (const float*)d_in[19];
    const float* b2   = (const float*)d_in[20];
    const float* W3   = (const float*)d_in[21];
    const float* b3   = (const float*)d_in[22];
    const float* ln2g = (const float*)d_in[23];
    const float* ln2b = (const float*)d_in[24];
    float* out = (float*)d_out;

    float* ws = (float*)d_ws;
    float* qb   = ws;
    float* kb   = qb   + (size_t)LL * HQK;
    float* vb   = kb   + (size_t)LL * HQK;
    float* qpl  = vb   + (size_t)LL * HV;       // raw local coords
    float* kpl  = qpl  + (size_t)LL * HP3;
    float* vpl  = kpl  + (size_t)LL * HP3;
    float* lgA  = vpl  + (size_t)LL * HP3;      // [384][12][384] logits -> alpha
    float* feat = lgA  + (size_t)LL * NH * LL;  // [384][1824]
    float* part = feat + (size_t)LL * DOUT;     // [12][384][128]; also prefetch dump

    k1a_gemm<<<442, 256, 0, stream>>>(x, z, Wq, Wk, Wv, Wqp, Wkp, Wvp,
                                      qb, kb, vb, qpl, kpl, vpl, part);
    k3_node<<<dim3(6, 6, 12), 256, 0, stream>>>(qb, kb, qpl, kpl, R, t, spc, lgA);
    k4a_fused<<<LL, 512, 0, stream>>>(z, Wpb, lgA, feat);
    k4b_aggr<<<dim3(24, 12), 256, 0, stream>>>(lgA, vb, vpl, R, t, feat);
    k5a_outproj<<<dim3(12, 12), 512, 0, stream>>>(feat, Wout, part);
    k5b_rowepi<<<LL, 256, 0, stream>>>(part, bout, x, ln1g, ln1b,
                                       W1, b1, W2, b2, W3, b3, ln2g, ln2b, out);
}

// Round 9
// 107.736 us; speedup vs baseline: 6.5240x; 1.0032x over previous
//
#include <hip/hip_runtime.h>
#include <math.h>

constexpr int LL   = 384;
constexpr int FF   = 128;
constexpr int NH   = 12;
constexpr int HQK  = 384;
constexpr int HV   = 384;
constexpr int HP3  = 288;
constexpr int NPT  = 96;
constexpr int CC   = 64;
constexpr int DOUT = 1824;
constexpr int KS   = 24;    // out-proj split-K slices
constexpr int KSL  = 76;    // slice length (24*76 = 1824)

__device__ inline unsigned short f2bf(float f) {
    unsigned int u = __float_as_uint(f);
    return (unsigned short)((u + 0x7fff + ((u >> 16) & 1)) >> 16);
}
__device__ inline float bf2f(unsigned short s) {
    return __uint_as_float(((unsigned int)s) << 16);
}

// ---------------- K1a: six projections + z L3-prefetch (256 blocks) ----------------
// grid: 0..377 GEMM jobs; 378..633 z prefetch (147KB each -> BW-bound ~6us, hidden under GEMM).
__global__ void __launch_bounds__(256) k1a_gemm(
    const float* __restrict__ x, const float* __restrict__ z,
    const float* __restrict__ Wq, const float* __restrict__ Wk, const float* __restrict__ Wv,
    const float* __restrict__ Wqp, const float* __restrict__ Wkp, const float* __restrict__ Wvp,
    float* __restrict__ qb, float* __restrict__ kb, float* __restrict__ vb,
    float* __restrict__ qpl, float* __restrict__ kpl, float* __restrict__ vpl,
    float* __restrict__ dump) {
    const int bid = blockIdx.x, tid = threadIdx.x;
    if (bid >= 378) {   // z prefetch -> warm L3 (z = 37.7MB fits 256MB Infinity Cache)
        const int pid = bid - 378;
        const float4* src = (const float4*)z + (size_t)pid * 9216;
        float4 s = make_float4(0.f, 0.f, 0.f, 0.f);
#pragma unroll 4
        for (int k = 0; k < 36; ++k) {
            float4 v = src[tid + k * 256];
            s.x += v.x; s.y += v.y; s.z += v.z; s.w += v.w;
        }
        dump[pid * 256 + tid] = s.x + s.y + s.z + s.w;  // part buffer; k5a overwrites fully
        return;
    }
    const int ct = bid % 63, rt = bid / 63;
    __shared__ float xs[64 * 132];

    const float* W; float* O; int ld, cb;
    if (ct < 12)      { W = Wq;  O = qb;  ld = 384; cb = ct * 32; }
    else if (ct < 24) { W = Wk;  O = kb;  ld = 384; cb = (ct - 12) * 32; }
    else if (ct < 36) { W = Wv;  O = vb;  ld = 384; cb = (ct - 24) * 32; }
    else if (ct < 45) { W = Wqp; O = qpl; ld = 288; cb = (ct - 36) * 32; }
    else if (ct < 54) { W = Wkp; O = kpl; ld = 288; cb = (ct - 45) * 32; }
    else              { W = Wvp; O = vpl; ld = 288; cb = (ct - 54) * 32; }
    const int r0 = rt * 64;

    const float4* xsrc = (const float4*)(x + (size_t)r0 * FF);
#pragma unroll
    for (int k = 0; k < 8; ++k) {
        int idx = tid + k * 256;
        float4 v = xsrc[idx];
        int row = idx >> 5, c4 = (idx & 31) * 4;
        float* d = &xs[row * 132 + c4];
        d[0] = v.x; d[1] = v.y; d[2] = v.z; d[3] = v.w;
    }
    __syncthreads();

    const int cq = (tid & 7) * 4;
    const int rr = (tid >> 3) * 2;
    const float* Wp = W + cb + cq;
    const float* xr0 = &xs[rr * 132];
    const float* xr1 = &xs[(rr + 1) * 132];
    float a00=0,a01=0,a02=0,a03=0, a10=0,a11=0,a12=0,a13=0;
#pragma unroll 8
    for (int f = 0; f < FF; ++f) {
        const float4 w = *(const float4*)(Wp + (size_t)f * ld);
        float xa = xr0[f], xb = xr1[f];
        a00 = fmaf(xa, w.x, a00); a01 = fmaf(xa, w.y, a01);
        a02 = fmaf(xa, w.z, a02); a03 = fmaf(xa, w.w, a03);
        a10 = fmaf(xb, w.x, a10); a11 = fmaf(xb, w.y, a11);
        a12 = fmaf(xb, w.z, a12); a13 = fmaf(xb, w.w, a13);
    }
    float* o0 = O + (size_t)(r0 + rr) * ld + cb + cq;
    float* o1 = o0 + ld;
    o0[0]=a00; o0[1]=a01; o0[2]=a02; o0[3]=a03;
    o1[0]=a10; o1[1]=a11; o1[2]=a12; o1[3]=a13;
}

// ---------------- K3: node+spatial logits; rigid transform + norms inlined ----------------
__global__ void __launch_bounds__(256) k3_node(
    const float* __restrict__ qb, const float* __restrict__ kb,
    const float* __restrict__ qpl, const float* __restrict__ kpl,
    const float* __restrict__ R, const float* __restrict__ t,
    const float* __restrict__ spc, float* __restrict__ lgN) {
    const int it = blockIdx.x, jt = blockIdx.y, h = blockIdx.z;
    const int tid = threadIdx.x;
    __shared__ float As[64 * 60];
    __shared__ float Bs[64 * 60];
    __shared__ float pnA[512], pnB[512];
    const float g = log1pf(expf(spc[h]));
    const float s3 = 0.5773502691896258f;
    const float c1 = s3 * 0.17677669529663687f;
    const float c2 = s3 * g * (1.f / 6.f);
    const float c3 = -s3 * g * (1.f / 12.f);
    const int i0 = it * 64, j0 = jt * 64;

    for (int idx = tid; idx < 2048; idx += 256) {
        int r = idx >> 5, c = idx & 31;
        As[r*60 + c] = qb[(size_t)(i0 + r) * HQK + h*32 + c];
        Bs[r*60 + c] = kb[(size_t)(j0 + r) * HQK + h*32 + c] * c1;
    }
    for (int idx = tid; idx < 1024; idx += 256) {
        const int side = idx >> 9, rem = idx & 511;
        const int r = rem >> 3, p = rem & 7;
        const int row = (side ? j0 : i0) + r;
        const float* P = side ? kpl : qpl;
        const float* lp = P + (size_t)row * HP3 + (h*8 + p) * 3;
        float l0 = lp[0], l1 = lp[1], l2 = lp[2];
        float g0 = fmaf(R[row*9+0], l0, fmaf(R[row*9+1], l1, fmaf(R[row*9+2], l2, t[row*3+0])));
        float g1 = fmaf(R[row*9+3], l0, fmaf(R[row*9+4], l1, fmaf(R[row*9+5], l2, t[row*3+1])));
        float g2 = fmaf(R[row*9+6], l0, fmaf(R[row*9+7], l1, fmaf(R[row*9+8], l2, t[row*3+2])));
        float nn = g0*g0 + g1*g1 + g2*g2;
        if (side == 0) {
            float* d = &As[r*60 + 32 + p*3];
            d[0] = g0 * c2; d[1] = g1 * c2; d[2] = g2 * c2;
            pnA[r*8 + p] = nn;
        } else {
            float* d = &Bs[r*60 + 32 + p*3];
            d[0] = g0; d[1] = g1; d[2] = g2;
            pnB[r*8 + p] = nn;
        }
    }
    __syncthreads();
    if (tid < 64) {
        float s = 0.f;
#pragma unroll
        for (int p = 0; p < 8; ++p) s += pnA[tid*8 + p];
        As[tid*60 + 56] = s * c3;
        As[tid*60 + 57] = 1.f;
        As[tid*60 + 58] = 0.f; As[tid*60 + 59] = 0.f;
    } else if (tid < 128) {
        const int r = tid - 64;
        float s = 0.f;
#pragma unroll
        for (int p = 0; p < 8; ++p) s += pnB[r*8 + p];
        Bs[r*60 + 56] = 1.f;
        Bs[r*60 + 57] = s * c3;
        Bs[r*60 + 58] = 0.f; Bs[r*60 + 59] = 0.f;
    }
    __syncthreads();

    const int tx = tid & 15, ty = tid >> 4;
    float acc[4][4] = {};
    for (int k4 = 0; k4 < 60; k4 += 4) {
        float4 a[4], b[4];
#pragma unroll
        for (int r = 0; r < 4; ++r) a[r] = *(const float4*)&As[(ty*4 + r)*60 + k4];
#pragma unroll
        for (int c = 0; c < 4; ++c) b[c] = *(const float4*)&Bs[(tx*4 + c)*60 + k4];
#pragma unroll
        for (int r = 0; r < 4; ++r)
#pragma unroll
            for (int c = 0; c < 4; ++c) {
                acc[r][c] = fmaf(a[r].x, b[c].x, acc[r][c]);
                acc[r][c] = fmaf(a[r].y, b[c].y, acc[r][c]);
                acc[r][c] = fmaf(a[r].z, b[c].z, acc[r][c]);
                acc[r][c] = fmaf(a[r].w, b[c].w, acc[r][c]);
            }
    }
#pragma unroll
    for (int r = 0; r < 4; ++r)
        *(float4*)&lgN[((size_t)(i0 + ty*4 + r) * NH + h) * LL + j0 + tx*4] =
            make_float4(acc[r][0], acc[r][1], acc[r][2], acc[r][3]);
}

// ---------------- K4a: pair term + softmax + p2n; z bf16 in LDS, red aliased ----------------
__global__ void __launch_bounds__(512, 4) k4a_fused(
    const float* __restrict__ z, const float* __restrict__ Wpb,
    float* __restrict__ lgA, float* __restrict__ feat) {
    const int i = blockIdx.x, tid = threadIdx.x;
    __shared__ __align__(16) unsigned char zu[384 * 68 * 2];
    unsigned short* z_s = (unsigned short*)zu;
    float* red = (float*)zu;
    __shared__ float a_s[NH * 384];

    const float4* zsrc = (const float4*)(z + (size_t)i * (LL * CC));
#pragma unroll
    for (int k = 0; k < 12; ++k) {
        int idx = tid + k * 512;
        float4 v = zsrc[idx];
        int j = idx >> 4, c4 = idx & 15;
        ushort4 pk;
        pk.x = f2bf(v.x); pk.y = f2bf(v.y); pk.z = f2bf(v.z); pk.w = f2bf(v.w);
        *(ushort4*)&z_s[j * 68 + c4 * 4] = pk;
    }
    __syncthreads();

    if (tid < 384) {
        const int j = tid;
        float pacc[12] = {};
        const unsigned short* zrow = &z_s[j * 68];
#pragma unroll
        for (int c4 = 0; c4 < 16; ++c4) {
            ushort4 zz = *(const ushort4*)&zrow[c4 * 4];
            float z0 = bf2f(zz.x), z1 = bf2f(zz.y), z2 = bf2f(zz.z), z3 = bf2f(zz.w);
            const float* wp = Wpb + c4 * 4 * NH;
#pragma unroll
            for (int hh = 0; hh < 12; ++hh) {
                float p = pacc[hh];
                p = fmaf(z0, wp[hh], p);
                p = fmaf(z1, wp[NH + hh], p);
                p = fmaf(z2, wp[2*NH + hh], p);
                p = fmaf(z3, wp[3*NH + hh], p);
                pacc[hh] = p;
            }
        }
        const float s3 = 0.5773502691896258f;
#pragma unroll
        for (int hh = 0; hh < 12; ++hh)
            a_s[hh * 384 + j] = lgA[((size_t)i * NH + hh) * LL + j] + pacc[hh] * s3;
    }
    __syncthreads();

    const int wv = tid >> 6, lane = tid & 63;
    if (wv < 6) {
#pragma unroll
        for (int rr = 0; rr < 2; ++rr) {
            const int h = wv * 2 + rr;
            float v[6];
#pragma unroll
            for (int k = 0; k < 6; ++k) v[k] = a_s[h * 384 + lane + k * 64];
            float m = v[0];
#pragma unroll
            for (int k = 1; k < 6; ++k) m = fmaxf(m, v[k]);
#pragma unroll
            for (int off = 32; off; off >>= 1) m = fmaxf(m, __shfl_xor(m, off));
            float s = 0.f;
#pragma unroll
            for (int k = 0; k < 6; ++k) { v[k] = expf(v[k] - m); s += v[k]; }
#pragma unroll
            for (int off = 32; off; off >>= 1) s += __shfl_xor(s, off);
            float inv = 1.f / s;
#pragma unroll
            for (int k = 0; k < 6; ++k) {
                float a = v[k] * inv;
                a_s[h * 384 + lane + k * 64] = a;
                lgA[((size_t)i * NH + h) * LL + lane + k * 64] = a;
            }
        }
    }
    __syncthreads();

    const int c4 = tid & 15, jc = tid >> 4;
    float4 acc[12] = {};
    const int jbase = jc * 12;
#pragma unroll
    for (int j4 = 0; j4 < 3; ++j4) {
        const int j = jbase + j4 * 4;
        float zv[4][4];
#pragma unroll
        for (int jj = 0; jj < 4; ++jj) {
            ushort4 zz = *(const ushort4*)&z_s[(j + jj) * 68 + c4 * 4];
            zv[jj][0] = bf2f(zz.x); zv[jj][1] = bf2f(zz.y);
            zv[jj][2] = bf2f(zz.z); zv[jj][3] = bf2f(zz.w);
        }
#pragma unroll
        for (int hh = 0; hh < 12; ++hh) {
            float4 a4 = *(const float4*)&a_s[hh * 384 + j];
            acc[hh].x = fmaf(a4.x, zv[0][0], acc[hh].x); acc[hh].y = fmaf(a4.x, zv[0][1], acc[hh].y);
            acc[hh].z = fmaf(a4.x, zv[0][2], acc[hh].z); acc[hh].w = fmaf(a4.x, zv[0][3], acc[hh].w);
            acc[hh].x = fmaf(a4.y, zv[1][0], acc[hh].x); acc[hh].y = fmaf(a4.y, zv[1][1], acc[hh].y);
            acc[hh].z = fmaf(a4.y, zv[1][2], acc[hh].z); acc[hh].w = fmaf(a4.y, zv[1][3], acc[hh].w);
            acc[hh].x = fmaf(a4.z, zv[2][0], acc[hh].x); acc[hh].y = fmaf(a4.z, zv[2][1], acc[hh].y);
            acc[hh].z = fmaf(a4.z, zv[2][2], acc[hh].z); acc[hh].w = fmaf(a4.z, zv[2][3], acc[hh].w);
            acc[hh].x = fmaf(a4.w, zv[3][0], acc[hh].x); acc[hh].y = fmaf(a4.w, zv[3][1], acc[hh].y);
            acc[hh].z = fmaf(a4.w, zv[3][2], acc[hh].z); acc[hh].w = fmaf(a4.w, zv[3][3], acc[hh].w);
        }
    }
    __syncthreads();   // z_s reads done; red aliases z_s
#pragma unroll
    for (int hh = 0; hh < 12; ++hh) {
        acc[hh].x += __shfl_xor(acc[hh].x, 16); acc[hh].y += __shfl_xor(acc[hh].y, 16);
        acc[hh].z += __shfl_xor(acc[hh].z, 16); acc[hh].w += __shfl_xor(acc[hh].w, 16);
        acc[hh].x += __shfl_xor(acc[hh].x, 32); acc[hh].y += __shfl_xor(acc[hh].y, 32);
        acc[hh].z += __shfl_xor(acc[hh].z, 32); acc[hh].w += __shfl_xor(acc[hh].w, 32);
    }
    if (lane < 16) {
#pragma unroll
        for (int hh = 0; hh < 12; ++hh)
            *(float4*)&red[wv * 768 + hh * 64 + lane * 4] = acc[hh];
    }
    __syncthreads();
    if (tid < 192) {
        int hh = tid >> 4, cc = tid & 15;
        float4 s = make_float4(0.f, 0.f, 0.f, 0.f);
#pragma unroll
        for (int w = 0; w < 8; ++w) {
            float4 p = *(const float4*)&red[w * 768 + hh * 64 + cc * 4];
            s.x += p.x; s.y += p.y; s.z += p.z; s.w += p.w;
        }
        *(float4*)&feat[(size_t)i * DOUT + hh * 64 + cc * 4] = s;
    }
}

// ---------------- K4b: node+vp aggregation (vp transform inlined) + frame transform ----------------
__global__ void __launch_bounds__(256) k4b_aggr(
    const float* __restrict__ alpha, const float* __restrict__ vb,
    const float* __restrict__ vpl, const float* __restrict__ R,
    const float* __restrict__ t, float* __restrict__ feat) {
    const int it = blockIdx.x, h = blockIdx.y;
    const int tid = threadIdx.x;
    __shared__ float bs[128 * 57];
    __shared__ float sa[16][24];
    const int i0 = it * 16;
    const int wv = __builtin_amdgcn_readfirstlane(tid >> 6);
    const int n = tid & 63;
    const float* arow0 = alpha + ((size_t)(i0 + wv * 4) * NH + h) * LL;

    float acc[4] = {};
    for (int tile = 0; tile < 3; ++tile) {
        const int j0 = tile * 128;
        __syncthreads();
        for (int idx = tid; idx < 2048; idx += 256) {
            if (idx < 1024) {
                int jr = idx >> 3, q = idx & 7;
                const float* src = vb + (size_t)(j0 + jr) * HV + h * 32 + q * 4;
                float* d = &bs[jr * 57 + q * 4];
                d[0] = src[0]; d[1] = src[1]; d[2] = src[2]; d[3] = src[3];
            } else {
                int id2 = idx - 1024;
                int jr = id2 >> 3, p = id2 & 7;
                const int row = j0 + jr;
                const float* lp = vpl + (size_t)row * HP3 + (h*8 + p) * 3;
                float l0 = lp[0], l1 = lp[1], l2 = lp[2];
                float g0 = fmaf(R[row*9+0], l0, fmaf(R[row*9+1], l1, fmaf(R[row*9+2], l2, t[row*3+0])));
                float g1 = fmaf(R[row*9+3], l0, fmaf(R[row*9+4], l1, fmaf(R[row*9+5], l2, t[row*3+1])));
                float g2 = fmaf(R[row*9+6], l0, fmaf(R[row*9+7], l1, fmaf(R[row*9+8], l2, t[row*3+2])));
                float* d = &bs[jr * 57 + 32 + p * 3];
                d[0] = g0; d[1] = g1; d[2] = g2;
            }
        }
        __syncthreads();
        if (n < 56) {
            for (int j4 = 0; j4 < 32; ++j4) {
                float bv0 = bs[(j4*4+0)*57 + n];
                float bv1 = bs[(j4*4+1)*57 + n];
                float bv2 = bs[(j4*4+2)*57 + n];
                float bv3 = bs[(j4*4+3)*57 + n];
#pragma unroll
                for (int r = 0; r < 4; ++r) {
                    const float* ar = arow0 + (size_t)r * (NH * LL) + j0 + j4 * 4;
                    acc[r] = fmaf(ar[0], bv0, acc[r]);
                    acc[r] = fmaf(ar[1], bv1, acc[r]);
                    acc[r] = fmaf(ar[2], bv2, acc[r]);
                    acc[r] = fmaf(ar[3], bv3, acc[r]);
                }
            }
        }
    }
    __syncthreads();
    if (n < 56) {
        if (n < 32) {
#pragma unroll
            for (int r = 0; r < 4; ++r) {
                int i = i0 + wv * 4 + r;
                feat[(size_t)i * DOUT + 768 + h * 32 + n] = acc[r];
            }
        } else {
#pragma unroll
            for (int r = 0; r < 4; ++r)
                sa[wv * 4 + r][n - 32] = acc[r];
        }
    }
    __syncthreads();
    if (tid < 128) {
        const int ri = tid >> 3, p = tid & 7;
        const int i = i0 + ri;
        const int pt = h * 8 + p;
        float a0 = sa[ri][p*3+0], a1 = sa[ri][p*3+1], a2 = sa[ri][p*3+2];
        float d0 = a0 - t[i*3+0], d1 = a1 - t[i*3+1], d2 = a2 - t[i*3+2];
        float f0 = R[i*9+0]*d0 + R[i*9+3]*d1 + R[i*9+6]*d2;
        float f1 = R[i*9+1]*d0 + R[i*9+4]*d1 + R[i*9+7]*d2;
        float f2 = R[i*9+2]*d0 + R[i*9+5]*d1 + R[i*9+8]*d2;
        float dist = sqrtf(f0*f0 + f1*f1 + f2*f2);
        float inv = 1.f / (dist + 1e-4f);
        float* fr = feat + (size_t)i * DOUT;
        fr[1152 + pt*3+0] = f0; fr[1152 + pt*3+1] = f1; fr[1152 + pt*3+2] = f2;
        fr[1440 + pt] = dist;
        fr[1536 + pt*3+0] = f0*inv; fr[1536 + pt*3+1] = f1*inv; fr[1536 + pt*3+2] = f2*inv;
    }
}

// ---------------- K5a: out-projection split-K GEMM. grid (12 mt, 24 ks), 512 thr ----------------
__global__ void __launch_bounds__(512) k5a_outproj(
    const float* __restrict__ feat, const float* __restrict__ Wout,
    float* __restrict__ partial) {
    const int mt = blockIdx.x, ks = blockIdx.y, tid = threadIdx.x;
    __shared__ float As[32 * 80];   // stride 80 (16B-aligned rows)
    const int m0 = mt * 32, k0 = ks * KSL;

    for (int idx = tid; idx < 32 * 19; idx += 512) {
        int r = idx / 19, c4 = idx % 19;
        float4 v = *(const float4*)&feat[(size_t)(m0 + r) * DOUT + k0 + c4 * 4];
        *(float4*)&As[r * 80 + c4 * 4] = v;
    }
    __syncthreads();

    const int f0 = (tid & 31) * 4;
    const int r0 = (tid >> 5) * 2;
    const float* ar0 = &As[r0 * 80];
    const float* ar1 = &As[(r0 + 1) * 80];
    const float* wp = Wout + (size_t)k0 * FF + f0;
    float a00=0,a01=0,a02=0,a03=0, a10=0,a11=0,a12=0,a13=0;
#pragma unroll 4
    for (int k = 0; k < KSL; ++k) {
        float4 w = *(const float4*)(wp + (size_t)k * FF);
        float xa = ar0[k], xb = ar1[k];
        a00 = fmaf(xa, w.x, a00); a01 = fmaf(xa, w.y, a01);
        a02 = fmaf(xa, w.z, a02); a03 = fmaf(xa, w.w, a03);
        a10 = fmaf(xb, w.x, a10); a11 = fmaf(xb, w.y, a11);
        a12 = fmaf(xb, w.z, a12); a13 = fmaf(xb, w.w, a13);
    }
    float* o0 = partial + ((size_t)ks * LL + m0 + r0) * FF + f0;
    *(float4*)o0 = make_float4(a00, a01, a02, a03);
    *(float4*)(o0 + FF) = make_float4(a10, a11, a12, a13);
}

// ---------------- K5b: per-row LN1 + MLP + LN2 ----------------
__global__ void __launch_bounds__(256) k5b_rowepi(
    const float* __restrict__ partial, const float* __restrict__ bout,
    const float* __restrict__ x,
    const float* __restrict__ ln1g, const float* __restrict__ ln1b,
    const float* __restrict__ W1, const float* __restrict__ b1,
    const float* __restrict__ W2, const float* __restrict__ b2,
    const float* __restrict__ W3, const float* __restrict__ b3,
    const float* __restrict__ ln2g, const float* __restrict__ ln2b,
    float* __restrict__ out) {
    const int i = blockIdx.x, tid = threadIdx.x;
    const int f = tid & 127, half = tid >> 7;
    __shared__ float prt[2][128];
    __shared__ float x1s[128], hbA[128], hbB[128];
    __shared__ float wrA[2], wrB[2];

    {
        float acc = 0.f;
#pragma unroll
        for (int k = 0; k < 12; ++k)
            acc += partial[((size_t)(half * 12 + k) * LL + i) * FF + f];
        prt[half][f] = acc;
    }
    __syncthreads();

    float s1 = 0.f, dv1 = 0.f;
    if (tid < 128) {
        s1 = prt[0][f] + prt[1][f] + bout[f] + x[(size_t)i * FF + f];
        float r = s1;
#pragma unroll
        for (int off = 32; off; off >>= 1) r += __shfl_xor(r, off);
        if ((tid & 63) == 0) wrA[tid >> 6] = r;
    }
    __syncthreads();
    if (tid < 128) {
        float mu = (wrA[0] + wrA[1]) * (1.f / FF);
        dv1 = s1 - mu;
        float r = dv1 * dv1;
#pragma unroll
        for (int off = 32; off; off >>= 1) r += __shfl_xor(r, off);
        if ((tid & 63) == 0) wrB[tid >> 6] = r;
    }
    __syncthreads();
    if (tid < 128) {
        float var = (wrB[0] + wrB[1]) * (1.f / FF);
        x1s[f] = dv1 * rsqrtf(var + 1e-5f) * ln1g[f] + ln1b[f];
    }
    __syncthreads();

    {
        float p0=0,p1=0,p2=0,p3=0;
        const int k0 = half * 64;
        for (int k = 0; k < 16; ++k) {
            int d = k0 + k * 4;
            p0 = fmaf(x1s[d+0], W1[(size_t)(d+0)*FF + f], p0);
            p1 = fmaf(x1s[d+1], W1[(size_t)(d+1)*FF + f], p1);
            p2 = fmaf(x1s[d+2], W1[(size_t)(d+2)*FF + f], p2);
            p3 = fmaf(x1s[d+3], W1[(size_t)(d+3)*FF + f], p3);
        }
        prt[half][f] = p0 + p1 + p2 + p3;
    }
    __syncthreads();
    if (tid < 128) hbA[f] = fmaxf(prt[0][f] + prt[1][f] + b1[f], 0.f);
    __syncthreads();
    {
        float p0=0,p1=0,p2=0,p3=0;
        const int k0 = half * 64;
        for (int k = 0; k < 16; ++k) {
            int d = k0 + k * 4;
            p0 = fmaf(hbA[d+0], W2[(size_t)(d+0)*FF + f], p0);
            p1 = fmaf(hbA[d+1], W2[(size_t)(d+1)*FF + f], p1);
            p2 = fmaf(hbA[d+2], W2[(size_t)(d+2)*FF + f], p2);
            p3 = fmaf(hbA[d+3], W2[(size_t)(d+3)*FF + f], p3);
        }
        prt[half][f] = p0 + p1 + p2 + p3;
    }
    __syncthreads();
    if (tid < 128) hbB[f] = fmaxf(prt[0][f] + prt[1][f] + b2[f], 0.f);
    __syncthreads();
    {
        float p0=0,p1=0,p2=0,p3=0;
        const int k0 = half * 64;
        for (int k = 0; k < 16; ++k) {
            int d = k0 + k * 4;
            p0 = fmaf(hbB[d+0], W3[(size_t)(d+0)*FF + f], p0);
            p1 = fmaf(hbB[d+1], W3[(size_t)(d+1)*FF + f], p1);
            p2 = fmaf(hbB[d+2], W3[(size_t)(d+2)*FF + f], p2);
            p3 = fmaf(hbB[d+3], W3[(size_t)(d+3)*FF + f], p3);
        }
        prt[half][f] = p0 + p1 + p2 + p3;
    }
    __syncthreads();

    float s2 = 0.f, dv2 = 0.f;
    if (tid < 128) {
        s2 = x1s[f] + prt[0][f] + prt[1][f] + b3[f];
        float r = s2;
#pragma unroll
        for (int off = 32; off; off >>= 1) r += __shfl_xor(r, off);
        if ((tid & 63) == 0) wrA[tid >> 6] = r;
    }
    __syncthreads();
    if (tid < 128) {
        float mu = (wrA[0] + wrA[1]) * (1.f / FF);
        dv2 = s2 - mu;
        float r = dv2 * dv2;
#pragma unroll
        for (int off = 32; off; off >>= 1) r += __shfl_xor(r, off);
        if ((tid & 63) == 0) wrB[tid >> 6] = r;
    }
    __syncthreads();
    if (tid < 128) {
        float var = (wrB[0] + wrB[1]) * (1.f / FF);
        out[(size_t)i * FF + f] = dv2 * rsqrtf(var + 1e-5f) * ln2g[f] + ln2b[f];
    }
}

extern "C" void kernel_launch(void* const* d_in, const int* in_sizes, int n_in,
                              void* d_out, int out_size, void* d_ws, size_t ws_size,
                              hipStream_t stream) {
    const float* R    = (const float*)d_in[0];
    const float* t    = (const float*)d_in[1];
    const float* x    = (const float*)d_in[2];
    const float* z    = (const float*)d_in[3];
    const float* Wq   = (const float*)d_in[5];
    const float* Wk   = (const float*)d_in[6];
    const float* Wv   = (const float*)d_in[7];
    const float* Wpb  = (const float*)d_in[8];
    const float* spc  = (const float*)d_in[9];
    const float* Wqp  = (const float*)d_in[10];
    const float* Wkp  = (const float*)d_in[11];
    const float* Wvp  = (const float*)d_in[12];
    const float* Wout = (const float*)d_in[13];
    const float* bout = (const float*)d_in[14];
    const float* ln1g = (const float*)d_in[15];
    const float* ln1b = (const float*)d_in[16];
    const float* W1   = (const float*)d_in[17];
    const float* b1   = (const float*)d_in[18];
    const float* W2   = (const float*)d_in[19];
    const float* b2   = (const float*)d_in[20];
    const float* W3   = (const float*)d_in[21];
    const float* b3   = (const float*)d_in[22];
    const float* ln2g = (const float*)d_in[23];
    const float* ln2b = (const float*)d_in[24];
    float* out = (float*)d_out;

    float* ws = (float*)d_ws;
    float* qb   = ws;
    float* kb   = qb   + (size_t)LL * HQK;
    float* vb   = kb   + (size_t)LL * HQK;
    float* qpl  = vb   + (size_t)LL * HV;       // raw local coords
    float* kpl  = qpl  + (size_t)LL * HP3;
    float* vpl  = kpl  + (size_t)LL * HP3;
    float* lgA  = vpl  + (size_t)LL * HP3;      // [384][12][384] logits -> alpha
    float* feat = lgA  + (size_t)LL * NH * LL;  // [384][1824]
    float* part = feat + (size_t)LL * DOUT;     // [24][384][128]; also prefetch dump

    k1a_gemm<<<378 + 256, 256, 0, stream>>>(x, z, Wq, Wk, Wv, Wqp, Wkp, Wvp,
                                            qb, kb, vb, qpl, kpl, vpl, part);
    k3_node<<<dim3(6, 6, 12), 256, 0, stream>>>(qb, kb, qpl, kpl, R, t, spc, lgA);
    k4a_fused<<<LL, 512, 0, stream>>>(z, Wpb, lgA, feat);
    k4b_aggr<<<dim3(24, 12), 256, 0, stream>>>(lgA, vb, vpl, R, t, feat);
    k5a_outproj<<<dim3(12, KS), 512, 0, stream>>>(feat, Wout, part);
    k5b_rowepi<<<LL, 256, 0, stream>>>(part, bout, x, ln1g, ln1b,
                                       W1, b1, W2, b2, W3, b3, ln2g, ln2b, out);
}

// Round 10
// 101.292 us; speedup vs baseline: 6.9390x; 1.0636x over previous
//
#include <hip/hip_runtime.h>
#include <math.h>

constexpr int LL   = 384;
constexpr int FF   = 128;
constexpr int NH   = 12;
constexpr int HQK  = 384;
constexpr int HV   = 384;
constexpr int HP3  = 288;
constexpr int CC   = 64;
constexpr int P2N  = 768;   // p2n feature width

__device__ inline unsigned short f2bf(float f) {
    unsigned int u = __float_as_uint(f);
    return (unsigned short)((u + 0x7fff + ((u >> 16) & 1)) >> 16);
}
__device__ inline float bf2f(unsigned short s) {
    return __uint_as_float(((unsigned int)s) << 16);
}

// ---------------- K1a: six projections (raw local point coords) ----------------
__global__ void __launch_bounds__(256) k1a_gemm(
    const float* __restrict__ x,
    const float* __restrict__ Wq, const float* __restrict__ Wk, const float* __restrict__ Wv,
    const float* __restrict__ Wqp, const float* __restrict__ Wkp, const float* __restrict__ Wvp,
    float* __restrict__ qb, float* __restrict__ kb, float* __restrict__ vb,
    float* __restrict__ qpl, float* __restrict__ kpl, float* __restrict__ vpl) {
    const int bid = blockIdx.x, tid = threadIdx.x;
    const int ct = bid % 63, rt = bid / 63;
    __shared__ float xs[64 * 132];

    const float* W; float* O; int ld, cb;
    if (ct < 12)      { W = Wq;  O = qb;  ld = 384; cb = ct * 32; }
    else if (ct < 24) { W = Wk;  O = kb;  ld = 384; cb = (ct - 12) * 32; }
    else if (ct < 36) { W = Wv;  O = vb;  ld = 384; cb = (ct - 24) * 32; }
    else if (ct < 45) { W = Wqp; O = qpl; ld = 288; cb = (ct - 36) * 32; }
    else if (ct < 54) { W = Wkp; O = kpl; ld = 288; cb = (ct - 45) * 32; }
    else              { W = Wvp; O = vpl; ld = 288; cb = (ct - 54) * 32; }
    const int r0 = rt * 64;

    const float4* xsrc = (const float4*)(x + (size_t)r0 * FF);
#pragma unroll
    for (int k = 0; k < 8; ++k) {
        int idx = tid + k * 256;
        float4 v = xsrc[idx];
        int row = idx >> 5, c4 = (idx & 31) * 4;
        float* d = &xs[row * 132 + c4];
        d[0] = v.x; d[1] = v.y; d[2] = v.z; d[3] = v.w;
    }
    __syncthreads();

    const int cq = (tid & 7) * 4;
    const int rr = (tid >> 3) * 2;
    const float* Wp = W + cb + cq;
    const float* xr0 = &xs[rr * 132];
    const float* xr1 = &xs[(rr + 1) * 132];
    float a00=0,a01=0,a02=0,a03=0, a10=0,a11=0,a12=0,a13=0;
#pragma unroll 8
    for (int f = 0; f < FF; ++f) {
        const float4 w = *(const float4*)(Wp + (size_t)f * ld);
        float xa = xr0[f], xb = xr1[f];
        a00 = fmaf(xa, w.x, a00); a01 = fmaf(xa, w.y, a01);
        a02 = fmaf(xa, w.z, a02); a03 = fmaf(xa, w.w, a03);
        a10 = fmaf(xb, w.x, a10); a11 = fmaf(xb, w.y, a11);
        a12 = fmaf(xb, w.z, a12); a13 = fmaf(xb, w.w, a13);
    }
    float* o0 = O + (size_t)(r0 + rr) * ld + cb + cq;
    float* o1 = o0 + ld;
    o0[0]=a00; o0[1]=a01; o0[2]=a02; o0[3]=a03;
    o1[0]=a10; o1[1]=a11; o1[2]=a12; o1[3]=a13;
}

// ---------------- K3: node+spatial logits; rigid transform + norms inlined ----------------
__global__ void __launch_bounds__(256) k3_node(
    const float* __restrict__ qb, const float* __restrict__ kb,
    const float* __restrict__ qpl, const float* __restrict__ kpl,
    const float* __restrict__ R, const float* __restrict__ t,
    const float* __restrict__ spc, float* __restrict__ lgN) {
    const int it = blockIdx.x, jt = blockIdx.y, h = blockIdx.z;
    const int tid = threadIdx.x;
    __shared__ float As[64 * 60];
    __shared__ float Bs[64 * 60];
    __shared__ float pnA[512], pnB[512];
    const float g = log1pf(expf(spc[h]));
    const float s3 = 0.5773502691896258f;
    const float c1 = s3 * 0.17677669529663687f;
    const float c2 = s3 * g * (1.f / 6.f);
    const float c3 = -s3 * g * (1.f / 12.f);
    const int i0 = it * 64, j0 = jt * 64;

    for (int idx = tid; idx < 2048; idx += 256) {
        int r = idx >> 5, c = idx & 31;
        As[r*60 + c] = qb[(size_t)(i0 + r) * HQK + h*32 + c];
        Bs[r*60 + c] = kb[(size_t)(j0 + r) * HQK + h*32 + c] * c1;
    }
    for (int idx = tid; idx < 1024; idx += 256) {
        const int side = idx >> 9, rem = idx & 511;
        const int r = rem >> 3, p = rem & 7;
        const int row = (side ? j0 : i0) + r;
        const float* P = side ? kpl : qpl;
        const float* lp = P + (size_t)row * HP3 + (h*8 + p) * 3;
        float l0 = lp[0], l1 = lp[1], l2 = lp[2];
        float g0 = fmaf(R[row*9+0], l0, fmaf(R[row*9+1], l1, fmaf(R[row*9+2], l2, t[row*3+0])));
        float g1 = fmaf(R[row*9+3], l0, fmaf(R[row*9+4], l1, fmaf(R[row*9+5], l2, t[row*3+1])));
        float g2 = fmaf(R[row*9+6], l0, fmaf(R[row*9+7], l1, fmaf(R[row*9+8], l2, t[row*3+2])));
        float nn = g0*g0 + g1*g1 + g2*g2;
        if (side == 0) {
            float* d = &As[r*60 + 32 + p*3];
            d[0] = g0 * c2; d[1] = g1 * c2; d[2] = g2 * c2;
            pnA[r*8 + p] = nn;
        } else {
            float* d = &Bs[r*60 + 32 + p*3];
            d[0] = g0; d[1] = g1; d[2] = g2;
            pnB[r*8 + p] = nn;
        }
    }
    __syncthreads();
    if (tid < 64) {
        float s = 0.f;
#pragma unroll
        for (int p = 0; p < 8; ++p) s += pnA[tid*8 + p];
        As[tid*60 + 56] = s * c3;
        As[tid*60 + 57] = 1.f;
        As[tid*60 + 58] = 0.f; As[tid*60 + 59] = 0.f;
    } else if (tid < 128) {
        const int r = tid - 64;
        float s = 0.f;
#pragma unroll
        for (int p = 0; p < 8; ++p) s += pnB[r*8 + p];
        Bs[r*60 + 56] = 1.f;
        Bs[r*60 + 57] = s * c3;
        Bs[r*60 + 58] = 0.f; Bs[r*60 + 59] = 0.f;
    }
    __syncthreads();

    const int tx = tid & 15, ty = tid >> 4;
    float acc[4][4] = {};
    for (int k4 = 0; k4 < 60; k4 += 4) {
        float4 a[4], b[4];
#pragma unroll
        for (int r = 0; r < 4; ++r) a[r] = *(const float4*)&As[(ty*4 + r)*60 + k4];
#pragma unroll
        for (int c = 0; c < 4; ++c) b[c] = *(const float4*)&Bs[(tx*4 + c)*60 + k4];
#pragma unroll
        for (int r = 0; r < 4; ++r)
#pragma unroll
            for (int c = 0; c < 4; ++c) {
                acc[r][c] = fmaf(a[r].x, b[c].x, acc[r][c]);
                acc[r][c] = fmaf(a[r].y, b[c].y, acc[r][c]);
                acc[r][c] = fmaf(a[r].z, b[c].z, acc[r][c]);
                acc[r][c] = fmaf(a[r].w, b[c].w, acc[r][c]);
            }
    }
#pragma unroll
    for (int r = 0; r < 4; ++r)
        *(float4*)&lgN[((size_t)(i0 + ty*4 + r) * NH + h) * LL + j0 + tx*4] =
            make_float4(acc[r][0], acc[r][1], acc[r][2], acc[r][3]);
}

// ---------------- K4a: pair term + softmax + p2n (feat now [384][768]) ----------------
__global__ void __launch_bounds__(512, 4) k4a_fused(
    const float* __restrict__ z, const float* __restrict__ Wpb,
    float* __restrict__ lgA, float* __restrict__ feat) {
    const int i = blockIdx.x, tid = threadIdx.x;
    __shared__ __align__(16) unsigned char zu[384 * 68 * 2];
    unsigned short* z_s = (unsigned short*)zu;
    float* red = (float*)zu;
    __shared__ float a_s[NH * 384];

    const float4* zsrc = (const float4*)(z + (size_t)i * (LL * CC));
#pragma unroll
    for (int k = 0; k < 12; ++k) {
        int idx = tid + k * 512;
        float4 v = zsrc[idx];
        int j = idx >> 4, c4 = idx & 15;
        ushort4 pk;
        pk.x = f2bf(v.x); pk.y = f2bf(v.y); pk.z = f2bf(v.z); pk.w = f2bf(v.w);
        *(ushort4*)&z_s[j * 68 + c4 * 4] = pk;
    }
    __syncthreads();

    if (tid < 384) {
        const int j = tid;
        float pacc[12] = {};
        const unsigned short* zrow = &z_s[j * 68];
#pragma unroll
        for (int c4 = 0; c4 < 16; ++c4) {
            ushort4 zz = *(const ushort4*)&zrow[c4 * 4];
            float z0 = bf2f(zz.x), z1 = bf2f(zz.y), z2 = bf2f(zz.z), z3 = bf2f(zz.w);
            const float* wp = Wpb + c4 * 4 * NH;
#pragma unroll
            for (int hh = 0; hh < 12; ++hh) {
                float p = pacc[hh];
                p = fmaf(z0, wp[hh], p);
                p = fmaf(z1, wp[NH + hh], p);
                p = fmaf(z2, wp[2*NH + hh], p);
                p = fmaf(z3, wp[3*NH + hh], p);
                pacc[hh] = p;
            }
        }
        const float s3 = 0.5773502691896258f;
#pragma unroll
        for (int hh = 0; hh < 12; ++hh)
            a_s[hh * 384 + j] = lgA[((size_t)i * NH + hh) * LL + j] + pacc[hh] * s3;
    }
    __syncthreads();

    const int wv = tid >> 6, lane = tid & 63;
    if (wv < 6) {
#pragma unroll
        for (int rr = 0; rr < 2; ++rr) {
            const int h = wv * 2 + rr;
            float v[6];
#pragma unroll
            for (int k = 0; k < 6; ++k) v[k] = a_s[h * 384 + lane + k * 64];
            float m = v[0];
#pragma unroll
            for (int k = 1; k < 6; ++k) m = fmaxf(m, v[k]);
#pragma unroll
            for (int off = 32; off; off >>= 1) m = fmaxf(m, __shfl_xor(m, off));
            float s = 0.f;
#pragma unroll
            for (int k = 0; k < 6; ++k) { v[k] = expf(v[k] - m); s += v[k]; }
#pragma unroll
            for (int off = 32; off; off >>= 1) s += __shfl_xor(s, off);
            float inv = 1.f / s;
#pragma unroll
            for (int k = 0; k < 6; ++k) {
                float a = v[k] * inv;
                a_s[h * 384 + lane + k * 64] = a;
                lgA[((size_t)i * NH + h) * LL + lane + k * 64] = a;
            }
        }
    }
    __syncthreads();

    const int c4 = tid & 15, jc = tid >> 4;
    float4 acc[12] = {};
    const int jbase = jc * 12;
#pragma unroll
    for (int j4 = 0; j4 < 3; ++j4) {
        const int j = jbase + j4 * 4;
        float zv[4][4];
#pragma unroll
        for (int jj = 0; jj < 4; ++jj) {
            ushort4 zz = *(const ushort4*)&z_s[(j + jj) * 68 + c4 * 4];
            zv[jj][0] = bf2f(zz.x); zv[jj][1] = bf2f(zz.y);
            zv[jj][2] = bf2f(zz.z); zv[jj][3] = bf2f(zz.w);
        }
#pragma unroll
        for (int hh = 0; hh < 12; ++hh) {
            float4 a4 = *(const float4*)&a_s[hh * 384 + j];
            acc[hh].x = fmaf(a4.x, zv[0][0], acc[hh].x); acc[hh].y = fmaf(a4.x, zv[0][1], acc[hh].y);
            acc[hh].z = fmaf(a4.x, zv[0][2], acc[hh].z); acc[hh].w = fmaf(a4.x, zv[0][3], acc[hh].w);
            acc[hh].x = fmaf(a4.y, zv[1][0], acc[hh].x); acc[hh].y = fmaf(a4.y, zv[1][1], acc[hh].y);
            acc[hh].z = fmaf(a4.y, zv[1][2], acc[hh].z); acc[hh].w = fmaf(a4.y, zv[1][3], acc[hh].w);
            acc[hh].x = fmaf(a4.z, zv[2][0], acc[hh].x); acc[hh].y = fmaf(a4.z, zv[2][1], acc[hh].y);
            acc[hh].z = fmaf(a4.z, zv[2][2], acc[hh].z); acc[hh].w = fmaf(a4.z, zv[2][3], acc[hh].w);
            acc[hh].x = fmaf(a4.w, zv[3][0], acc[hh].x); acc[hh].y = fmaf(a4.w, zv[3][1], acc[hh].y);
            acc[hh].z = fmaf(a4.w, zv[3][2], acc[hh].z); acc[hh].w = fmaf(a4.w, zv[3][3], acc[hh].w);
        }
    }
    __syncthreads();   // z_s reads done; red aliases z_s
#pragma unroll
    for (int hh = 0; hh < 12; ++hh) {
        acc[hh].x += __shfl_xor(acc[hh].x, 16); acc[hh].y += __shfl_xor(acc[hh].y, 16);
        acc[hh].z += __shfl_xor(acc[hh].z, 16); acc[hh].w += __shfl_xor(acc[hh].w, 16);
        acc[hh].x += __shfl_xor(acc[hh].x, 32); acc[hh].y += __shfl_xor(acc[hh].y, 32);
        acc[hh].z += __shfl_xor(acc[hh].z, 32); acc[hh].w += __shfl_xor(acc[hh].w, 32);
    }
    if (lane < 16) {
#pragma unroll
        for (int hh = 0; hh < 12; ++hh)
            *(float4*)&red[wv * 768 + hh * 64 + lane * 4] = acc[hh];
    }
    __syncthreads();
    if (tid < 192) {
        int hh = tid >> 4, cc = tid & 15;
        float4 s = make_float4(0.f, 0.f, 0.f, 0.f);
#pragma unroll
        for (int w = 0; w < 8; ++w) {
            float4 p = *(const float4*)&red[w * 768 + hh * 64 + cc * 4];
            s.x += p.x; s.y += p.y; s.z += p.z; s.w += p.w;
        }
        *(float4*)&feat[(size_t)i * P2N + hh * 64 + cc * 4] = s;
    }
}

// ---------------- K45: aggregation + frame transform + per-head out-proj partial ----------------
// grid (24 it, 12 h), 256 thr. Produces partial[h][i][128] (sum of head-h's 152 Wout rows).
__global__ void __launch_bounds__(256) k45_aggproj(
    const float* __restrict__ alpha, const float* __restrict__ vb,
    const float* __restrict__ vpl, const float* __restrict__ R,
    const float* __restrict__ t, const float* __restrict__ feat,
    const float* __restrict__ Wout, float* __restrict__ partial) {
    const int it = blockIdx.x, h = blockIdx.y;
    const int tid = threadIdx.x;
    __shared__ float bs[128 * 57];         // 29.2 KB
    __shared__ float fa[16][152];          // 9.7 KB: [0:64] p2n, [64:96] node, [96:120] fp, [120:128] dist, [128:152] dirn
    __shared__ float sa[16][24];           // 1.5 KB
    const int i0 = it * 16;
    const int wv = __builtin_amdgcn_readfirstlane(tid >> 6);
    const int n = tid & 63;
    const float* arow0 = alpha + ((size_t)(i0 + wv * 4) * NH + h) * LL;

    // stage p2n slice for head h (16 rows x 64) — written by k4a
    if (tid < 256) {
        int r = tid >> 4, c4 = tid & 15;
        float4 v = *(const float4*)&feat[(size_t)(i0 + r) * P2N + h * 64 + c4 * 4];
        *(float4*)&fa[r][c4 * 4] = v;
    }

    float acc[4] = {};
    for (int tile = 0; tile < 3; ++tile) {
        const int j0 = tile * 128;
        __syncthreads();
        for (int idx = tid; idx < 2048; idx += 256) {
            if (idx < 1024) {
                int jr = idx >> 3, q = idx & 7;
                const float* src = vb + (size_t)(j0 + jr) * HV + h * 32 + q * 4;
                float* d = &bs[jr * 57 + q * 4];
                d[0] = src[0]; d[1] = src[1]; d[2] = src[2]; d[3] = src[3];
            } else {
                int id2 = idx - 1024;
                int jr = id2 >> 3, p = id2 & 7;
                const int row = j0 + jr;
                const float* lp = vpl + (size_t)row * HP3 + (h*8 + p) * 3;
                float l0 = lp[0], l1 = lp[1], l2 = lp[2];
                float g0 = fmaf(R[row*9+0], l0, fmaf(R[row*9+1], l1, fmaf(R[row*9+2], l2, t[row*3+0])));
                float g1 = fmaf(R[row*9+3], l0, fmaf(R[row*9+4], l1, fmaf(R[row*9+5], l2, t[row*3+1])));
                float g2 = fmaf(R[row*9+6], l0, fmaf(R[row*9+7], l1, fmaf(R[row*9+8], l2, t[row*3+2])));
                float* d = &bs[jr * 57 + 32 + p * 3];
                d[0] = g0; d[1] = g1; d[2] = g2;
            }
        }
        __syncthreads();
        if (n < 56) {
            for (int j4 = 0; j4 < 32; ++j4) {
                float bv0 = bs[(j4*4+0)*57 + n];
                float bv1 = bs[(j4*4+1)*57 + n];
                float bv2 = bs[(j4*4+2)*57 + n];
                float bv3 = bs[(j4*4+3)*57 + n];
#pragma unroll
                for (int r = 0; r < 4; ++r) {
                    const float* ar = arow0 + (size_t)r * (NH * LL) + j0 + j4 * 4;
                    acc[r] = fmaf(ar[0], bv0, acc[r]);
                    acc[r] = fmaf(ar[1], bv1, acc[r]);
                    acc[r] = fmaf(ar[2], bv2, acc[r]);
                    acc[r] = fmaf(ar[3], bv3, acc[r]);
                }
            }
        }
    }
    __syncthreads();
    if (n < 56) {
        if (n < 32) {
#pragma unroll
            for (int r = 0; r < 4; ++r) fa[wv * 4 + r][64 + n] = acc[r];
        } else {
#pragma unroll
            for (int r = 0; r < 4; ++r) sa[wv * 4 + r][n - 32] = acc[r];
        }
    }
    __syncthreads();
    if (tid < 128) {
        const int ri = tid >> 3, p = tid & 7;
        const int i = i0 + ri;
        float d0 = sa[ri][p*3+0] - t[i*3+0];
        float d1 = sa[ri][p*3+1] - t[i*3+1];
        float d2 = sa[ri][p*3+2] - t[i*3+2];
        float f0 = R[i*9+0]*d0 + R[i*9+3]*d1 + R[i*9+6]*d2;
        float f1 = R[i*9+1]*d0 + R[i*9+4]*d1 + R[i*9+7]*d2;
        float f2 = R[i*9+2]*d0 + R[i*9+5]*d1 + R[i*9+8]*d2;
        float dist = sqrtf(f0*f0 + f1*f1 + f2*f2);
        float inv = 1.f / (dist + 1e-4f);
        fa[ri][96 + p*3+0] = f0; fa[ri][96 + p*3+1] = f1; fa[ri][96 + p*3+2] = f2;
        fa[ri][120 + p] = dist;
        fa[ri][128 + p*3+0] = f0*inv; fa[ri][128 + p*3+1] = f1*inv; fa[ri][128 + p*3+2] = f2*inv;
    }
    __syncthreads();

    // out-projection for head h's 152 features, 16 rows. thread = f (128) x rg (2, 8 rows each)
    const int f = tid & 127, rg = tid >> 7;
    float o[8] = {};
    const float* fr0 = &fa[rg * 8][0];
    // 5 contiguous Wout segments
    {
        const float* w = Wout + (size_t)(h * 64) * FF + f;          // p2n
        for (int k = 0; k < 64; ++k) {
            float wv_ = w[(size_t)k * FF];
#pragma unroll
            for (int r = 0; r < 8; ++r) o[r] = fmaf(fr0[r * 152 + k], wv_, o[r]);
        }
    }
    {
        const float* w = Wout + (size_t)(768 + h * 32) * FF + f;    // node
        for (int k = 0; k < 32; ++k) {
            float wv_ = w[(size_t)k * FF];
#pragma unroll
            for (int r = 0; r < 8; ++r) o[r] = fmaf(fr0[r * 152 + 64 + k], wv_, o[r]);
        }
    }
    {
        const float* w = Wout + (size_t)(1152 + h * 24) * FF + f;   // fp
        for (int k = 0; k < 24; ++k) {
            float wv_ = w[(size_t)k * FF];
#pragma unroll
            for (int r = 0; r < 8; ++r) o[r] = fmaf(fr0[r * 152 + 96 + k], wv_, o[r]);
        }
    }
    {
        const float* w = Wout + (size_t)(1440 + h * 8) * FF + f;    // dist
        for (int k = 0; k < 8; ++k) {
            float wv_ = w[(size_t)k * FF];
#pragma unroll
            for (int r = 0; r < 8; ++r) o[r] = fmaf(fr0[r * 152 + 120 + k], wv_, o[r]);
        }
    }
    {
        const float* w = Wout + (size_t)(1536 + h * 24) * FF + f;   // dirn
        for (int k = 0; k < 24; ++k) {
            float wv_ = w[(size_t)k * FF];
#pragma unroll
            for (int r = 0; r < 8; ++r) o[r] = fmaf(fr0[r * 152 + 128 + k], wv_, o[r]);
        }
    }
#pragma unroll
    for (int r = 0; r < 8; ++r)
        partial[((size_t)h * LL + i0 + rg * 8 + r) * FF + f] = o[r];
}

// ---------------- K5b: sum 12 partials + LN1 + MLP(split-4) + LN2. grid 384, 512 thr ----------------
__global__ void __launch_bounds__(512) k5b_rowepi(
    const float* __restrict__ partial, const float* __restrict__ bout,
    const float* __restrict__ x,
    const float* __restrict__ ln1g, const float* __restrict__ ln1b,
    const float* __restrict__ W1, const float* __restrict__ b1,
    const float* __restrict__ W2, const float* __restrict__ b2,
    const float* __restrict__ W3, const float* __restrict__ b3,
    const float* __restrict__ ln2g, const float* __restrict__ ln2b,
    float* __restrict__ out) {
    const int i = blockIdx.x, tid = threadIdx.x;
    const int f = tid & 127, q = tid >> 7;   // q 0..3
    __shared__ float prt[4][128];
    __shared__ float x1s[128], hbA[128], hbB[128];
    __shared__ float wrA[2], wrB[2];

    {
        float acc = 0.f;
#pragma unroll
        for (int k = 0; k < 3; ++k)
            acc += partial[((size_t)(q * 3 + k) * LL + i) * FF + f];
        prt[q][f] = acc;
    }
    __syncthreads();

    float s1 = 0.f, dv1 = 0.f;
    if (tid < 128) {
        s1 = prt[0][f] + prt[1][f] + prt[2][f] + prt[3][f] + bout[f] + x[(size_t)i * FF + f];
        float r = s1;
#pragma unroll
        for (int off = 32; off; off >>= 1) r += __shfl_xor(r, off);
        if ((tid & 63) == 0) wrA[tid >> 6] = r;
    }
    __syncthreads();
    if (tid < 128) {
        float mu = (wrA[0] + wrA[1]) * (1.f / FF);
        dv1 = s1 - mu;
        float r = dv1 * dv1;
#pragma unroll
        for (int off = 32; off; off >>= 1) r += __shfl_xor(r, off);
        if ((tid & 63) == 0) wrB[tid >> 6] = r;
    }
    __syncthreads();
    if (tid < 128) {
        float var = (wrB[0] + wrB[1]) * (1.f / FF);
        x1s[f] = dv1 * rsqrtf(var + 1e-5f) * ln1g[f] + ln1b[f];
    }
    __syncthreads();

    // MLP L1, split-K=4
    {
        const int k0 = q * 32;
        float p0=0,p1=0,p2=0,p3=0;
        for (int k = 0; k < 8; ++k) {
            int d = k0 + k * 4;
            p0 = fmaf(x1s[d+0], W1[(size_t)(d+0)*FF + f], p0);
            p1 = fmaf(x1s[d+1], W1[(size_t)(d+1)*FF + f], p1);
            p2 = fmaf(x1s[d+2], W1[(size_t)(d+2)*FF + f], p2);
            p3 = fmaf(x1s[d+3], W1[(size_t)(d+3)*FF + f], p3);
        }
        prt[q][f] = p0 + p1 + p2 + p3;
    }
    __syncthreads();
    if (tid < 128) hbA[f] = fmaxf(prt[0][f]+prt[1][f]+prt[2][f]+prt[3][f] + b1[f], 0.f);
    __syncthreads();
    {
        const int k0 = q * 32;
        float p0=0,p1=0,p2=0,p3=0;
        for (int k = 0; k < 8; ++k) {
            int d = k0 + k * 4;
            p0 = fmaf(hbA[d+0], W2[(size_t)(d+0)*FF + f], p0);
            p1 = fmaf(hbA[d+1], W2[(size_t)(d+1)*FF + f], p1);
            p2 = fmaf(hbA[d+2], W2[(size_t)(d+2)*FF + f], p2);
            p3 = fmaf(hbA[d+3], W2[(size_t)(d+3)*FF + f], p3);
        }
        prt[q][f] = p0 + p1 + p2 + p3;
    }
    __syncthreads();
    if (tid < 128) hbB[f] = fmaxf(prt[0][f]+prt[1][f]+prt[2][f]+prt[3][f] + b2[f], 0.f);
    __syncthreads();
    {
        const int k0 = q * 32;
        float p0=0,p1=0,p2=0,p3=0;
        for (int k = 0; k < 8; ++k) {
            int d = k0 + k * 4;
            p0 = fmaf(hbB[d+0], W3[(size_t)(d+0)*FF + f], p0);
            p1 = fmaf(hbB[d+1], W3[(size_t)(d+1)*FF + f], p1);
            p2 = fmaf(hbB[d+2], W3[(size_t)(d+2)*FF + f], p2);
            p3 = fmaf(hbB[d+3], W3[(size_t)(d+3)*FF + f], p3);
        }
        prt[q][f] = p0 + p1 + p2 + p3;
    }
    __syncthreads();

    float s2 = 0.f, dv2 = 0.f;
    if (tid < 128) {
        s2 = x1s[f] + prt[0][f]+prt[1][f]+prt[2][f]+prt[3][f] + b3[f];
        float r = s2;
#pragma unroll
        for (int off = 32; off; off >>= 1) r += __shfl_xor(r, off);
        if ((tid & 63) == 0) wrA[tid >> 6] = r;
    }
    __syncthreads();
    if (tid < 128) {
        float mu = (wrA[0] + wrA[1]) * (1.f / FF);
        dv2 = s2 - mu;
        float r = dv2 * dv2;
#pragma unroll
        for (int off = 32; off; off >>= 1) r += __shfl_xor(r, off);
        if ((tid & 63) == 0) wrB[tid >> 6] = r;
    }
    __syncthreads();
    if (tid < 128) {
        float var = (wrB[0] + wrB[1]) * (1.f / FF);
        out[(size_t)i * FF + f] = dv2 * rsqrtf(var + 1e-5f) * ln2g[f] + ln2b[f];
    }
}

extern "C" void kernel_launch(void* const* d_in, const int* in_sizes, int n_in,
                              void* d_out, int out_size, void* d_ws, size_t ws_size,
                              hipStream_t stream) {
    const float* R    = (const float*)d_in[0];
    const float* t    = (const float*)d_in[1];
    const float* x    = (const float*)d_in[2];
    const float* z    = (const float*)d_in[3];
    const float* Wq   = (const float*)d_in[5];
    const float* Wk   = (const float*)d_in[6];
    const float* Wv   = (const float*)d_in[7];
    const float* Wpb  = (const float*)d_in[8];
    const float* spc  = (const float*)d_in[9];
    const float* Wqp  = (const float*)d_in[10];
    const float* Wkp  = (const float*)d_in[11];
    const float* Wvp  = (const float*)d_in[12];
    const float* Wout = (const float*)d_in[13];
    const float* bout = (const float*)d_in[14];
    const float* ln1g = (const float*)d_in[15];
    const float* ln1b = (const float*)d_in[16];
    const float* W1   = (const float*)d_in[17];
    const float* b1   = (const float*)d_in[18];
    const float* W2   = (const float*)d_in[19];
    const float* b2   = (const float*)d_in[20];
    const float* W3   = (const float*)d_in[21];
    const float* b3   = (const float*)d_in[22];
    const float* ln2g = (const float*)d_in[23];
    const float* ln2b = (const float*)d_in[24];
    float* out = (float*)d_out;

    float* ws = (float*)d_ws;
    float* qb   = ws;
    float* kb   = qb   + (size_t)LL * HQK;
    float* vb   = kb   + (size_t)LL * HQK;
    float* qpl  = vb   + (size_t)LL * HV;
    float* kpl  = qpl  + (size_t)LL * HP3;
    float* vpl  = kpl  + (size_t)LL * HP3;
    float* lgA  = vpl  + (size_t)LL * HP3;      // [384][12][384] logits -> alpha
    float* feat = lgA  + (size_t)LL * NH * LL;  // [384][768] p2n only
    float* part = feat + (size_t)LL * P2N;      // [12][384][128]

    k1a_gemm<<<378, 256, 0, stream>>>(x, Wq, Wk, Wv, Wqp, Wkp, Wvp,
                                      qb, kb, vb, qpl, kpl, vpl);
    k3_node<<<dim3(6, 6, 12), 256, 0, stream>>>(qb, kb, qpl, kpl, R, t, spc, lgA);
    k4a_fused<<<LL, 512, 0, stream>>>(z, Wpb, lgA, feat);
    k45_aggproj<<<dim3(24, 12), 256, 0, stream>>>(lgA, vb, vpl, R, t, feat, Wout, part);
    k5b_rowepi<<<LL, 512, 0, stream>>>(part, bout, x, ln1g, ln1b,
                                       W1, b1, W2, b2, W3, b3, ln2g, ln2b, out);
}

// Round 11
// 86.867 us; speedup vs baseline: 8.0913x; 1.1661x over previous
//
#include <hip/hip_runtime.h>
#include <math.h>

constexpr int LL   = 384;
constexpr int FF   = 128;
constexpr int NH   = 12;
constexpr int HQK  = 384;
constexpr int HV   = 384;
constexpr int HP3  = 288;
constexpr int CC   = 64;
constexpr int P2N  = 768;   // p2n feature width

__device__ inline unsigned short f2bf(float f) {
    unsigned int u = __float_as_uint(f);
    return (unsigned short)((u + 0x7fff + ((u >> 16) & 1)) >> 16);
}
__device__ inline float bf2f(unsigned short s) {
    return __uint_as_float(((unsigned int)s) << 16);
}

// ---------------- K1a: six projections (raw local point coords) ----------------
__global__ void __launch_bounds__(256) k1a_gemm(
    const float* __restrict__ x,
    const float* __restrict__ Wq, const float* __restrict__ Wk, const float* __restrict__ Wv,
    const float* __restrict__ Wqp, const float* __restrict__ Wkp, const float* __restrict__ Wvp,
    float* __restrict__ qb, float* __restrict__ kb, float* __restrict__ vb,
    float* __restrict__ qpl, float* __restrict__ kpl, float* __restrict__ vpl) {
    const int bid = blockIdx.x, tid = threadIdx.x;
    const int ct = bid % 63, rt = bid / 63;
    __shared__ float xs[64 * 132];

    const float* W; float* O; int ld, cb;
    if (ct < 12)      { W = Wq;  O = qb;  ld = 384; cb = ct * 32; }
    else if (ct < 24) { W = Wk;  O = kb;  ld = 384; cb = (ct - 12) * 32; }
    else if (ct < 36) { W = Wv;  O = vb;  ld = 384; cb = (ct - 24) * 32; }
    else if (ct < 45) { W = Wqp; O = qpl; ld = 288; cb = (ct - 36) * 32; }
    else if (ct < 54) { W = Wkp; O = kpl; ld = 288; cb = (ct - 45) * 32; }
    else              { W = Wvp; O = vpl; ld = 288; cb = (ct - 54) * 32; }
    const int r0 = rt * 64;

    const float4* xsrc = (const float4*)(x + (size_t)r0 * FF);
#pragma unroll
    for (int k = 0; k < 8; ++k) {
        int idx = tid + k * 256;
        float4 v = xsrc[idx];
        int row = idx >> 5, c4 = (idx & 31) * 4;
        float* d = &xs[row * 132 + c4];
        d[0] = v.x; d[1] = v.y; d[2] = v.z; d[3] = v.w;
    }
    __syncthreads();

    const int cq = (tid & 7) * 4;
    const int rr = (tid >> 3) * 2;
    const float* Wp = W + cb + cq;
    const float* xr0 = &xs[rr * 132];
    const float* xr1 = &xs[(rr + 1) * 132];
    float a00=0,a01=0,a02=0,a03=0, a10=0,a11=0,a12=0,a13=0;
#pragma unroll 8
    for (int f = 0; f < FF; ++f) {
        const float4 w = *(const float4*)(Wp + (size_t)f * ld);
        float xa = xr0[f], xb = xr1[f];
        a00 = fmaf(xa, w.x, a00); a01 = fmaf(xa, w.y, a01);
        a02 = fmaf(xa, w.z, a02); a03 = fmaf(xa, w.w, a03);
        a10 = fmaf(xb, w.x, a10); a11 = fmaf(xb, w.y, a11);
        a12 = fmaf(xb, w.z, a12); a13 = fmaf(xb, w.w, a13);
    }
    float* o0 = O + (size_t)(r0 + rr) * ld + cb + cq;
    float* o1 = o0 + ld;
    o0[0]=a00; o0[1]=a01; o0[2]=a02; o0[3]=a03;
    o1[0]=a10; o1[1]=a11; o1[2]=a12; o1[3]=a13;
}

// ---------------- K3: node+spatial logits; rigid transform + norms inlined ----------------
__global__ void __launch_bounds__(256) k3_node(
    const float* __restrict__ qb, const float* __restrict__ kb,
    const float* __restrict__ qpl, const float* __restrict__ kpl,
    const float* __restrict__ R, const float* __restrict__ t,
    const float* __restrict__ spc, float* __restrict__ lgN) {
    const int it = blockIdx.x, jt = blockIdx.y, h = blockIdx.z;
    const int tid = threadIdx.x;
    __shared__ float As[64 * 60];
    __shared__ float Bs[64 * 60];
    __shared__ float pnA[512], pnB[512];
    const float g = log1pf(expf(spc[h]));
    const float s3 = 0.5773502691896258f;
    const float c1 = s3 * 0.17677669529663687f;
    const float c2 = s3 * g * (1.f / 6.f);
    const float c3 = -s3 * g * (1.f / 12.f);
    const int i0 = it * 64, j0 = jt * 64;

    for (int idx = tid; idx < 2048; idx += 256) {
        int r = idx >> 5, c = idx & 31;
        As[r*60 + c] = qb[(size_t)(i0 + r) * HQK + h*32 + c];
        Bs[r*60 + c] = kb[(size_t)(j0 + r) * HQK + h*32 + c] * c1;
    }
    for (int idx = tid; idx < 1024; idx += 256) {
        const int side = idx >> 9, rem = idx & 511;
        const int r = rem >> 3, p = rem & 7;
        const int row = (side ? j0 : i0) + r;
        const float* P = side ? kpl : qpl;
        const float* lp = P + (size_t)row * HP3 + (h*8 + p) * 3;
        float l0 = lp[0], l1 = lp[1], l2 = lp[2];
        float g0 = fmaf(R[row*9+0], l0, fmaf(R[row*9+1], l1, fmaf(R[row*9+2], l2, t[row*3+0])));
        float g1 = fmaf(R[row*9+3], l0, fmaf(R[row*9+4], l1, fmaf(R[row*9+5], l2, t[row*3+1])));
        float g2 = fmaf(R[row*9+6], l0, fmaf(R[row*9+7], l1, fmaf(R[row*9+8], l2, t[row*3+2])));
        float nn = g0*g0 + g1*g1 + g2*g2;
        if (side == 0) {
            float* d = &As[r*60 + 32 + p*3];
            d[0] = g0 * c2; d[1] = g1 * c2; d[2] = g2 * c2;
            pnA[r*8 + p] = nn;
        } else {
            float* d = &Bs[r*60 + 32 + p*3];
            d[0] = g0; d[1] = g1; d[2] = g2;
            pnB[r*8 + p] = nn;
        }
    }
    __syncthreads();
    if (tid < 64) {
        float s = 0.f;
#pragma unroll
        for (int p = 0; p < 8; ++p) s += pnA[tid*8 + p];
        As[tid*60 + 56] = s * c3;
        As[tid*60 + 57] = 1.f;
        As[tid*60 + 58] = 0.f; As[tid*60 + 59] = 0.f;
    } else if (tid < 128) {
        const int r = tid - 64;
        float s = 0.f;
#pragma unroll
        for (int p = 0; p < 8; ++p) s += pnB[r*8 + p];
        Bs[r*60 + 56] = 1.f;
        Bs[r*60 + 57] = s * c3;
        Bs[r*60 + 58] = 0.f; Bs[r*60 + 59] = 0.f;
    }
    __syncthreads();

    const int tx = tid & 15, ty = tid >> 4;
    float acc[4][4] = {};
    for (int k4 = 0; k4 < 60; k4 += 4) {
        float4 a[4], b[4];
#pragma unroll
        for (int r = 0; r < 4; ++r) a[r] = *(const float4*)&As[(ty*4 + r)*60 + k4];
#pragma unroll
        for (int c = 0; c < 4; ++c) b[c] = *(const float4*)&Bs[(tx*4 + c)*60 + k4];
#pragma unroll
        for (int r = 0; r < 4; ++r)
#pragma unroll
            for (int c = 0; c < 4; ++c) {
                acc[r][c] = fmaf(a[r].x, b[c].x, acc[r][c]);
                acc[r][c] = fmaf(a[r].y, b[c].y, acc[r][c]);
                acc[r][c] = fmaf(a[r].z, b[c].z, acc[r][c]);
                acc[r][c] = fmaf(a[r].w, b[c].w, acc[r][c]);
            }
    }
#pragma unroll
    for (int r = 0; r < 4; ++r)
        *(float4*)&lgN[((size_t)(i0 + ty*4 + r) * NH + h) * LL + j0 + tx*4] =
            make_float4(acc[r][0], acc[r][1], acc[r][2], acc[r][3]);
}

// ---------------- K4a: pair term + softmax + p2n (feat [384][768]) ----------------
__global__ void __launch_bounds__(512, 4) k4a_fused(
    const float* __restrict__ z, const float* __restrict__ Wpb,
    float* __restrict__ lgA, float* __restrict__ feat) {
    const int i = blockIdx.x, tid = threadIdx.x;
    __shared__ __align__(16) unsigned char zu[384 * 68 * 2];
    unsigned short* z_s = (unsigned short*)zu;
    float* red = (float*)zu;
    __shared__ float a_s[NH * 384];

    const float4* zsrc = (const float4*)(z + (size_t)i * (LL * CC));
#pragma unroll
    for (int k = 0; k < 12; ++k) {
        int idx = tid + k * 512;
        float4 v = zsrc[idx];
        int j = idx >> 4, c4 = idx & 15;
        ushort4 pk;
        pk.x = f2bf(v.x); pk.y = f2bf(v.y); pk.z = f2bf(v.z); pk.w = f2bf(v.w);
        *(ushort4*)&z_s[j * 68 + c4 * 4] = pk;
    }
    __syncthreads();

    if (tid < 384) {
        const int j = tid;
        float pacc[12] = {};
        const unsigned short* zrow = &z_s[j * 68];
#pragma unroll
        for (int c4 = 0; c4 < 16; ++c4) {
            ushort4 zz = *(const ushort4*)&zrow[c4 * 4];
            float z0 = bf2f(zz.x), z1 = bf2f(zz.y), z2 = bf2f(zz.z), z3 = bf2f(zz.w);
            const float* wp = Wpb + c4 * 4 * NH;
#pragma unroll
            for (int hh = 0; hh < 12; ++hh) {
                float p = pacc[hh];
                p = fmaf(z0, wp[hh], p);
                p = fmaf(z1, wp[NH + hh], p);
                p = fmaf(z2, wp[2*NH + hh], p);
                p = fmaf(z3, wp[3*NH + hh], p);
                pacc[hh] = p;
            }
        }
        const float s3 = 0.5773502691896258f;
#pragma unroll
        for (int hh = 0; hh < 12; ++hh)
            a_s[hh * 384 + j] = lgA[((size_t)i * NH + hh) * LL + j] + pacc[hh] * s3;
    }
    __syncthreads();

    const int wv = tid >> 6, lane = tid & 63;
    if (wv < 6) {
#pragma unroll
        for (int rr = 0; rr < 2; ++rr) {
            const int h = wv * 2 + rr;
            float v[6];
#pragma unroll
            for (int k = 0; k < 6; ++k) v[k] = a_s[h * 384 + lane + k * 64];
            float m = v[0];
#pragma unroll
            for (int k = 1; k < 6; ++k) m = fmaxf(m, v[k]);
#pragma unroll
            for (int off = 32; off; off >>= 1) m = fmaxf(m, __shfl_xor(m, off));
            float s = 0.f;
#pragma unroll
            for (int k = 0; k < 6; ++k) { v[k] = expf(v[k] - m); s += v[k]; }
#pragma unroll
            for (int off = 32; off; off >>= 1) s += __shfl_xor(s, off);
            float inv = 1.f / s;
#pragma unroll
            for (int k = 0; k < 6; ++k) {
                float a = v[k] * inv;
                a_s[h * 384 + lane + k * 64] = a;
                lgA[((size_t)i * NH + h) * LL + lane + k * 64] = a;
            }
        }
    }
    __syncthreads();

    const int c4 = tid & 15, jc = tid >> 4;
    float4 acc[12] = {};
    const int jbase = jc * 12;
#pragma unroll
    for (int j4 = 0; j4 < 3; ++j4) {
        const int j = jbase + j4 * 4;
        float zv[4][4];
#pragma unroll
        for (int jj = 0; jj < 4; ++jj) {
            ushort4 zz = *(const ushort4*)&z_s[(j + jj) * 68 + c4 * 4];
            zv[jj][0] = bf2f(zz.x); zv[jj][1] = bf2f(zz.y);
            zv[jj][2] = bf2f(zz.z); zv[jj][3] = bf2f(zz.w);
        }
#pragma unroll
        for (int hh = 0; hh < 12; ++hh) {
            float4 a4 = *(const float4*)&a_s[hh * 384 + j];
            acc[hh].x = fmaf(a4.x, zv[0][0], acc[hh].x); acc[hh].y = fmaf(a4.x, zv[0][1], acc[hh].y);
            acc[hh].z = fmaf(a4.x, zv[0][2], acc[hh].z); acc[hh].w = fmaf(a4.x, zv[0][3], acc[hh].w);
            acc[hh].x = fmaf(a4.y, zv[1][0], acc[hh].x); acc[hh].y = fmaf(a4.y, zv[1][1], acc[hh].y);
            acc[hh].z = fmaf(a4.y, zv[1][2], acc[hh].z); acc[hh].w = fmaf(a4.y, zv[1][3], acc[hh].w);
            acc[hh].x = fmaf(a4.z, zv[2][0], acc[hh].x); acc[hh].y = fmaf(a4.z, zv[2][1], acc[hh].y);
            acc[hh].z = fmaf(a4.z, zv[2][2], acc[hh].z); acc[hh].w = fmaf(a4.z, zv[2][3], acc[hh].w);
            acc[hh].x = fmaf(a4.w, zv[3][0], acc[hh].x); acc[hh].y = fmaf(a4.w, zv[3][1], acc[hh].y);
            acc[hh].z = fmaf(a4.w, zv[3][2], acc[hh].z); acc[hh].w = fmaf(a4.w, zv[3][3], acc[hh].w);
        }
    }
    __syncthreads();   // z_s reads done; red aliases z_s
#pragma unroll
    for (int hh = 0; hh < 12; ++hh) {
        acc[hh].x += __shfl_xor(acc[hh].x, 16); acc[hh].y += __shfl_xor(acc[hh].y, 16);
        acc[hh].z += __shfl_xor(acc[hh].z, 16); acc[hh].w += __shfl_xor(acc[hh].w, 16);
        acc[hh].x += __shfl_xor(acc[hh].x, 32); acc[hh].y += __shfl_xor(acc[hh].y, 32);
        acc[hh].z += __shfl_xor(acc[hh].z, 32); acc[hh].w += __shfl_xor(acc[hh].w, 32);
    }
    if (lane < 16) {
#pragma unroll
        for (int hh = 0; hh < 12; ++hh)
            *(float4*)&red[wv * 768 + hh * 64 + lane * 4] = acc[hh];
    }
    __syncthreads();
    if (tid < 192) {
        int hh = tid >> 4, cc = tid & 15;
        float4 s = make_float4(0.f, 0.f, 0.f, 0.f);
#pragma unroll
        for (int w = 0; w < 8; ++w) {
            float4 p = *(const float4*)&red[w * 768 + hh * 64 + cc * 4];
            s.x += p.x; s.y += p.y; s.z += p.z; s.w += p.w;
        }
        *(float4*)&feat[(size_t)i * P2N + hh * 64 + cc * 4] = s;
    }
}

// ---------------- K45: aggregation + frame transform + per-head out-proj ----------------
// grid (24 it, 12 h), 512 thr. Alpha staged in LDS per j-tile (no scalar-load stalls).
__global__ void __launch_bounds__(512) k45_aggproj(
    const float* __restrict__ alpha, const float* __restrict__ vb,
    const float* __restrict__ vpl, const float* __restrict__ R,
    const float* __restrict__ t, const float* __restrict__ feat,
    const float* __restrict__ Wout, float* __restrict__ partial) {
    const int it = blockIdx.x, h = blockIdx.y;
    const int tid = threadIdx.x;
    __shared__ float bs[128 * 57];         // 29.2 KB: vb|vp tile
    __shared__ float atile[16][128];       // 8 KB: alpha tile
    __shared__ float fa[16][152];          // 9.7 KB
    __shared__ float sa[16][24];           // 1.5 KB
    const int i0 = it * 16;
    const int wv = __builtin_amdgcn_readfirstlane(tid >> 6);  // 0..7
    const int n = tid & 63;

    // stage p2n slice for head h (16 rows x 64)
    if (tid < 256) {
        int r = tid >> 4, c4 = tid & 15;
        float4 v = *(const float4*)&feat[(size_t)(i0 + r) * P2N + h * 64 + c4 * 4];
        *(float4*)&fa[r][c4 * 4] = v;
    }

    float acc[2] = {0.f, 0.f};
    for (int tile = 0; tile < 3; ++tile) {
        const int j0 = tile * 128;
        __syncthreads();
        // stage vb | vp(transformed) tile: 2048 entries
        for (int idx = tid; idx < 2048; idx += 512) {
            if (idx < 1024) {
                int jr = idx >> 3, q = idx & 7;
                const float* src = vb + (size_t)(j0 + jr) * HV + h * 32 + q * 4;
                float* d = &bs[jr * 57 + q * 4];
                d[0] = src[0]; d[1] = src[1]; d[2] = src[2]; d[3] = src[3];
            } else {
                int id2 = idx - 1024;
                int jr = id2 >> 3, p = id2 & 7;
                const int row = j0 + jr;
                const float* lp = vpl + (size_t)row * HP3 + (h*8 + p) * 3;
                float l0 = lp[0], l1 = lp[1], l2 = lp[2];
                float g0 = fmaf(R[row*9+0], l0, fmaf(R[row*9+1], l1, fmaf(R[row*9+2], l2, t[row*3+0])));
                float g1 = fmaf(R[row*9+3], l0, fmaf(R[row*9+4], l1, fmaf(R[row*9+5], l2, t[row*3+1])));
                float g2 = fmaf(R[row*9+6], l0, fmaf(R[row*9+7], l1, fmaf(R[row*9+8], l2, t[row*3+2])));
                float* d = &bs[jr * 57 + 32 + p * 3];
                d[0] = g0; d[1] = g1; d[2] = g2;
            }
        }
        // stage alpha tile: 16 rows x 128 j (coalesced float4 -> LDS)
        {
            int r = tid >> 5, c4 = tid & 31;
            float4 v = *(const float4*)&alpha[((size_t)(i0 + r) * NH + h) * LL + j0 + c4 * 4];
            *(float4*)&atile[r][c4 * 4] = v;
        }
        __syncthreads();
        if (n < 56) {
            for (int j4 = 0; j4 < 32; ++j4) {
                float bv0 = bs[(j4*4+0)*57 + n];
                float bv1 = bs[(j4*4+1)*57 + n];
                float bv2 = bs[(j4*4+2)*57 + n];
                float bv3 = bs[(j4*4+3)*57 + n];
#pragma unroll
                for (int r = 0; r < 2; ++r) {
                    float4 a4 = *(const float4*)&atile[wv * 2 + r][j4 * 4];  // broadcast b128
                    acc[r] = fmaf(a4.x, bv0, acc[r]);
                    acc[r] = fmaf(a4.y, bv1, acc[r]);
                    acc[r] = fmaf(a4.z, bv2, acc[r]);
                    acc[r] = fmaf(a4.w, bv3, acc[r]);
                }
            }
        }
    }
    __syncthreads();
    if (n < 56) {
        if (n < 32) {
#pragma unroll
            for (int r = 0; r < 2; ++r) fa[wv * 2 + r][64 + n] = acc[r];
        } else {
#pragma unroll
            for (int r = 0; r < 2; ++r) sa[wv * 2 + r][n - 32] = acc[r];
        }
    }
    __syncthreads();
    if (tid < 128) {
        const int ri = tid >> 3, p = tid & 7;
        const int i = i0 + ri;
        float d0 = sa[ri][p*3+0] - t[i*3+0];
        float d1 = sa[ri][p*3+1] - t[i*3+1];
        float d2 = sa[ri][p*3+2] - t[i*3+2];
        float f0 = R[i*9+0]*d0 + R[i*9+3]*d1 + R[i*9+6]*d2;
        float f1 = R[i*9+1]*d0 + R[i*9+4]*d1 + R[i*9+7]*d2;
        float f2 = R[i*9+2]*d0 + R[i*9+5]*d1 + R[i*9+8]*d2;
        float dist = sqrtf(f0*f0 + f1*f1 + f2*f2);
        float inv = 1.f / (dist + 1e-4f);
        fa[ri][96 + p*3+0] = f0; fa[ri][96 + p*3+1] = f1; fa[ri][96 + p*3+2] = f2;
        fa[ri][120 + p] = dist;
        fa[ri][128 + p*3+0] = f0*inv; fa[ri][128 + p*3+1] = f1*inv; fa[ri][128 + p*3+2] = f2*inv;
    }
    __syncthreads();

    // out-projection for head h's 152 features. thread = f (128) x rg (4 groups of 4 rows)
    const int f = tid & 127, rg = tid >> 7;
    float o[4] = {};
    const float* fr0 = &fa[rg * 4][0];
    {
        const float* w = Wout + (size_t)(h * 64) * FF + f;          // p2n
        for (int k = 0; k < 64; ++k) {
            float wv_ = w[(size_t)k * FF];
#pragma unroll
            for (int r = 0; r < 4; ++r) o[r] = fmaf(fr0[r * 152 + k], wv_, o[r]);
        }
    }
    {
        const float* w = Wout + (size_t)(768 + h * 32) * FF + f;    // node
        for (int k = 0; k < 32; ++k) {
            float wv_ = w[(size_t)k * FF];
#pragma unroll
            for (int r = 0; r < 4; ++r) o[r] = fmaf(fr0[r * 152 + 64 + k], wv_, o[r]);
        }
    }
    {
        const float* w = Wout + (size_t)(1152 + h * 24) * FF + f;   // fp
        for (int k = 0; k < 24; ++k) {
            float wv_ = w[(size_t)k * FF];
#pragma unroll
            for (int r = 0; r < 4; ++r) o[r] = fmaf(fr0[r * 152 + 96 + k], wv_, o[r]);
        }
    }
    {
        const float* w = Wout + (size_t)(1440 + h * 8) * FF + f;    // dist
        for (int k = 0; k < 8; ++k) {
            float wv_ = w[(size_t)k * FF];
#pragma unroll
            for (int r = 0; r < 4; ++r) o[r] = fmaf(fr0[r * 152 + 120 + k], wv_, o[r]);
        }
    }
    {
        const float* w = Wout + (size_t)(1536 + h * 24) * FF + f;   // dirn
        for (int k = 0; k < 24; ++k) {
            float wv_ = w[(size_t)k * FF];
#pragma unroll
            for (int r = 0; r < 4; ++r) o[r] = fmaf(fr0[r * 152 + 128 + k], wv_, o[r]);
        }
    }
#pragma unroll
    for (int r = 0; r < 4; ++r)
        partial[((size_t)h * LL + i0 + rg * 4 + r) * FF + f] = o[r];
}

// ---------------- K5b: sum 12 partials + LN1 + MLP(split-4) + LN2. grid 384, 512 thr ----------------
__global__ void __launch_bounds__(512) k5b_rowepi(
    const float* __restrict__ partial, const float* __restrict__ bout,
    const float* __restrict__ x,
    const float* __restrict__ ln1g, const float* __restrict__ ln1b,
    const float* __restrict__ W1, const float* __restrict__ b1,
    const float* __restrict__ W2, const float* __restrict__ b2,
    const float* __restrict__ W3, const float* __restrict__ b3,
    const float* __restrict__ ln2g, const float* __restrict__ ln2b,
    float* __restrict__ out) {
    const int i = blockIdx.x, tid = threadIdx.x;
    const int f = tid & 127, q = tid >> 7;   // q 0..3
    __shared__ float prt[4][128];
    __shared__ float x1s[128], hbA[128], hbB[128];
    __shared__ float wrA[2], wrB[2];

    {
        float acc = 0.f;
#pragma unroll
        for (int k = 0; k < 3; ++k)
            acc += partial[((size_t)(q * 3 + k) * LL + i) * FF + f];
        prt[q][f] = acc;
    }
    __syncthreads();

    float s1 = 0.f, dv1 = 0.f;
    if (tid < 128) {
        s1 = prt[0][f] + prt[1][f] + prt[2][f] + prt[3][f] + bout[f] + x[(size_t)i * FF + f];
        float r = s1;
#pragma unroll
        for (int off = 32; off; off >>= 1) r += __shfl_xor(r, off);
        if ((tid & 63) == 0) wrA[tid >> 6] = r;
    }
    __syncthreads();
    if (tid < 128) {
        float mu = (wrA[0] + wrA[1]) * (1.f / FF);
        dv1 = s1 - mu;
        float r = dv1 * dv1;
#pragma unroll
        for (int off = 32; off; off >>= 1) r += __shfl_xor(r, off);
        if ((tid & 63) == 0) wrB[tid >> 6] = r;
    }
    __syncthreads();
    if (tid < 128) {
        float var = (wrB[0] + wrB[1]) * (1.f / FF);
        x1s[f] = dv1 * rsqrtf(var + 1e-5f) * ln1g[f] + ln1b[f];
    }
    __syncthreads();

    {
        const int k0 = q * 32;
        float p0=0,p1=0,p2=0,p3=0;
        for (int k = 0; k < 8; ++k) {
            int d = k0 + k * 4;
            p0 = fmaf(x1s[d+0], W1[(size_t)(d+0)*FF + f], p0);
            p1 = fmaf(x1s[d+1], W1[(size_t)(d+1)*FF + f], p1);
            p2 = fmaf(x1s[d+2], W1[(size_t)(d+2)*FF + f], p2);
            p3 = fmaf(x1s[d+3], W1[(size_t)(d+3)*FF + f], p3);
        }
        prt[q][f] = p0 + p1 + p2 + p3;
    }
    __syncthreads();
    if (tid < 128) hbA[f] = fmaxf(prt[0][f]+prt[1][f]+prt[2][f]+prt[3][f] + b1[f], 0.f);
    __syncthreads();
    {
        const int k0 = q * 32;
        float p0=0,p1=0,p2=0,p3=0;
        for (int k = 0; k < 8; ++k) {
            int d = k0 + k * 4;
            p0 = fmaf(hbA[d+0], W2[(size_t)(d+0)*FF + f], p0);
            p1 = fmaf(hbA[d+1], W2[(size_t)(d+1)*FF + f], p1);
            p2 = fmaf(hbA[d+2], W2[(size_t)(d+2)*FF + f], p2);
            p3 = fmaf(hbA[d+3], W2[(size_t)(d+3)*FF + f], p3);
        }
        prt[q][f] = p0 + p1 + p2 + p3;
    }
    __syncthreads();
    if (tid < 128) hbB[f] = fmaxf(prt[0][f]+prt[1][f]+prt[2][f]+prt[3][f] + b2[f], 0.f);
    __syncthreads();
    {
        const int k0 = q * 32;
        float p0=0,p1=0,p2=0,p3=0;
        for (int k = 0; k < 8; ++k) {
            int d = k0 + k * 4;
            p0 = fmaf(hbB[d+0], W3[(size_t)(d+0)*FF + f], p0);
            p1 = fmaf(hbB[d+1], W3[(size_t)(d+1)*FF + f], p1);
            p2 = fmaf(hbB[d+2], W3[(size_t)(d+2)*FF + f], p2);
            p3 = fmaf(hbB[d+3], W3[(size_t)(d+3)*FF + f], p3);
        }
        prt[q][f] = p0 + p1 + p2 + p3;
    }
    __syncthreads();

    float s2 = 0.f, dv2 = 0.f;
    if (tid < 128) {
        s2 = x1s[f] + prt[0][f]+prt[1][f]+prt[2][f]+prt[3][f] + b3[f];
        float r = s2;
#pragma unroll
        for (int off = 32; off; off >>= 1) r += __shfl_xor(r, off);
        if ((tid & 63) == 0) wrA[tid >> 6] = r;
    }
    __syncthreads();
    if (tid < 128) {
        float mu = (wrA[0] + wrA[1]) * (1.f / FF);
        dv2 = s2 - mu;
        float r = dv2 * dv2;
#pragma unroll
        for (int off = 32; off; off >>= 1) r += __shfl_xor(r, off);
        if ((tid & 63) == 0) wrB[tid >> 6] = r;
    }
    __syncthreads();
    if (tid < 128) {
        float var = (wrB[0] + wrB[1]) * (1.f / FF);
        out[(size_t)i * FF + f] = dv2 * rsqrtf(var + 1e-5f) * ln2g[f] + ln2b[f];
    }
}

extern "C" void kernel_launch(void* const* d_in, const int* in_sizes, int n_in,
                              void* d_out, int out_size, void* d_ws, size_t ws_size,
                              hipStream_t stream) {
    const float* R    = (const float*)d_in[0];
    const float* t    = (const float*)d_in[1];
    const float* x    = (const float*)d_in[2];
    const float* z    = (const float*)d_in[3];
    const float* Wq   = (const float*)d_in[5];
    const float* Wk   = (const float*)d_in[6];
    const float* Wv   = (const float*)d_in[7];
    const float* Wpb  = (const float*)d_in[8];
    const float* spc  = (const float*)d_in[9];
    const float* Wqp  = (const float*)d_in[10];
    const float* Wkp  = (const float*)d_in[11];
    const float* Wvp  = (const float*)d_in[12];
    const float* Wout = (const float*)d_in[13];
    const float* bout = (const float*)d_in[14];
    const float* ln1g = (const float*)d_in[15];
    const float* ln1b = (const float*)d_in[16];
    const float* W1   = (const float*)d_in[17];
    const float* b1   = (const float*)d_in[18];
    const float* W2   = (const float*)d_in[19];
    const float* b2   = (const float*)d_in[20];
    const float* W3   = (const float*)d_in[21];
    const float* b3   = (const float*)d_in[22];
    const float* ln2g = (const float*)d_in[23];
    const float* ln2b = (const float*)d_in[24];
    float* out = (float*)d_out;

    float* ws = (float*)d_ws;
    float* qb   = ws;
    float* kb   = qb   + (size_t)LL * HQK;
    float* vb   = kb   + (size_t)LL * HQK;
    float* qpl  = vb   + (size_t)LL * HV;
    float* kpl  = qpl  + (size_t)LL * HP3;
    float* vpl  = kpl  + (size_t)LL * HP3;
    float* lgA  = vpl  + (size_t)LL * HP3;      // [384][12][384] logits -> alpha
    float* feat = lgA  + (size_t)LL * NH * LL;  // [384][768] p2n only
    float* part = feat + (size_t)LL * P2N;      // [12][384][128]

    k1a_gemm<<<378, 256, 0, stream>>>(x, Wq, Wk, Wv, Wqp, Wkp, Wvp,
                                      qb, kb, vb, qpl, kpl, vpl);
    k3_node<<<dim3(6, 6, 12), 256, 0, stream>>>(qb, kb, qpl, kpl, R, t, spc, lgA);
    k4a_fused<<<LL, 512, 0, stream>>>(z, Wpb, lgA, feat);
    k45_aggproj<<<dim3(24, 12), 512, 0, stream>>>(lgA, vb, vpl, R, t, feat, Wout, part);
    k5b_rowepi<<<LL, 512, 0, stream>>>(part, bout, x, ln1g, ln1b,
                                       W1, b1, W2, b2, W3, b3, ln2g, ln2b, out);
}

// Round 12
// 86.316 us; speedup vs baseline: 8.1429x; 1.0064x over previous
//
#include <hip/hip_runtime.h>
#include <math.h>

constexpr int LL   = 384;
constexpr int FF   = 128;
constexpr int NH   = 12;
constexpr int HQK  = 384;
constexpr int HV   = 384;
constexpr int HP3  = 288;
constexpr int CC   = 64;
constexpr int P2N  = 768;   // p2n feature width

__device__ inline unsigned short f2bf(float f) {
    unsigned int u = __float_as_uint(f);
    return (unsigned short)((u + 0x7fff + ((u >> 16) & 1)) >> 16);
}
__device__ inline float bf2f(unsigned short s) {
    return __uint_as_float(((unsigned int)s) << 16);
}

// ---------------- K1a: six projections (raw local point coords) ----------------
__global__ void __launch_bounds__(256) k1a_gemm(
    const float* __restrict__ x,
    const float* __restrict__ Wq, const float* __restrict__ Wk, const float* __restrict__ Wv,
    const float* __restrict__ Wqp, const float* __restrict__ Wkp, const float* __restrict__ Wvp,
    float* __restrict__ qb, float* __restrict__ kb, float* __restrict__ vb,
    float* __restrict__ qpl, float* __restrict__ kpl, float* __restrict__ vpl) {
    const int bid = blockIdx.x, tid = threadIdx.x;
    const int ct = bid % 63, rt = bid / 63;
    __shared__ float xs[64 * 132];

    const float* W; float* O; int ld, cb;
    if (ct < 12)      { W = Wq;  O = qb;  ld = 384; cb = ct * 32; }
    else if (ct < 24) { W = Wk;  O = kb;  ld = 384; cb = (ct - 12) * 32; }
    else if (ct < 36) { W = Wv;  O = vb;  ld = 384; cb = (ct - 24) * 32; }
    else if (ct < 45) { W = Wqp; O = qpl; ld = 288; cb = (ct - 36) * 32; }
    else if (ct < 54) { W = Wkp; O = kpl; ld = 288; cb = (ct - 45) * 32; }
    else              { W = Wvp; O = vpl; ld = 288; cb = (ct - 54) * 32; }
    const int r0 = rt * 64;

    const float4* xsrc = (const float4*)(x + (size_t)r0 * FF);
#pragma unroll
    for (int k = 0; k < 8; ++k) {
        int idx = tid + k * 256;
        float4 v = xsrc[idx];
        int row = idx >> 5, c4 = (idx & 31) * 4;
        float* d = &xs[row * 132 + c4];
        d[0] = v.x; d[1] = v.y; d[2] = v.z; d[3] = v.w;
    }
    __syncthreads();

    const int cq = (tid & 7) * 4;
    const int rr = (tid >> 3) * 2;
    const float* Wp = W + cb + cq;
    const float* xr0 = &xs[rr * 132];
    const float* xr1 = &xs[(rr + 1) * 132];
    float a00=0,a01=0,a02=0,a03=0, a10=0,a11=0,a12=0,a13=0;
#pragma unroll 2
    for (int f4 = 0; f4 < FF; f4 += 4) {
        float4 xa4 = *(const float4*)(xr0 + f4);
        float4 xb4 = *(const float4*)(xr1 + f4);
        float4 w0 = *(const float4*)(Wp + (size_t)(f4+0) * ld);
        float4 w1 = *(const float4*)(Wp + (size_t)(f4+1) * ld);
        float4 w2 = *(const float4*)(Wp + (size_t)(f4+2) * ld);
        float4 w3 = *(const float4*)(Wp + (size_t)(f4+3) * ld);
        a00 = fmaf(xa4.x, w0.x, a00); a01 = fmaf(xa4.x, w0.y, a01);
        a02 = fmaf(xa4.x, w0.z, a02); a03 = fmaf(xa4.x, w0.w, a03);
        a10 = fmaf(xb4.x, w0.x, a10); a11 = fmaf(xb4.x, w0.y, a11);
        a12 = fmaf(xb4.x, w0.z, a12); a13 = fmaf(xb4.x, w0.w, a13);
        a00 = fmaf(xa4.y, w1.x, a00); a01 = fmaf(xa4.y, w1.y, a01);
        a02 = fmaf(xa4.y, w1.z, a02); a03 = fmaf(xa4.y, w1.w, a03);
        a10 = fmaf(xb4.y, w1.x, a10); a11 = fmaf(xb4.y, w1.y, a11);
        a12 = fmaf(xb4.y, w1.z, a12); a13 = fmaf(xb4.y, w1.w, a13);
        a00 = fmaf(xa4.z, w2.x, a00); a01 = fmaf(xa4.z, w2.y, a01);
        a02 = fmaf(xa4.z, w2.z, a02); a03 = fmaf(xa4.z, w2.w, a03);
        a10 = fmaf(xb4.z, w2.x, a10); a11 = fmaf(xb4.z, w2.y, a11);
        a12 = fmaf(xb4.z, w2.z, a12); a13 = fmaf(xb4.z, w2.w, a13);
        a00 = fmaf(xa4.w, w3.x, a00); a01 = fmaf(xa4.w, w3.y, a01);
        a02 = fmaf(xa4.w, w3.z, a02); a03 = fmaf(xa4.w, w3.w, a03);
        a10 = fmaf(xb4.w, w3.x, a10); a11 = fmaf(xb4.w, w3.y, a11);
        a12 = fmaf(xb4.w, w3.z, a12); a13 = fmaf(xb4.w, w3.w, a13);
    }
    float* o0 = O + (size_t)(r0 + rr) * ld + cb + cq;
    float* o1 = o0 + ld;
    o0[0]=a00; o0[1]=a01; o0[2]=a02; o0[3]=a03;
    o1[0]=a10; o1[1]=a11; o1[2]=a12; o1[3]=a13;
}

// ---------------- K3: node+spatial logits; rigid transform + norms inlined ----------------
__global__ void __launch_bounds__(256) k3_node(
    const float* __restrict__ qb, const float* __restrict__ kb,
    const float* __restrict__ qpl, const float* __restrict__ kpl,
    const float* __restrict__ R, const float* __restrict__ t,
    const float* __restrict__ spc, float* __restrict__ lgN) {
    const int it = blockIdx.x, jt = blockIdx.y, h = blockIdx.z;
    const int tid = threadIdx.x;
    __shared__ float As[64 * 60];
    __shared__ float Bs[64 * 60];
    __shared__ float pnA[512], pnB[512];
    const float g = log1pf(expf(spc[h]));
    const float s3 = 0.5773502691896258f;
    const float c1 = s3 * 0.17677669529663687f;
    const float c2 = s3 * g * (1.f / 6.f);
    const float c3 = -s3 * g * (1.f / 12.f);
    const int i0 = it * 64, j0 = jt * 64;

    for (int idx = tid; idx < 2048; idx += 256) {
        int r = idx >> 5, c = idx & 31;
        As[r*60 + c] = qb[(size_t)(i0 + r) * HQK + h*32 + c];
        Bs[r*60 + c] = kb[(size_t)(j0 + r) * HQK + h*32 + c] * c1;
    }
    for (int idx = tid; idx < 1024; idx += 256) {
        const int side = idx >> 9, rem = idx & 511;
        const int r = rem >> 3, p = rem & 7;
        const int row = (side ? j0 : i0) + r;
        const float* P = side ? kpl : qpl;
        const float* lp = P + (size_t)row * HP3 + (h*8 + p) * 3;
        float l0 = lp[0], l1 = lp[1], l2 = lp[2];
        float g0 = fmaf(R[row*9+0], l0, fmaf(R[row*9+1], l1, fmaf(R[row*9+2], l2, t[row*3+0])));
        float g1 = fmaf(R[row*9+3], l0, fmaf(R[row*9+4], l1, fmaf(R[row*9+5], l2, t[row*3+1])));
        float g2 = fmaf(R[row*9+6], l0, fmaf(R[row*9+7], l1, fmaf(R[row*9+8], l2, t[row*3+2])));
        float nn = g0*g0 + g1*g1 + g2*g2;
        if (side == 0) {
            float* d = &As[r*60 + 32 + p*3];
            d[0] = g0 * c2; d[1] = g1 * c2; d[2] = g2 * c2;
            pnA[r*8 + p] = nn;
        } else {
            float* d = &Bs[r*60 + 32 + p*3];
            d[0] = g0; d[1] = g1; d[2] = g2;
            pnB[r*8 + p] = nn;
        }
    }
    __syncthreads();
    if (tid < 64) {
        float s = 0.f;
#pragma unroll
        for (int p = 0; p < 8; ++p) s += pnA[tid*8 + p];
        As[tid*60 + 56] = s * c3;
        As[tid*60 + 57] = 1.f;
        As[tid*60 + 58] = 0.f; As[tid*60 + 59] = 0.f;
    } else if (tid < 128) {
        const int r = tid - 64;
        float s = 0.f;
#pragma unroll
        for (int p = 0; p < 8; ++p) s += pnB[r*8 + p];
        Bs[r*60 + 56] = 1.f;
        Bs[r*60 + 57] = s * c3;
        Bs[r*60 + 58] = 0.f; Bs[r*60 + 59] = 0.f;
    }
    __syncthreads();

    const int tx = tid & 15, ty = tid >> 4;
    float acc[4][4] = {};
    for (int k4 = 0; k4 < 60; k4 += 4) {
        float4 a[4], b[4];
#pragma unroll
        for (int r = 0; r < 4; ++r) a[r] = *(const float4*)&As[(ty*4 + r)*60 + k4];
#pragma unroll
        for (int c = 0; c < 4; ++c) b[c] = *(const float4*)&Bs[(tx*4 + c)*60 + k4];
#pragma unroll
        for (int r = 0; r < 4; ++r)
#pragma unroll
            for (int c = 0; c < 4; ++c) {
                acc[r][c] = fmaf(a[r].x, b[c].x, acc[r][c]);
                acc[r][c] = fmaf(a[r].y, b[c].y, acc[r][c]);
                acc[r][c] = fmaf(a[r].z, b[c].z, acc[r][c]);
                acc[r][c] = fmaf(a[r].w, b[c].w, acc[r][c]);
            }
    }
#pragma unroll
    for (int r = 0; r < 4; ++r)
        *(float4*)&lgN[((size_t)(i0 + ty*4 + r) * NH + h) * LL + j0 + tx*4] =
            make_float4(acc[r][0], acc[r][1], acc[r][2], acc[r][3]);
}

// ---------------- K4a: pair term + softmax + p2n; alpha out as bf16 ----------------
__global__ void __launch_bounds__(512, 4) k4a_fused(
    const float* __restrict__ z, const float* __restrict__ Wpb,
    const float* __restrict__ lgA, unsigned short* __restrict__ albf,
    float* __restrict__ feat) {
    const int i = blockIdx.x, tid = threadIdx.x;
    __shared__ __align__(16) unsigned char zu[384 * 68 * 2];
    unsigned short* z_s = (unsigned short*)zu;
    float* red = (float*)zu;
    __shared__ float a_s[NH * 384];
    __shared__ float wpb_s[CC * NH];

    const float4* zsrc = (const float4*)(z + (size_t)i * (LL * CC));
#pragma unroll
    for (int k = 0; k < 12; ++k) {
        int idx = tid + k * 512;
        float4 v = zsrc[idx];
        int j = idx >> 4, c4 = idx & 15;
        ushort4 pk;
        pk.x = f2bf(v.x); pk.y = f2bf(v.y); pk.z = f2bf(v.z); pk.w = f2bf(v.w);
        *(ushort4*)&z_s[j * 68 + c4 * 4] = pk;
    }
    if (tid < 384) {
        wpb_s[tid] = Wpb[tid];
        if (tid < CC * NH - 384) wpb_s[384 + tid] = Wpb[384 + tid];
    }
    __syncthreads();

    if (tid < 384) {
        const int j = tid;
        float pacc[12] = {};
        const unsigned short* zrow = &z_s[j * 68];
#pragma unroll
        for (int c4 = 0; c4 < 16; ++c4) {
            ushort4 zz = *(const ushort4*)&zrow[c4 * 4];
            float z0 = bf2f(zz.x), z1 = bf2f(zz.y), z2 = bf2f(zz.z), z3 = bf2f(zz.w);
            const float* wp = wpb_s + c4 * 4 * NH;
#pragma unroll
            for (int hh = 0; hh < 12; ++hh) {
                float p = pacc[hh];
                p = fmaf(z0, wp[hh], p);
                p = fmaf(z1, wp[NH + hh], p);
                p = fmaf(z2, wp[2*NH + hh], p);
                p = fmaf(z3, wp[3*NH + hh], p);
                pacc[hh] = p;
            }
        }
        const float s3 = 0.5773502691896258f;
#pragma unroll
        for (int hh = 0; hh < 12; ++hh)
            a_s[hh * 384 + j] = lgA[((size_t)i * NH + hh) * LL + j] + pacc[hh] * s3;
    }
    __syncthreads();

    const int wv = tid >> 6, lane = tid & 63;
    if (wv < 6) {
#pragma unroll
        for (int rr = 0; rr < 2; ++rr) {
            const int h = wv * 2 + rr;
            float v[6];
#pragma unroll
            for (int k = 0; k < 6; ++k) v[k] = a_s[h * 384 + lane + k * 64];
            float m = v[0];
#pragma unroll
            for (int k = 1; k < 6; ++k) m = fmaxf(m, v[k]);
#pragma unroll
            for (int off = 32; off; off >>= 1) m = fmaxf(m, __shfl_xor(m, off));
            float s = 0.f;
#pragma unroll
            for (int k = 0; k < 6; ++k) { v[k] = expf(v[k] - m); s += v[k]; }
#pragma unroll
            for (int off = 32; off; off >>= 1) s += __shfl_xor(s, off);
            float inv = 1.f / s;
            unsigned short* arow = albf + ((size_t)i * NH + h) * LL;
#pragma unroll
            for (int k = 0; k < 6; ++k) {
                float a = v[k] * inv;
                a_s[h * 384 + lane + k * 64] = a;
                arow[lane + k * 64] = f2bf(a);
            }
        }
    }
    __syncthreads();

    const int c4 = tid & 15, jc = tid >> 4;
    float4 acc[12] = {};
    const int jbase = jc * 12;
#pragma unroll
    for (int j4 = 0; j4 < 3; ++j4) {
        const int j = jbase + j4 * 4;
        float zv[4][4];
#pragma unroll
        for (int jj = 0; jj < 4; ++jj) {
            ushort4 zz = *(const ushort4*)&z_s[(j + jj) * 68 + c4 * 4];
            zv[jj][0] = bf2f(zz.x); zv[jj][1] = bf2f(zz.y);
            zv[jj][2] = bf2f(zz.z); zv[jj][3] = bf2f(zz.w);
        }
#pragma unroll
        for (int hh = 0; hh < 12; ++hh) {
            float4 a4 = *(const float4*)&a_s[hh * 384 + j];
            acc[hh].x = fmaf(a4.x, zv[0][0], acc[hh].x); acc[hh].y = fmaf(a4.x, zv[0][1], acc[hh].y);
            acc[hh].z = fmaf(a4.x, zv[0][2], acc[hh].z); acc[hh].w = fmaf(a4.x, zv[0][3], acc[hh].w);
            acc[hh].x = fmaf(a4.y, zv[1][0], acc[hh].x); acc[hh].y = fmaf(a4.y, zv[1][1], acc[hh].y);
            acc[hh].z = fmaf(a4.y, zv[1][2], acc[hh].z); acc[hh].w = fmaf(a4.y, zv[1][3], acc[hh].w);
            acc[hh].x = fmaf(a4.z, zv[2][0], acc[hh].x); acc[hh].y = fmaf(a4.z, zv[2][1], acc[hh].y);
            acc[hh].z = fmaf(a4.z, zv[2][2], acc[hh].z); acc[hh].w = fmaf(a4.z, zv[2][3], acc[hh].w);
            acc[hh].x = fmaf(a4.w, zv[3][0], acc[hh].x); acc[hh].y = fmaf(a4.w, zv[3][1], acc[hh].y);
            acc[hh].z = fmaf(a4.w, zv[3][2], acc[hh].z); acc[hh].w = fmaf(a4.w, zv[3][3], acc[hh].w);
        }
    }
    __syncthreads();   // z_s reads done; red aliases z_s
#pragma unroll
    for (int hh = 0; hh < 12; ++hh) {
        acc[hh].x += __shfl_xor(acc[hh].x, 16); acc[hh].y += __shfl_xor(acc[hh].y, 16);
        acc[hh].z += __shfl_xor(acc[hh].z, 16); acc[hh].w += __shfl_xor(acc[hh].w, 16);
        acc[hh].x += __shfl_xor(acc[hh].x, 32); acc[hh].y += __shfl_xor(acc[hh].y, 32);
        acc[hh].z += __shfl_xor(acc[hh].z, 32); acc[hh].w += __shfl_xor(acc[hh].w, 32);
    }
    if (lane < 16) {
#pragma unroll
        for (int hh = 0; hh < 12; ++hh)
            *(float4*)&red[wv * 768 + hh * 64 + lane * 4] = acc[hh];
    }
    __syncthreads();
    if (tid < 192) {
        int hh = tid >> 4, cc = tid & 15;
        float4 s = make_float4(0.f, 0.f, 0.f, 0.f);
#pragma unroll
        for (int w = 0; w < 8; ++w) {
            float4 p = *(const float4*)&red[w * 768 + hh * 64 + cc * 4];
            s.x += p.x; s.y += p.y; s.z += p.z; s.w += p.w;
        }
        *(float4*)&feat[(size_t)i * P2N + hh * 64 + cc * 4] = s;
    }
}

// ---------------- K45: aggregation + frame transform + per-head out-proj ----------------
// grid (24 it, 12 h), 512 thr; alpha staged bf16 -> fp32 LDS; LDS ~44KB -> 3 blocks/CU.
__global__ void __launch_bounds__(512) k45_aggproj(
    const unsigned short* __restrict__ albf, const float* __restrict__ vb,
    const float* __restrict__ vpl, const float* __restrict__ R,
    const float* __restrict__ t, const float* __restrict__ feat,
    const float* __restrict__ Wout, float* __restrict__ partial) {
    const int it = blockIdx.x, h = blockIdx.y;
    const int tid = threadIdx.x;
    __shared__ float bs[128 * 57];         // 29.2 KB
    __shared__ float atile[16][128];       // 8 KB
    __shared__ float fa[16][152];          // 9.7 KB
    __shared__ float sa[16][24];           // 1.5 KB
    const int i0 = it * 16;
    const int wv = __builtin_amdgcn_readfirstlane(tid >> 6);
    const int n = tid & 63;

    if (tid < 256) {
        int r = tid >> 4, c4 = tid & 15;
        float4 v = *(const float4*)&feat[(size_t)(i0 + r) * P2N + h * 64 + c4 * 4];
        *(float4*)&fa[r][c4 * 4] = v;
    }

    float acc[2] = {0.f, 0.f};
    for (int tile = 0; tile < 3; ++tile) {
        const int j0 = tile * 128;
        __syncthreads();
        for (int idx = tid; idx < 2048; idx += 512) {
            if (idx < 1024) {
                int jr = idx >> 3, q = idx & 7;
                const float* src = vb + (size_t)(j0 + jr) * HV + h * 32 + q * 4;
                float* d = &bs[jr * 57 + q * 4];
                d[0] = src[0]; d[1] = src[1]; d[2] = src[2]; d[3] = src[3];
            } else {
                int id2 = idx - 1024;
                int jr = id2 >> 3, p = id2 & 7;
                const int row = j0 + jr;
                const float* lp = vpl + (size_t)row * HP3 + (h*8 + p) * 3;
                float l0 = lp[0], l1 = lp[1], l2 = lp[2];
                float g0 = fmaf(R[row*9+0], l0, fmaf(R[row*9+1], l1, fmaf(R[row*9+2], l2, t[row*3+0])));
                float g1 = fmaf(R[row*9+3], l0, fmaf(R[row*9+4], l1, fmaf(R[row*9+5], l2, t[row*3+1])));
                float g2 = fmaf(R[row*9+6], l0, fmaf(R[row*9+7], l1, fmaf(R[row*9+8], l2, t[row*3+2])));
                float* d = &bs[jr * 57 + 32 + p * 3];
                d[0] = g0; d[1] = g1; d[2] = g2;
            }
        }
        // stage alpha tile bf16 -> fp32: 16 rows x 128 j
        {
            int r = tid >> 5, c8 = tid & 31;
            ushort4 v = *(const ushort4*)&albf[((size_t)(i0 + r) * NH + h) * LL + j0 + c8 * 4];
            float* d = &atile[r][c8 * 4];
            d[0] = bf2f(v.x); d[1] = bf2f(v.y); d[2] = bf2f(v.z); d[3] = bf2f(v.w);
        }
        __syncthreads();
        if (n < 56) {
            for (int j4 = 0; j4 < 32; ++j4) {
                float bv0 = bs[(j4*4+0)*57 + n];
                float bv1 = bs[(j4*4+1)*57 + n];
                float bv2 = bs[(j4*4+2)*57 + n];
                float bv3 = bs[(j4*4+3)*57 + n];
#pragma unroll
                for (int r = 0; r < 2; ++r) {
                    float4 a4 = *(const float4*)&atile[wv * 2 + r][j4 * 4];
                    acc[r] = fmaf(a4.x, bv0, acc[r]);
                    acc[r] = fmaf(a4.y, bv1, acc[r]);
                    acc[r] = fmaf(a4.z, bv2, acc[r]);
                    acc[r] = fmaf(a4.w, bv3, acc[r]);
                }
            }
        }
    }
    __syncthreads();
    if (n < 56) {
        if (n < 32) {
#pragma unroll
            for (int r = 0; r < 2; ++r) fa[wv * 2 + r][64 + n] = acc[r];
        } else {
#pragma unroll
            for (int r = 0; r < 2; ++r) sa[wv * 2 + r][n - 32] = acc[r];
        }
    }
    __syncthreads();
    if (tid < 128) {
        const int ri = tid >> 3, p = tid & 7;
        const int i = i0 + ri;
        float d0 = sa[ri][p*3+0] - t[i*3+0];
        float d1 = sa[ri][p*3+1] - t[i*3+1];
        float d2 = sa[ri][p*3+2] - t[i*3+2];
        float f0 = R[i*9+0]*d0 + R[i*9+3]*d1 + R[i*9+6]*d2;
        float f1 = R[i*9+1]*d0 + R[i*9+4]*d1 + R[i*9+7]*d2;
        float f2 = R[i*9+2]*d0 + R[i*9+5]*d1 + R[i*9+8]*d2;
        float dist = sqrtf(f0*f0 + f1*f1 + f2*f2);
        float inv = 1.f / (dist + 1e-4f);
        fa[ri][96 + p*3+0] = f0; fa[ri][96 + p*3+1] = f1; fa[ri][96 + p*3+2] = f2;
        fa[ri][120 + p] = dist;
        fa[ri][128 + p*3+0] = f0*inv; fa[ri][128 + p*3+1] = f1*inv; fa[ri][128 + p*3+2] = f2*inv;
    }
    __syncthreads();

    const int f = tid & 127, rg = tid >> 7;
    float o[4] = {};
    const float* fr0 = &fa[rg * 4][0];
    {
        const float* w = Wout + (size_t)(h * 64) * FF + f;          // p2n
        for (int k = 0; k < 64; ++k) {
            float wv_ = w[(size_t)k * FF];
#pragma unroll
            for (int r = 0; r < 4; ++r) o[r] = fmaf(fr0[r * 152 + k], wv_, o[r]);
        }
    }
    {
        const float* w = Wout + (size_t)(768 + h * 32) * FF + f;    // node
        for (int k = 0; k < 32; ++k) {
            float wv_ = w[(size_t)k * FF];
#pragma unroll
            for (int r = 0; r < 4; ++r) o[r] = fmaf(fr0[r * 152 + 64 + k], wv_, o[r]);
        }
    }
    {
        const float* w = Wout + (size_t)(1152 + h * 24) * FF + f;   // fp
        for (int k = 0; k < 24; ++k) {
            float wv_ = w[(size_t)k * FF];
#pragma unroll
            for (int r = 0; r < 4; ++r) o[r] = fmaf(fr0[r * 152 + 96 + k], wv_, o[r]);
        }
    }
    {
        const float* w = Wout + (size_t)(1440 + h * 8) * FF + f;    // dist
        for (int k = 0; k < 8; ++k) {
            float wv_ = w[(size_t)k * FF];
#pragma unroll
            for (int r = 0; r < 4; ++r) o[r] = fmaf(fr0[r * 152 + 120 + k], wv_, o[r]);
        }
    }
    {
        const float* w = Wout + (size_t)(1536 + h * 24) * FF + f;   // dirn
        for (int k = 0; k < 24; ++k) {
            float wv_ = w[(size_t)k * FF];
#pragma unroll
            for (int r = 0; r < 4; ++r) o[r] = fmaf(fr0[r * 152 + 128 + k], wv_, o[r]);
        }
    }
#pragma unroll
    for (int r = 0; r < 4; ++r)
        partial[((size_t)h * LL + i0 + rg * 4 + r) * FF + f] = o[r];
}

// ---------------- K5b: sum 12 partials + LN1 + MLP(split-4) + LN2 ----------------
__global__ void __launch_bounds__(512) k5b_rowepi(
    const float* __restrict__ partial, const float* __restrict__ bout,
    const float* __restrict__ x,
    const float* __restrict__ ln1g, const float* __restrict__ ln1b,
    const float* __restrict__ W1, const float* __restrict__ b1,
    const float* __restrict__ W2, const float* __restrict__ b2,
    const float* __restrict__ W3, const float* __restrict__ b3,
    const float* __restrict__ ln2g, const float* __restrict__ ln2b,
    float* __restrict__ out) {
    const int i = blockIdx.x, tid = threadIdx.x;
    const int f = tid & 127, q = tid >> 7;
    __shared__ float prt[4][128];
    __shared__ float x1s[128], hbA[128], hbB[128];
    __shared__ float wrA[2], wrB[2];

    {
        float acc = 0.f;
#pragma unroll
        for (int k = 0; k < 3; ++k)
            acc += partial[((size_t)(q * 3 + k) * LL + i) * FF + f];
        prt[q][f] = acc;
    }
    __syncthreads();

    float s1 = 0.f, dv1 = 0.f;
    if (tid < 128) {
        s1 = prt[0][f] + prt[1][f] + prt[2][f] + prt[3][f] + bout[f] + x[(size_t)i * FF + f];
        float r = s1;
#pragma unroll
        for (int off = 32; off; off >>= 1) r += __shfl_xor(r, off);
        if ((tid & 63) == 0) wrA[tid >> 6] = r;
    }
    __syncthreads();
    if (tid < 128) {
        float mu = (wrA[0] + wrA[1]) * (1.f / FF);
        dv1 = s1 - mu;
        float r = dv1 * dv1;
#pragma unroll
        for (int off = 32; off; off >>= 1) r += __shfl_xor(r, off);
        if ((tid & 63) == 0) wrB[tid >> 6] = r;
    }
    __syncthreads();
    if (tid < 128) {
        float var = (wrB[0] + wrB[1]) * (1.f / FF);
        x1s[f] = dv1 * rsqrtf(var + 1e-5f) * ln1g[f] + ln1b[f];
    }
    __syncthreads();

    {
        const int k0 = q * 32;
        float p0=0,p1=0,p2=0,p3=0;
        for (int k = 0; k < 8; ++k) {
            int d = k0 + k * 4;
            p0 = fmaf(x1s[d+0], W1[(size_t)(d+0)*FF + f], p0);
            p1 = fmaf(x1s[d+1], W1[(size_t)(d+1)*FF + f], p1);
            p2 = fmaf(x1s[d+2], W1[(size_t)(d+2)*FF + f], p2);
            p3 = fmaf(x1s[d+3], W1[(size_t)(d+3)*FF + f], p3);
        }
        prt[q][f] = p0 + p1 + p2 + p3;
    }
    __syncthreads();
    if (tid < 128) hbA[f] = fmaxf(prt[0][f]+prt[1][f]+prt[2][f]+prt[3][f] + b1[f], 0.f);
    __syncthreads();
    {
        const int k0 = q * 32;
        float p0=0,p1=0,p2=0,p3=0;
        for (int k = 0; k < 8; ++k) {
            int d = k0 + k * 4;
            p0 = fmaf(hbA[d+0], W2[(size_t)(d+0)*FF + f], p0);
            p1 = fmaf(hbA[d+1], W2[(size_t)(d+1)*FF + f], p1);
            p2 = fmaf(hbA[d+2], W2[(size_t)(d+2)*FF + f], p2);
            p3 = fmaf(hbA[d+3], W2[(size_t)(d+3)*FF + f], p3);
        }
        prt[q][f] = p0 + p1 + p2 + p3;
    }
    __syncthreads();
    if (tid < 128) hbB[f] = fmaxf(prt[0][f]+prt[1][f]+prt[2][f]+prt[3][f] + b2[f], 0.f);
    __syncthreads();
    {
        const int k0 = q * 32;
        float p0=0,p1=0,p2=0,p3=0;
        for (int k = 0; k < 8; ++k) {
            int d = k0 + k * 4;
            p0 = fmaf(hbB[d+0], W3[(size_t)(d+0)*FF + f], p0);
            p1 = fmaf(hbB[d+1], W3[(size_t)(d+1)*FF + f], p1);
            p2 = fmaf(hbB[d+2], W3[(size_t)(d+2)*FF + f], p2);
            p3 = fmaf(hbB[d+3], W3[(size_t)(d+3)*FF + f], p3);
        }
        prt[q][f] = p0 + p1 + p2 + p3;
    }
    __syncthreads();

    float s2 = 0.f, dv2 = 0.f;
    if (tid < 128) {
        s2 = x1s[f] + prt[0][f]+prt[1][f]+prt[2][f]+prt[3][f] + b3[f];
        float r = s2;
#pragma unroll
        for (int off = 32; off; off >>= 1) r += __shfl_xor(r, off);
        if ((tid & 63) == 0) wrA[tid >> 6] = r;
    }
    __syncthreads();
    if (tid < 128) {
        float mu = (wrA[0] + wrA[1]) * (1.f / FF);
        dv2 = s2 - mu;
        float r = dv2 * dv2;
#pragma unroll
        for (int off = 32; off; off >>= 1) r += __shfl_xor(r, off);
        if ((tid & 63) == 0) wrB[tid >> 6] = r;
    }
    __syncthreads();
    if (tid < 128) {
        float var = (wrB[0] + wrB[1]) * (1.f / FF);
        out[(size_t)i * FF + f] = dv2 * rsqrtf(var + 1e-5f) * ln2g[f] + ln2b[f];
    }
}

extern "C" void kernel_launch(void* const* d_in, const int* in_sizes, int n_in,
                              void* d_out, int out_size, void* d_ws, size_t ws_size,
                              hipStream_t stream) {
    const float* R    = (const float*)d_in[0];
    const float* t    = (const float*)d_in[1];
    const float* x    = (const float*)d_in[2];
    const float* z    = (const float*)d_in[3];
    const float* Wq   = (const float*)d_in[5];
    const float* Wk   = (const float*)d_in[6];
    const float* Wv   = (const float*)d_in[7];
    const float* Wpb  = (const float*)d_in[8];
    const float* spc  = (const float*)d_in[9];
    const float* Wqp  = (const float*)d_in[10];
    const float* Wkp  = (const float*)d_in[11];
    const float* Wvp  = (const float*)d_in[12];
    const float* Wout = (const float*)d_in[13];
    const float* bout = (const float*)d_in[14];
    const float* ln1g = (const float*)d_in[15];
    const float* ln1b = (const float*)d_in[16];
    const float* W1   = (const float*)d_in[17];
    const float* b1   = (const float*)d_in[18];
    const float* W2   = (const float*)d_in[19];
    const float* b2   = (const float*)d_in[20];
    const float* W3   = (const float*)d_in[21];
    const float* b3   = (const float*)d_in[22];
    const float* ln2g = (const float*)d_in[23];
    const float* ln2b = (const float*)d_in[24];
    float* out = (float*)d_out;

    float* ws = (float*)d_ws;
    float* qb   = ws;
    float* kb   = qb   + (size_t)LL * HQK;
    float* vb   = kb   + (size_t)LL * HQK;
    float* qpl  = vb   + (size_t)LL * HV;
    float* kpl  = qpl  + (size_t)LL * HP3;
    float* vpl  = kpl  + (size_t)LL * HP3;
    float* lgA  = vpl  + (size_t)LL * HP3;      // [384][12][384] node+spatial logits
    float* feat = lgA  + (size_t)LL * NH * LL;  // [384][768] p2n only
    float* part = feat + (size_t)LL * P2N;      // [12][384][128]
    unsigned short* albf = (unsigned short*)(part + (size_t)NH * LL * FF);  // bf16 alpha

    k1a_gemm<<<378, 256, 0, stream>>>(x, Wq, Wk, Wv, Wqp, Wkp, Wvp,
                                      qb, kb, vb, qpl, kpl, vpl);
    k3_node<<<dim3(6, 6, 12), 256, 0, stream>>>(qb, kb, qpl, kpl, R, t, spc, lgA);
    k4a_fused<<<LL, 512, 0, stream>>>(z, Wpb, lgA, albf, feat);
    k45_aggproj<<<dim3(24, 12), 512, 0, stream>>>(albf, vb, vpl, R, t, feat, Wout, part);
    k5b_rowepi<<<LL, 512, 0, stream>>>(part, bout, x, ln1g, ln1b,
                                       W1, b1, W2, b2, W3, b3, ln2g, ln2b, out);
}

// Round 13
// 80.191 us; speedup vs baseline: 8.7649x; 1.0764x over previous
//
#include <hip/hip_runtime.h>
#include <math.h>

constexpr int LL   = 384;
constexpr int FF   = 128;
constexpr int NH   = 12;
constexpr int HQK  = 384;
constexpr int HV   = 384;
constexpr int HP3  = 288;
constexpr int CC   = 64;
constexpr int P2N  = 768;   // p2n feature width

__device__ inline unsigned short f2bf(float f) {
    unsigned int u = __float_as_uint(f);
    return (unsigned short)((u + 0x7fff + ((u >> 16) & 1)) >> 16);
}
__device__ inline float bf2f(unsigned short s) {
    return __uint_as_float(((unsigned int)s) << 16);
}

// ---------------- K1a: six projections (raw local point coords) ----------------
__global__ void __launch_bounds__(256) k1a_gemm(
    const float* __restrict__ x,
    const float* __restrict__ Wq, const float* __restrict__ Wk, const float* __restrict__ Wv,
    const float* __restrict__ Wqp, const float* __restrict__ Wkp, const float* __restrict__ Wvp,
    float* __restrict__ qb, float* __restrict__ kb, float* __restrict__ vb,
    float* __restrict__ qpl, float* __restrict__ kpl, float* __restrict__ vpl) {
    const int bid = blockIdx.x, tid = threadIdx.x;
    const int ct = bid % 63, rt = bid / 63;
    __shared__ float xs[64 * 132];

    const float* W; float* O; int ld, cb;
    if (ct < 12)      { W = Wq;  O = qb;  ld = 384; cb = ct * 32; }
    else if (ct < 24) { W = Wk;  O = kb;  ld = 384; cb = (ct - 12) * 32; }
    else if (ct < 36) { W = Wv;  O = vb;  ld = 384; cb = (ct - 24) * 32; }
    else if (ct < 45) { W = Wqp; O = qpl; ld = 288; cb = (ct - 36) * 32; }
    else if (ct < 54) { W = Wkp; O = kpl; ld = 288; cb = (ct - 45) * 32; }
    else              { W = Wvp; O = vpl; ld = 288; cb = (ct - 54) * 32; }
    const int r0 = rt * 64;

    const float4* xsrc = (const float4*)(x + (size_t)r0 * FF);
#pragma unroll
    for (int k = 0; k < 8; ++k) {
        int idx = tid + k * 256;
        float4 v = xsrc[idx];
        int row = idx >> 5, c4 = (idx & 31) * 4;
        float* d = &xs[row * 132 + c4];
        d[0] = v.x; d[1] = v.y; d[2] = v.z; d[3] = v.w;
    }
    __syncthreads();

    const int cq = (tid & 7) * 4;
    const int rr = (tid >> 3) * 2;
    const float* Wp = W + cb + cq;
    const float* xr0 = &xs[rr * 132];
    const float* xr1 = &xs[(rr + 1) * 132];
    float a00=0,a01=0,a02=0,a03=0, a10=0,a11=0,a12=0,a13=0;
#pragma unroll 2
    for (int f4 = 0; f4 < FF; f4 += 4) {
        float4 xa4 = *(const float4*)(xr0 + f4);
        float4 xb4 = *(const float4*)(xr1 + f4);
        float4 w0 = *(const float4*)(Wp + (size_t)(f4+0) * ld);
        float4 w1 = *(const float4*)(Wp + (size_t)(f4+1) * ld);
        float4 w2 = *(const float4*)(Wp + (size_t)(f4+2) * ld);
        float4 w3 = *(const float4*)(Wp + (size_t)(f4+3) * ld);
        a00 = fmaf(xa4.x, w0.x, a00); a01 = fmaf(xa4.x, w0.y, a01);
        a02 = fmaf(xa4.x, w0.z, a02); a03 = fmaf(xa4.x, w0.w, a03);
        a10 = fmaf(xb4.x, w0.x, a10); a11 = fmaf(xb4.x, w0.y, a11);
        a12 = fmaf(xb4.x, w0.z, a12); a13 = fmaf(xb4.x, w0.w, a13);
        a00 = fmaf(xa4.y, w1.x, a00); a01 = fmaf(xa4.y, w1.y, a01);
        a02 = fmaf(xa4.y, w1.z, a02); a03 = fmaf(xa4.y, w1.w, a03);
        a10 = fmaf(xb4.y, w1.x, a10); a11 = fmaf(xb4.y, w1.y, a11);
        a12 = fmaf(xb4.y, w1.z, a12); a13 = fmaf(xb4.y, w1.w, a13);
        a00 = fmaf(xa4.z, w2.x, a00); a01 = fmaf(xa4.z, w2.y, a01);
        a02 = fmaf(xa4.z, w2.z, a02); a03 = fmaf(xa4.z, w2.w, a03);
        a10 = fmaf(xb4.z, w2.x, a10); a11 = fmaf(xb4.z, w2.y, a11);
        a12 = fmaf(xb4.z, w2.z, a12); a13 = fmaf(xb4.z, w2.w, a13);
        a00 = fmaf(xa4.w, w3.x, a00); a01 = fmaf(xa4.w, w3.y, a01);
        a02 = fmaf(xa4.w, w3.z, a02); a03 = fmaf(xa4.w, w3.w, a03);
        a10 = fmaf(xb4.w, w3.x, a10); a11 = fmaf(xb4.w, w3.y, a11);
        a12 = fmaf(xb4.w, w3.z, a12); a13 = fmaf(xb4.w, w3.w, a13);
    }
    float* o0 = O + (size_t)(r0 + rr) * ld + cb + cq;
    float* o1 = o0 + ld;
    o0[0]=a00; o0[1]=a01; o0[2]=a02; o0[3]=a03;
    o1[0]=a10; o1[1]=a11; o1[2]=a12; o1[3]=a13;
}

// ---------------- K3: node+spatial logits; rigid transform + norms inlined ----------------
__global__ void __launch_bounds__(256) k3_node(
    const float* __restrict__ qb, const float* __restrict__ kb,
    const float* __restrict__ qpl, const float* __restrict__ kpl,
    const float* __restrict__ R, const float* __restrict__ t,
    const float* __restrict__ spc, float* __restrict__ lgN) {
    const int it = blockIdx.x, jt = blockIdx.y, h = blockIdx.z;
    const int tid = threadIdx.x;
    __shared__ float As[64 * 60];
    __shared__ float Bs[64 * 60];
    __shared__ float pnA[512], pnB[512];
    const float g = log1pf(expf(spc[h]));
    const float s3 = 0.5773502691896258f;
    const float c1 = s3 * 0.17677669529663687f;
    const float c2 = s3 * g * (1.f / 6.f);
    const float c3 = -s3 * g * (1.f / 12.f);
    const int i0 = it * 64, j0 = jt * 64;

    for (int idx = tid; idx < 2048; idx += 256) {
        int r = idx >> 5, c = idx & 31;
        As[r*60 + c] = qb[(size_t)(i0 + r) * HQK + h*32 + c];
        Bs[r*60 + c] = kb[(size_t)(j0 + r) * HQK + h*32 + c] * c1;
    }
    for (int idx = tid; idx < 1024; idx += 256) {
        const int side = idx >> 9, rem = idx & 511;
        const int r = rem >> 3, p = rem & 7;
        const int row = (side ? j0 : i0) + r;
        const float* P = side ? kpl : qpl;
        const float* lp = P + (size_t)row * HP3 + (h*8 + p) * 3;
        float l0 = lp[0], l1 = lp[1], l2 = lp[2];
        float g0 = fmaf(R[row*9+0], l0, fmaf(R[row*9+1], l1, fmaf(R[row*9+2], l2, t[row*3+0])));
        float g1 = fmaf(R[row*9+3], l0, fmaf(R[row*9+4], l1, fmaf(R[row*9+5], l2, t[row*3+1])));
        float g2 = fmaf(R[row*9+6], l0, fmaf(R[row*9+7], l1, fmaf(R[row*9+8], l2, t[row*3+2])));
        float nn = g0*g0 + g1*g1 + g2*g2;
        if (side == 0) {
            float* d = &As[r*60 + 32 + p*3];
            d[0] = g0 * c2; d[1] = g1 * c2; d[2] = g2 * c2;
            pnA[r*8 + p] = nn;
        } else {
            float* d = &Bs[r*60 + 32 + p*3];
            d[0] = g0; d[1] = g1; d[2] = g2;
            pnB[r*8 + p] = nn;
        }
    }
    __syncthreads();
    if (tid < 64) {
        float s = 0.f;
#pragma unroll
        for (int p = 0; p < 8; ++p) s += pnA[tid*8 + p];
        As[tid*60 + 56] = s * c3;
        As[tid*60 + 57] = 1.f;
        As[tid*60 + 58] = 0.f; As[tid*60 + 59] = 0.f;
    } else if (tid < 128) {
        const int r = tid - 64;
        float s = 0.f;
#pragma unroll
        for (int p = 0; p < 8; ++p) s += pnB[r*8 + p];
        Bs[r*60 + 56] = 1.f;
        Bs[r*60 + 57] = s * c3;
        Bs[r*60 + 58] = 0.f; Bs[r*60 + 59] = 0.f;
    }
    __syncthreads();

    const int tx = tid & 15, ty = tid >> 4;
    float acc[4][4] = {};
    for (int k4 = 0; k4 < 60; k4 += 4) {
        float4 a[4], b[4];
#pragma unroll
        for (int r = 0; r < 4; ++r) a[r] = *(const float4*)&As[(ty*4 + r)*60 + k4];
#pragma unroll
        for (int c = 0; c < 4; ++c) b[c] = *(const float4*)&Bs[(tx*4 + c)*60 + k4];
#pragma unroll
        for (int r = 0; r < 4; ++r)
#pragma unroll
            for (int c = 0; c < 4; ++c) {
                acc[r][c] = fmaf(a[r].x, b[c].x, acc[r][c]);
                acc[r][c] = fmaf(a[r].y, b[c].y, acc[r][c]);
                acc[r][c] = fmaf(a[r].z, b[c].z, acc[r][c]);
                acc[r][c] = fmaf(a[r].w, b[c].w, acc[r][c]);
            }
    }
#pragma unroll
    for (int r = 0; r < 4; ++r)
        *(float4*)&lgN[((size_t)(i0 + ty*4 + r) * NH + h) * LL + j0 + tx*4] =
            make_float4(acc[r][0], acc[r][1], acc[r][2], acc[r][3]);
}

// ---------------- K4a: pair term + softmax + p2n; alpha out as bf16 ----------------
__global__ void __launch_bounds__(512, 4) k4a_fused(
    const float* __restrict__ z, const float* __restrict__ Wpb,
    const float* __restrict__ lgA, unsigned short* __restrict__ albf,
    float* __restrict__ feat) {
    const int i = blockIdx.x, tid = threadIdx.x;
    __shared__ __align__(16) unsigned char zu[384 * 68 * 2];
    unsigned short* z_s = (unsigned short*)zu;
    float* red = (float*)zu;
    __shared__ float a_s[NH * 384];
    __shared__ float wpb_s[CC * NH];

    const float4* zsrc = (const float4*)(z + (size_t)i * (LL * CC));
#pragma unroll
    for (int k = 0; k < 12; ++k) {
        int idx = tid + k * 512;
        float4 v = zsrc[idx];
        int j = idx >> 4, c4 = idx & 15;
        ushort4 pk;
        pk.x = f2bf(v.x); pk.y = f2bf(v.y); pk.z = f2bf(v.z); pk.w = f2bf(v.w);
        *(ushort4*)&z_s[j * 68 + c4 * 4] = pk;
    }
    if (tid < 384) {
        wpb_s[tid] = Wpb[tid];
        if (tid < CC * NH - 384) wpb_s[384 + tid] = Wpb[384 + tid];
    }
    __syncthreads();

    if (tid < 384) {
        const int j = tid;
        float pacc[12] = {};
        const unsigned short* zrow = &z_s[j * 68];
#pragma unroll
        for (int c4 = 0; c4 < 16; ++c4) {
            ushort4 zz = *(const ushort4*)&zrow[c4 * 4];
            float z0 = bf2f(zz.x), z1 = bf2f(zz.y), z2 = bf2f(zz.z), z3 = bf2f(zz.w);
            const float* wp = wpb_s + c4 * 4 * NH;
#pragma unroll
            for (int hh = 0; hh < 12; ++hh) {
                float p = pacc[hh];
                p = fmaf(z0, wp[hh], p);
                p = fmaf(z1, wp[NH + hh], p);
                p = fmaf(z2, wp[2*NH + hh], p);
                p = fmaf(z3, wp[3*NH + hh], p);
                pacc[hh] = p;
            }
        }
        const float s3 = 0.5773502691896258f;
#pragma unroll
        for (int hh = 0; hh < 12; ++hh)
            a_s[hh * 384 + j] = lgA[((size_t)i * NH + hh) * LL + j] + pacc[hh] * s3;
    }
    __syncthreads();

    const int wv = tid >> 6, lane = tid & 63;
    if (wv < 6) {
#pragma unroll
        for (int rr = 0; rr < 2; ++rr) {
            const int h = wv * 2 + rr;
            float v[6];
#pragma unroll
            for (int k = 0; k < 6; ++k) v[k] = a_s[h * 384 + lane + k * 64];
            float m = v[0];
#pragma unroll
            for (int k = 1; k < 6; ++k) m = fmaxf(m, v[k]);
#pragma unroll
            for (int off = 32; off; off >>= 1) m = fmaxf(m, __shfl_xor(m, off));
            float s = 0.f;
#pragma unroll
            for (int k = 0; k < 6; ++k) { v[k] = expf(v[k] - m); s += v[k]; }
#pragma unroll
            for (int off = 32; off; off >>= 1) s += __shfl_xor(s, off);
            float inv = 1.f / s;
            unsigned short* arow = albf + ((size_t)i * NH + h) * LL;
#pragma unroll
            for (int k = 0; k < 6; ++k) {
                float a = v[k] * inv;
                a_s[h * 384 + lane + k * 64] = a;
                arow[lane + k * 64] = f2bf(a);
            }
        }
    }
    __syncthreads();

    const int c4 = tid & 15, jc = tid >> 4;
    float4 acc[12] = {};
    const int jbase = jc * 12;
#pragma unroll
    for (int j4 = 0; j4 < 3; ++j4) {
        const int j = jbase + j4 * 4;
        float zv[4][4];
#pragma unroll
        for (int jj = 0; jj < 4; ++jj) {
            ushort4 zz = *(const ushort4*)&z_s[(j + jj) * 68 + c4 * 4];
            zv[jj][0] = bf2f(zz.x); zv[jj][1] = bf2f(zz.y);
            zv[jj][2] = bf2f(zz.z); zv[jj][3] = bf2f(zz.w);
        }
#pragma unroll
        for (int hh = 0; hh < 12; ++hh) {
            float4 a4 = *(const float4*)&a_s[hh * 384 + j];
            acc[hh].x = fmaf(a4.x, zv[0][0], acc[hh].x); acc[hh].y = fmaf(a4.x, zv[0][1], acc[hh].y);
            acc[hh].z = fmaf(a4.x, zv[0][2], acc[hh].z); acc[hh].w = fmaf(a4.x, zv[0][3], acc[hh].w);
            acc[hh].x = fmaf(a4.y, zv[1][0], acc[hh].x); acc[hh].y = fmaf(a4.y, zv[1][1], acc[hh].y);
            acc[hh].z = fmaf(a4.y, zv[1][2], acc[hh].z); acc[hh].w = fmaf(a4.y, zv[1][3], acc[hh].w);
            acc[hh].x = fmaf(a4.z, zv[2][0], acc[hh].x); acc[hh].y = fmaf(a4.z, zv[2][1], acc[hh].y);
            acc[hh].z = fmaf(a4.z, zv[2][2], acc[hh].z); acc[hh].w = fmaf(a4.z, zv[2][3], acc[hh].w);
            acc[hh].x = fmaf(a4.w, zv[3][0], acc[hh].x); acc[hh].y = fmaf(a4.w, zv[3][1], acc[hh].y);
            acc[hh].z = fmaf(a4.w, zv[3][2], acc[hh].z); acc[hh].w = fmaf(a4.w, zv[3][3], acc[hh].w);
        }
    }
    __syncthreads();   // z_s reads done; red aliases z_s
#pragma unroll
    for (int hh = 0; hh < 12; ++hh) {
        acc[hh].x += __shfl_xor(acc[hh].x, 16); acc[hh].y += __shfl_xor(acc[hh].y, 16);
        acc[hh].z += __shfl_xor(acc[hh].z, 16); acc[hh].w += __shfl_xor(acc[hh].w, 16);
        acc[hh].x += __shfl_xor(acc[hh].x, 32); acc[hh].y += __shfl_xor(acc[hh].y, 32);
        acc[hh].z += __shfl_xor(acc[hh].z, 32); acc[hh].w += __shfl_xor(acc[hh].w, 32);
    }
    if (lane < 16) {
#pragma unroll
        for (int hh = 0; hh < 12; ++hh)
            *(float4*)&red[wv * 768 + hh * 64 + lane * 4] = acc[hh];
    }
    __syncthreads();
    if (tid < 192) {
        int hh = tid >> 4, cc = tid & 15;
        float4 s = make_float4(0.f, 0.f, 0.f, 0.f);
#pragma unroll
        for (int w = 0; w < 8; ++w) {
            float4 p = *(const float4*)&red[w * 768 + hh * 64 + cc * 4];
            s.x += p.x; s.y += p.y; s.z += p.z; s.w += p.w;
        }
        *(float4*)&feat[(size_t)i * P2N + hh * 64 + cc * 4] = s;
    }
}

// ---------------- K45: aggregation + frame transform + per-head out-proj ----------------
// grid (24 it, 12 h), 512 thr. Inner loop: 8 rows/thread, 4-way j-split
// (bs b32 reads per FMA cut 4x; alpha reads are same-address broadcasts).
__global__ void __launch_bounds__(512) k45_aggproj(
    const unsigned short* __restrict__ albf, const float* __restrict__ vb,
    const float* __restrict__ vpl, const float* __restrict__ R,
    const float* __restrict__ t, const float* __restrict__ feat,
    const float* __restrict__ Wout, float* __restrict__ partial) {
    const int it = blockIdx.x, h = blockIdx.y;
    const int tid = threadIdx.x;
    __shared__ float bs[128 * 57];         // 29.2 KB; reused as jq-reduce scratch
    __shared__ float atile[16][128];       // 8 KB
    __shared__ float fa[16][152];          // 9.7 KB
    __shared__ float sa[16][24];           // 1.5 KB
    const int i0 = it * 16;
    const int n  = tid & 63;               // feature lane
    const int rg = (tid >> 6) & 1;         // rows rg*8 .. rg*8+7
    const int jq = tid >> 7;               // j-quarter 0..3

    if (tid < 256) {
        int r = tid >> 4, c4 = tid & 15;
        float4 v = *(const float4*)&feat[(size_t)(i0 + r) * P2N + h * 64 + c4 * 4];
        *(float4*)&fa[r][c4 * 4] = v;
    }

    float acc[8] = {};
    for (int tile = 0; tile < 3; ++tile) {
        const int j0 = tile * 128;
        __syncthreads();
        for (int idx = tid; idx < 2048; idx += 512) {
            if (idx < 1024) {
                int jr = idx >> 3, q = idx & 7;
                const float* src = vb + (size_t)(j0 + jr) * HV + h * 32 + q * 4;
                float* d = &bs[jr * 57 + q * 4];
                d[0] = src[0]; d[1] = src[1]; d[2] = src[2]; d[3] = src[3];
            } else {
                int id2 = idx - 1024;
                int jr = id2 >> 3, p = id2 & 7;
                const int row = j0 + jr;
                const float* lp = vpl + (size_t)row * HP3 + (h*8 + p) * 3;
                float l0 = lp[0], l1 = lp[1], l2 = lp[2];
                float g0 = fmaf(R[row*9+0], l0, fmaf(R[row*9+1], l1, fmaf(R[row*9+2], l2, t[row*3+0])));
                float g1 = fmaf(R[row*9+3], l0, fmaf(R[row*9+4], l1, fmaf(R[row*9+5], l2, t[row*3+1])));
                float g2 = fmaf(R[row*9+6], l0, fmaf(R[row*9+7], l1, fmaf(R[row*9+8], l2, t[row*3+2])));
                float* d = &bs[jr * 57 + 32 + p * 3];
                d[0] = g0; d[1] = g1; d[2] = g2;
            }
        }
        // stage alpha tile bf16 -> fp32: 16 rows x 128 j
        {
            int r = tid >> 5, c8 = tid & 31;
            ushort4 v = *(const ushort4*)&albf[((size_t)(i0 + r) * NH + h) * LL + j0 + c8 * 4];
            float* d = &atile[r][c8 * 4];
            d[0] = bf2f(v.x); d[1] = bf2f(v.y); d[2] = bf2f(v.z); d[3] = bf2f(v.w);
        }
        __syncthreads();
        if (n < 56) {
#pragma unroll
            for (int jj = 0; jj < 8; ++jj) {
                const int j4 = jq * 8 + jj;
                float bv0 = bs[(j4*4+0)*57 + n];
                float bv1 = bs[(j4*4+1)*57 + n];
                float bv2 = bs[(j4*4+2)*57 + n];
                float bv3 = bs[(j4*4+3)*57 + n];
#pragma unroll
                for (int r = 0; r < 8; ++r) {
                    float4 a4 = *(const float4*)&atile[rg * 8 + r][j4 * 4];  // broadcast
                    acc[r] = fmaf(a4.x, bv0, acc[r]);
                    acc[r] = fmaf(a4.y, bv1, acc[r]);
                    acc[r] = fmaf(a4.z, bv2, acc[r]);
                    acc[r] = fmaf(a4.w, bv3, acc[r]);
                }
            }
        }
    }
    __syncthreads();
    // reduce 4 jq partials via bs scratch: layout [jq][row][n] (4*16*64 = 4096 floats)
    {
#pragma unroll
        for (int r = 0; r < 8; ++r)
            bs[((jq * 16) + rg * 8 + r) * 64 + n] = acc[r];
    }
    __syncthreads();
    for (int e = tid; e < 1024; e += 512) {
        int row = e >> 6, nn = e & 63;
        if (nn < 56) {
            float s = bs[(0*16 + row) * 64 + nn] + bs[(1*16 + row) * 64 + nn]
                    + bs[(2*16 + row) * 64 + nn] + bs[(3*16 + row) * 64 + nn];
            if (nn < 32) fa[row][64 + nn] = s;
            else         sa[row][nn - 32] = s;
        }
    }
    __syncthreads();
    if (tid < 128) {
        const int ri = tid >> 3, p = tid & 7;
        const int i = i0 + ri;
        float d0 = sa[ri][p*3+0] - t[i*3+0];
        float d1 = sa[ri][p*3+1] - t[i*3+1];
        float d2 = sa[ri][p*3+2] - t[i*3+2];
        float f0 = R[i*9+0]*d0 + R[i*9+3]*d1 + R[i*9+6]*d2;
        float f1 = R[i*9+1]*d0 + R[i*9+4]*d1 + R[i*9+7]*d2;
        float f2 = R[i*9+2]*d0 + R[i*9+5]*d1 + R[i*9+8]*d2;
        float dist = sqrtf(f0*f0 + f1*f1 + f2*f2);
        float inv = 1.f / (dist + 1e-4f);
        fa[ri][96 + p*3+0] = f0; fa[ri][96 + p*3+1] = f1; fa[ri][96 + p*3+2] = f2;
        fa[ri][120 + p] = dist;
        fa[ri][128 + p*3+0] = f0*inv; fa[ri][128 + p*3+1] = f1*inv; fa[ri][128 + p*3+2] = f2*inv;
    }
    __syncthreads();

    const int f = tid & 127, rgo = tid >> 7;
    float o[4] = {};
    const float* fr0 = &fa[rgo * 4][0];
    {
        const float* w = Wout + (size_t)(h * 64) * FF + f;          // p2n
        for (int k = 0; k < 64; ++k) {
            float wv_ = w[(size_t)k * FF];
#pragma unroll
            for (int r = 0; r < 4; ++r) o[r] = fmaf(fr0[r * 152 + k], wv_, o[r]);
        }
    }
    {
        const float* w = Wout + (size_t)(768 + h * 32) * FF + f;    // node
        for (int k = 0; k < 32; ++k) {
            float wv_ = w[(size_t)k * FF];
#pragma unroll
            for (int r = 0; r < 4; ++r) o[r] = fmaf(fr0[r * 152 + 64 + k], wv_, o[r]);
        }
    }
    {
        const float* w = Wout + (size_t)(1152 + h * 24) * FF + f;   // fp
        for (int k = 0; k < 24; ++k) {
            float wv_ = w[(size_t)k * FF];
#pragma unroll
            for (int r = 0; r < 4; ++r) o[r] = fmaf(fr0[r * 152 + 96 + k], wv_, o[r]);
        }
    }
    {
        const float* w = Wout + (size_t)(1440 + h * 8) * FF + f;    // dist
        for (int k = 0; k < 8; ++k) {
            float wv_ = w[(size_t)k * FF];
#pragma unroll
            for (int r = 0; r < 4; ++r) o[r] = fmaf(fr0[r * 152 + 120 + k], wv_, o[r]);
        }
    }
    {
        const float* w = Wout + (size_t)(1536 + h * 24) * FF + f;   // dirn
        for (int k = 0; k < 24; ++k) {
            float wv_ = w[(size_t)k * FF];
#pragma unroll
            for (int r = 0; r < 4; ++r) o[r] = fmaf(fr0[r * 152 + 128 + k], wv_, o[r]);
        }
    }
#pragma unroll
    for (int r = 0; r < 4; ++r)
        partial[((size_t)h * LL + i0 + rgo * 4 + r) * FF + f] = o[r];
}

// ---------------- K5b: sum 12 partials + LN1 + MLP(split-4) + LN2 ----------------
__global__ void __launch_bounds__(512) k5b_rowepi(
    const float* __restrict__ partial, const float* __restrict__ bout,
    const float* __restrict__ x,
    const float* __restrict__ ln1g, const float* __restrict__ ln1b,
    const float* __restrict__ W1, const float* __restrict__ b1,
    const float* __restrict__ W2, const float* __restrict__ b2,
    const float* __restrict__ W3, const float* __restrict__ b3,
    const float* __restrict__ ln2g, const float* __restrict__ ln2b,
    float* __restrict__ out) {
    const int i = blockIdx.x, tid = threadIdx.x;
    const int f = tid & 127, q = tid >> 7;
    __shared__ float prt[4][128];
    __shared__ float x1s[128], hbA[128], hbB[128];
    __shared__ float wrA[2], wrB[2];

    {
        float acc = 0.f;
#pragma unroll
        for (int k = 0; k < 3; ++k)
            acc += partial[((size_t)(q * 3 + k) * LL + i) * FF + f];
        prt[q][f] = acc;
    }
    __syncthreads();

    float s1 = 0.f, dv1 = 0.f;
    if (tid < 128) {
        s1 = prt[0][f] + prt[1][f] + prt[2][f] + prt[3][f] + bout[f] + x[(size_t)i * FF + f];
        float r = s1;
#pragma unroll
        for (int off = 32; off; off >>= 1) r += __shfl_xor(r, off);
        if ((tid & 63) == 0) wrA[tid >> 6] = r;
    }
    __syncthreads();
    if (tid < 128) {
        float mu = (wrA[0] + wrA[1]) * (1.f / FF);
        dv1 = s1 - mu;
        float r = dv1 * dv1;
#pragma unroll
        for (int off = 32; off; off >>= 1) r += __shfl_xor(r, off);
        if ((tid & 63) == 0) wrB[tid >> 6] = r;
    }
    __syncthreads();
    if (tid < 128) {
        float var = (wrB[0] + wrB[1]) * (1.f / FF);
        x1s[f] = dv1 * rsqrtf(var + 1e-5f) * ln1g[f] + ln1b[f];
    }
    __syncthreads();

    {
        const int k0 = q * 32;
        float p0=0,p1=0,p2=0,p3=0;
        for (int k = 0; k < 8; ++k) {
            int d = k0 + k * 4;
            p0 = fmaf(x1s[d+0], W1[(size_t)(d+0)*FF + f], p0);
            p1 = fmaf(x1s[d+1], W1[(size_t)(d+1)*FF + f], p1);
            p2 = fmaf(x1s[d+2], W1[(size_t)(d+2)*FF + f], p2);
            p3 = fmaf(x1s[d+3], W1[(size_t)(d+3)*FF + f], p3);
        }
        prt[q][f] = p0 + p1 + p2 + p3;
    }
    __syncthreads();
    if (tid < 128) hbA[f] = fmaxf(prt[0][f]+prt[1][f]+prt[2][f]+prt[3][f] + b1[f], 0.f);
    __syncthreads();
    {
        const int k0 = q * 32;
        float p0=0,p1=0,p2=0,p3=0;
        for (int k = 0; k < 8; ++k) {
            int d = k0 + k * 4;
            p0 = fmaf(hbA[d+0], W2[(size_t)(d+0)*FF + f], p0);
            p1 = fmaf(hbA[d+1], W2[(size_t)(d+1)*FF + f], p1);
            p2 = fmaf(hbA[d+2], W2[(size_t)(d+2)*FF + f], p2);
            p3 = fmaf(hbA[d+3], W2[(size_t)(d+3)*FF + f], p3);
        }
        prt[q][f] = p0 + p1 + p2 + p3;
    }
    __syncthreads();
    if (tid < 128) hbB[f] = fmaxf(prt[0][f]+prt[1][f]+prt[2][f]+prt[3][f] + b2[f], 0.f);
    __syncthreads();
    {
        const int k0 = q * 32;
        float p0=0,p1=0,p2=0,p3=0;
        for (int k = 0; k < 8; ++k) {
            int d = k0 + k * 4;
            p0 = fmaf(hbB[d+0], W3[(size_t)(d+0)*FF + f], p0);
            p1 = fmaf(hbB[d+1], W3[(size_t)(d+1)*FF + f], p1);
            p2 = fmaf(hbB[d+2], W3[(size_t)(d+2)*FF + f], p2);
            p3 = fmaf(hbB[d+3], W3[(size_t)(d+3)*FF + f], p3);
        }
        prt[q][f] = p0 + p1 + p2 + p3;
    }
    __syncthreads();

    float s2 = 0.f, dv2 = 0.f;
    if (tid < 128) {
        s2 = x1s[f] + prt[0][f]+prt[1][f]+prt[2][f]+prt[3][f] + b3[f];
        float r = s2;
#pragma unroll
        for (int off = 32; off; off >>= 1) r += __shfl_xor(r, off);
        if ((tid & 63) == 0) wrA[tid >> 6] = r;
    }
    __syncthreads();
    if (tid < 128) {
        float mu = (wrA[0] + wrA[1]) * (1.f / FF);
        dv2 = s2 - mu;
        float r = dv2 * dv2;
#pragma unroll
        for (int off = 32; off; off >>= 1) r += __shfl_xor(r, off);
        if ((tid & 63) == 0) wrB[tid >> 6] = r;
    }
    __syncthreads();
    if (tid < 128) {
        float var = (wrB[0] + wrB[1]) * (1.f / FF);
        out[(size_t)i * FF + f] = dv2 * rsqrtf(var + 1e-5f) * ln2g[f] + ln2b[f];
    }
}

extern "C" void kernel_launch(void* const* d_in, const int* in_sizes, int n_in,
                              void* d_out, int out_size, void* d_ws, size_t ws_size,
                              hipStream_t stream) {
    const float* R    = (const float*)d_in[0];
    const float* t    = (const float*)d_in[1];
    const float* x    = (const float*)d_in[2];
    const float* z    = (const float*)d_in[3];
    const float* Wq   = (const float*)d_in[5];
    const float* Wk   = (const float*)d_in[6];
    const float* Wv   = (const float*)d_in[7];
    const float* Wpb  = (const float*)d_in[8];
    const float* spc  = (const float*)d_in[9];
    const float* Wqp  = (const float*)d_in[10];
    const float* Wkp  = (const float*)d_in[11];
    const float* Wvp  = (const float*)d_in[12];
    const float* Wout = (const float*)d_in[13];
    const float* bout = (const float*)d_in[14];
    const float* ln1g = (const float*)d_in[15];
    const float* ln1b = (const float*)d_in[16];
    const float* W1   = (const float*)d_in[17];
    const float* b1   = (const float*)d_in[18];
    const float* W2   = (const float*)d_in[19];
    const float* b2   = (const float*)d_in[20];
    const float* W3   = (const float*)d_in[21];
    const float* b3   = (const float*)d_in[22];
    const float* ln2g = (const float*)d_in[23];
    const float* ln2b = (const float*)d_in[24];
    float* out = (float*)d_out;

    float* ws = (float*)d_ws;
    float* qb   = ws;
    float* kb   = qb   + (size_t)LL * HQK;
    float* vb   = kb   + (size_t)LL * HQK;
    float* qpl  = vb   + (size_t)LL * HV;
    float* kpl  = qpl  + (size_t)LL * HP3;
    float* vpl  = kpl  + (size_t)LL * HP3;
    float* lgA  = vpl  + (size_t)LL * HP3;      // [384][12][384] node+spatial logits
    float* feat = lgA  + (size_t)LL * NH * LL;  // [384][768] p2n only
    float* part = feat + (size_t)LL * P2N;      // [12][384][128]
    unsigned short* albf = (unsigned short*)(part + (size_t)NH * LL * FF);  // bf16 alpha

    k1a_gemm<<<378, 256, 0, stream>>>(x, Wq, Wk, Wv, Wqp, Wkp, Wvp,
                                      qb, kb, vb, qpl, kpl, vpl);
    k3_node<<<dim3(6, 6, 12), 256, 0, stream>>>(qb, kb, qpl, kpl, R, t, spc, lgA);
    k4a_fused<<<LL, 512, 0, stream>>>(z, Wpb, lgA, albf, feat);
    k45_aggproj<<<dim3(24, 12), 512, 0, stream>>>(albf, vb, vpl, R, t, feat, Wout, part);
    k5b_rowepi<<<LL, 512, 0, stream>>>(part, bout, x, ln1g, ln1b,
                                       W1, b1, W2, b2, W3, b3, ln2g, ln2b, out);
}